// Round 2
// baseline (2331.417 us; speedup 1.0000x reference)
//
#include <hip/hip_runtime.h>
#include <hip/hip_bf16.h>
#include <stdint.h>

typedef __bf16 bf16x8 __attribute__((ext_vector_type(8)));
typedef float  f32x4  __attribute__((ext_vector_type(4)));
typedef unsigned short u16x8 __attribute__((ext_vector_type(8)));

__device__ __forceinline__ unsigned short f2bf(float f) {
  unsigned u = __builtin_bit_cast(unsigned, f);
  unsigned r = (u + 0x7fffu + ((u >> 16) & 1u)) >> 16;
  return (unsigned short)r;
}
__device__ __forceinline__ float bf2f(unsigned short s) {
  unsigned u = ((unsigned)s) << 16;
  return __builtin_bit_cast(float, u);
}

__device__ __forceinline__ void gload_lds16(const void* g, void* l) {
  __builtin_amdgcn_global_load_lds(
      (const __attribute__((address_space(1))) unsigned int*)(g),
      (__attribute__((address_space(3))) unsigned int*)(l),
      16, 0, 0);
}

// ---------------- cast fp32 -> bf16 (vectorized) ----------------
__global__ __launch_bounds__(256) void cast_bf16_k(const float4* __restrict__ in,
                                                   ushort4* __restrict__ out, int n4) {
  int i = blockIdx.x * 256 + threadIdx.x;
  int stride = gridDim.x * 256;
  for (; i < n4; i += stride) {
    float4 v = in[i];
    ushort4 o;
    o.x = f2bf(v.x); o.y = f2bf(v.y); o.z = f2bf(v.z); o.w = f2bf(v.w);
    out[i] = o;
  }
}

// ---------------- pad+cast x_proj_w (33x2048) -> (128x2048) bf16 ----------------
__global__ __launch_bounds__(256) void pad_xw_k(const float* __restrict__ xw,
                                                unsigned short* __restrict__ xwp) {
  int i = blockIdx.x * 256 + threadIdx.x;   // grid covers 128*2048
  if (i >= 128 * 2048) return;
  int row = i >> 11, col = i & 2047;
  xwp[i] = (row < 33) ? f2bf(xw[row * 2048 + col]) : (unsigned short)0;
}

// ---------------- bf16 MFMA GEMM: C[M][N] = A[M][K] * B[N][K]^T ----------------
// 128x128 tile, BK=32, 4 waves, 4x4 16x16x32 fragments per wave.
template <bool BF16OUT>
__global__ __launch_bounds__(256) void gemm_bf16_nt(
    const unsigned short* __restrict__ A, const unsigned short* __restrict__ B,
    void* __restrict__ Cv, int M, int N, int K)
{
  __shared__ __align__(16) unsigned short As[128 * 32];
  __shared__ __align__(16) unsigned short Bs[128 * 32];
  const int tid = threadIdx.x;
  const int m0 = blockIdx.x * 128;
  const int n0 = blockIdx.y * 128;
  const int w = tid >> 6, l = tid & 63;
  const int wr = w >> 1, wc = w & 1;
  const int lr = l & 15, kk = (l >> 4) * 8;

  f32x4 acc[4][4];
#pragma unroll
  for (int mi = 0; mi < 4; ++mi)
#pragma unroll
    for (int ni = 0; ni < 4; ++ni)
      acc[mi][ni] = (f32x4){0.f, 0.f, 0.f, 0.f};

  for (int k0 = 0; k0 < K; k0 += 32) {
#pragma unroll
    for (int i = 0; i < 2; ++i) {
      int q = tid + 256 * i;
      int row = q >> 2, sub = q & 3;
      gload_lds16(A + (size_t)(m0 + row) * K + k0 + sub * 8, &As[q * 8]);
      gload_lds16(B + (size_t)(n0 + row) * K + k0 + sub * 8, &Bs[q * 8]);
    }
    __syncthreads();
    bf16x8 af[4], bfr[4];
#pragma unroll
    for (int mi = 0; mi < 4; ++mi)
      af[mi] = *(const bf16x8*)&As[(wr * 64 + mi * 16 + lr) * 32 + kk];
#pragma unroll
    for (int ni = 0; ni < 4; ++ni)
      bfr[ni] = *(const bf16x8*)&Bs[(wc * 64 + ni * 16 + lr) * 32 + kk];
#pragma unroll
    for (int mi = 0; mi < 4; ++mi)
#pragma unroll
      for (int ni = 0; ni < 4; ++ni)
        acc[mi][ni] = __builtin_amdgcn_mfma_f32_16x16x32_bf16(af[mi], bfr[ni], acc[mi][ni], 0, 0, 0);
    __syncthreads();
  }

#pragma unroll
  for (int mi = 0; mi < 4; ++mi)
#pragma unroll
    for (int ni = 0; ni < 4; ++ni) {
      int gr = m0 + wr * 64 + mi * 16 + (l >> 4) * 4;
      int gc = n0 + wc * 64 + ni * 16 + (l & 15);
#pragma unroll
      for (int j = 0; j < 4; ++j) {
        if (BF16OUT)
          ((unsigned short*)Cv)[(size_t)(gr + j) * N + gc] = f2bf(acc[mi][ni][j]);
        else
          ((float*)Cv)[(size_t)(gr + j) * N + gc] = acc[mi][ni][j];
      }
    }
}

// ---------------- depthwise causal conv(4) + bias + SiLU (bf16 in/out) ----------------
__global__ __launch_bounds__(256) void conv_silu_k(
    const unsigned short* __restrict__ xzb, const float* __restrict__ cw,
    const float* __restrict__ cb, unsigned short* __restrict__ xsb)
{
  const int b = blockIdx.y;
  const int l0 = blockIdx.x * 64;
  const int d = threadIdx.x * 8;
  float w[4][8], bias[8];
#pragma unroll
  for (int i = 0; i < 8; ++i) {
    bias[i] = cb[d + i];
#pragma unroll
    for (int j = 0; j < 4; ++j) w[j][i] = cw[(d + i) * 4 + j];
  }
  const size_t rb = (size_t)b * 4096;
  float win[3][8];
#pragma unroll
  for (int j = 0; j < 3; ++j) {
    int l = l0 - 3 + j;
    if (l >= 0) {
      u16x8 v = *(const u16x8*)(xzb + (rb + l) * 4096 + d);
#pragma unroll
      for (int i = 0; i < 8; ++i) win[j][i] = bf2f(v[i]);
    } else {
#pragma unroll
      for (int i = 0; i < 8; ++i) win[j][i] = 0.f;
    }
  }
  for (int l = l0; l < l0 + 64; ++l) {
    u16x8 v = *(const u16x8*)(xzb + (rb + l) * 4096 + d);
    float cur[8]; u16x8 ob;
#pragma unroll
    for (int i = 0; i < 8; ++i) {
      cur[i] = bf2f(v[i]);
      float u = bias[i] + w[0][i] * win[0][i] + w[1][i] * win[1][i]
                        + w[2][i] * win[2][i] + w[3][i] * cur[i];
      float s = u / (1.f + __expf(-u));
      ob[i] = f2bf(s);
    }
    *(u16x8*)(xsb + (rb + l) * 2048 + d) = ob;
#pragma unroll
    for (int i = 0; i < 8; ++i) { win[0][i] = win[1][i]; win[1][i] = win[2][i]; win[2][i] = cur[i]; }
  }
}

// ---------------- selective scan + fused gating ----------------
// one (b,d) channel = 16 lanes (one per state n); 16 channels per block.
__global__ __launch_bounds__(256) void scan_k(
    const unsigned short* __restrict__ xsb16, // [B*L][2048] bf16
    const float* __restrict__ dbc,            // [B*L][128] fp32 (col0=draw, 1..16=B, 17..32=C)
    const float* __restrict__ dtw, const float* __restrict__ dtb,
    const float* __restrict__ alog, const float* __restrict__ Dp,
    const unsigned short* __restrict__ xzb,   // z = xzb[:, :, 2048+d] bf16
    unsigned short* __restrict__ gb)
{
  const int blk = blockIdx.x;
  const int b = blk >> 7;
  const int d0 = (blk & 127) * 16;
  const int tid = threadIdx.x;
  const int c = tid >> 4, n = tid & 15;
  const int d = d0 + c;
  const float adn = -__expf(alog[d * 16 + n]);
  const float wdt = dtw[d], bdt = dtb[d], Dd = Dp[d];

  __shared__ float xs_s[64 * 16];
  __shared__ float bcb[64 * 32];
  __shared__ float drb[64];
  __shared__ float yb[64 * 16];

  float h = 0.f;
  const size_t rowbase = (size_t)b * 4096;

  for (int t0 = 0; t0 < 4096; t0 += 64) {
    for (int i = tid; i < 1024; i += 256) {
      int tt = i >> 4, cc = i & 15;
      xs_s[i] = bf2f(xsb16[(rowbase + t0 + tt) * 2048 + d0 + cc]);
    }
    for (int i = tid; i < 2048; i += 256) {
      int tt = i >> 5, cc = i & 31;
      bcb[i] = dbc[(rowbase + t0 + tt) * 128 + 1 + cc];
    }
    if (tid < 64) drb[tid] = dbc[(rowbase + t0 + tid) * 128];
    __syncthreads();

    for (int tt = 0; tt < 64; ++tt) {
      float xv = xs_s[tt * 16 + c];
      float dr = drb[tt];
      float Bn = bcb[tt * 32 + n];
      float Cn = bcb[tt * 32 + 16 + n];
      float pre = fmaf(dr, wdt, bdt);
      float dlt = (pre > 20.f) ? pre : log1pf(__expf(pre));
      float dA = __expf(dlt * adn);
      h = fmaf(dA, h, dlt * xv * Bn);
      float p = h * Cn;
      p += __shfl_xor(p, 1, 16);
      p += __shfl_xor(p, 2, 16);
      p += __shfl_xor(p, 4, 16);
      p += __shfl_xor(p, 8, 16);
      if (n == 0) yb[tt * 16 + c] = fmaf(Dd, xv, p);
    }
    __syncthreads();

    for (int i = tid; i < 1024; i += 256) {
      int tt = i >> 4, cc = i & 15;
      size_t row = rowbase + t0 + tt;
      float y = yb[i];
      float z = bf2f(xzb[row * 4096 + 2048 + d0 + cc]);
      float s = z / (1.f + __expf(-z));
      gb[row * 2048 + d0 + cc] = f2bf(y * s);
    }
    __syncthreads();
  }
}

extern "C" void kernel_launch(void* const* d_in, const int* in_sizes, int n_in,
                              void* d_out, int out_size, void* d_ws, size_t ws_size,
                              hipStream_t stream) {
  const float* x    = (const float*)d_in[0];
  const float* ipw  = (const float*)d_in[1];
  const float* cw   = (const float*)d_in[2];
  const float* cb   = (const float*)d_in[3];
  const float* xpw  = (const float*)d_in[4];
  const float* dtw  = (const float*)d_in[5];
  const float* dtb  = (const float*)d_in[6];
  const float* alog = (const float*)d_in[7];
  const float* Dp   = (const float*)d_in[8];
  const float* opw  = (const float*)d_in[9];
  float* out = (float*)d_out;

  char* p = (char*)d_ws;
  unsigned short* xb   = (unsigned short*)p; p += (size_t)8388608 * 2;   // x bf16           (16 MiB)
  unsigned short* wb1  = (unsigned short*)p; p += (size_t)4194304 * 2;   // in_proj_w bf16   (8 MiB)
  unsigned short* wb2  = (unsigned short*)p; p += (size_t)2097152 * 2;   // out_proj_w bf16  (4 MiB)
  unsigned short* xwp  = (unsigned short*)p; p += (size_t)262144 * 2;    // padded x_proj_w  (0.5 MiB)
  unsigned short* xzb  = (unsigned short*)p; p += (size_t)33554432 * 2;  // in_proj out bf16 (64 MiB)
  unsigned short* xsb16= (unsigned short*)p; p += (size_t)16777216 * 2;  // conv+silu bf16   (32 MiB)
  float*          dbc  = (float*)p;          p += (size_t)1048576 * 4;   // x_proj out fp32  (4 MiB)
  unsigned short* gb   = (unsigned short*)p; p += (size_t)16777216 * 2;  // y*silu(z) bf16   (32 MiB)

  cast_bf16_k<<<1024, 256, 0, stream>>>((const float4*)x,   (ushort4*)xb,  8388608 / 4);
  cast_bf16_k<<<1024, 256, 0, stream>>>((const float4*)ipw, (ushort4*)wb1, 4194304 / 4);
  cast_bf16_k<<<512,  256, 0, stream>>>((const float4*)opw, (ushort4*)wb2, 2097152 / 4);
  pad_xw_k<<<1024, 256, 0, stream>>>(xpw, xwp);

  gemm_bf16_nt<true ><<<dim3(64, 32), 256, 0, stream>>>(xb, wb1, xzb, 8192, 4096, 1024);
  conv_silu_k<<<dim3(64, 2), 256, 0, stream>>>(xzb, cw, cb, xsb16);
  gemm_bf16_nt<false><<<dim3(64, 1), 256, 0, stream>>>(xsb16, xwp, dbc, 8192, 128, 2048);
  scan_k<<<256, 256, 0, stream>>>(xsb16, dbc, dtw, dtb, alog, Dp, xzb, gb);
  gemm_bf16_nt<false><<<dim3(64, 8), 256, 0, stream>>>(gb, wb2, out, 8192, 1024, 2048);
}

// Round 3
// 724.385 us; speedup vs baseline: 3.2185x; 3.2185x over previous
//
#include <hip/hip_runtime.h>
#include <hip/hip_bf16.h>
#include <stdint.h>

typedef __bf16 bf16x8 __attribute__((ext_vector_type(8)));
typedef float  f32x4  __attribute__((ext_vector_type(4)));
typedef unsigned short u16x8 __attribute__((ext_vector_type(8)));

#define TC 128   // timesteps per chunk
#define NC 32    // chunks (TC*NC == 4096)

__device__ __forceinline__ unsigned short f2bf(float f) {
  unsigned u = __builtin_bit_cast(unsigned, f);
  unsigned r = (u + 0x7fffu + ((u >> 16) & 1u)) >> 16;
  return (unsigned short)r;
}
__device__ __forceinline__ float bf2f(unsigned short s) {
  unsigned u = ((unsigned)s) << 16;
  return __builtin_bit_cast(float, u);
}

__device__ __forceinline__ void gload_lds16(const void* g, void* l) {
  __builtin_amdgcn_global_load_lds(
      (const __attribute__((address_space(1))) unsigned int*)(g),
      (__attribute__((address_space(3))) unsigned int*)(l),
      16, 0, 0);
}

// ---------------- cast fp32 -> bf16 (vectorized) ----------------
__global__ __launch_bounds__(256) void cast_bf16_k(const float4* __restrict__ in,
                                                   ushort4* __restrict__ out, int n4) {
  int i = blockIdx.x * 256 + threadIdx.x;
  int stride = gridDim.x * 256;
  for (; i < n4; i += stride) {
    float4 v = in[i];
    ushort4 o;
    o.x = f2bf(v.x); o.y = f2bf(v.y); o.z = f2bf(v.z); o.w = f2bf(v.w);
    out[i] = o;
  }
}

// ---------------- pad+cast x_proj_w (33x2048) -> (128x2048) bf16 ----------------
__global__ __launch_bounds__(256) void pad_xw_k(const float* __restrict__ xw,
                                                unsigned short* __restrict__ xwp) {
  int i = blockIdx.x * 256 + threadIdx.x;   // grid covers 128*2048
  if (i >= 128 * 2048) return;
  int row = i >> 11, col = i & 2047;
  xwp[i] = (row < 33) ? f2bf(xw[row * 2048 + col]) : (unsigned short)0;
}

// ---------------- bf16 MFMA GEMM: C[M][N] = A[M][K] * B[N][K]^T ----------------
// 128x128 tile, BK=32, 4 waves, 4x4 16x16x32 fragments per wave.
template <bool BF16OUT>
__global__ __launch_bounds__(256) void gemm_bf16_nt(
    const unsigned short* __restrict__ A, const unsigned short* __restrict__ B,
    void* __restrict__ Cv, int M, int N, int K)
{
  __shared__ __align__(16) unsigned short As[128 * 32];
  __shared__ __align__(16) unsigned short Bs[128 * 32];
  const int tid = threadIdx.x;
  const int m0 = blockIdx.x * 128;
  const int n0 = blockIdx.y * 128;
  const int w = tid >> 6, l = tid & 63;
  const int wr = w >> 1, wc = w & 1;
  const int lr = l & 15, kk = (l >> 4) * 8;

  f32x4 acc[4][4];
#pragma unroll
  for (int mi = 0; mi < 4; ++mi)
#pragma unroll
    for (int ni = 0; ni < 4; ++ni)
      acc[mi][ni] = (f32x4){0.f, 0.f, 0.f, 0.f};

  for (int k0 = 0; k0 < K; k0 += 32) {
#pragma unroll
    for (int i = 0; i < 2; ++i) {
      int q = tid + 256 * i;
      int row = q >> 2, sub = q & 3;
      gload_lds16(A + (size_t)(m0 + row) * K + k0 + sub * 8, &As[q * 8]);
      gload_lds16(B + (size_t)(n0 + row) * K + k0 + sub * 8, &Bs[q * 8]);
    }
    __syncthreads();
    bf16x8 af[4], bfr[4];
#pragma unroll
    for (int mi = 0; mi < 4; ++mi)
      af[mi] = *(const bf16x8*)&As[(wr * 64 + mi * 16 + lr) * 32 + kk];
#pragma unroll
    for (int ni = 0; ni < 4; ++ni)
      bfr[ni] = *(const bf16x8*)&Bs[(wc * 64 + ni * 16 + lr) * 32 + kk];
#pragma unroll
    for (int mi = 0; mi < 4; ++mi)
#pragma unroll
      for (int ni = 0; ni < 4; ++ni)
        acc[mi][ni] = __builtin_amdgcn_mfma_f32_16x16x32_bf16(af[mi], bfr[ni], acc[mi][ni], 0, 0, 0);
    __syncthreads();
  }

#pragma unroll
  for (int mi = 0; mi < 4; ++mi)
#pragma unroll
    for (int ni = 0; ni < 4; ++ni) {
      int gr = m0 + wr * 64 + mi * 16 + (l >> 4) * 4;
      int gc = n0 + wc * 64 + ni * 16 + (l & 15);
#pragma unroll
      for (int j = 0; j < 4; ++j) {
        if (BF16OUT)
          ((unsigned short*)Cv)[(size_t)(gr + j) * N + gc] = f2bf(acc[mi][ni][j]);
        else
          ((float*)Cv)[(size_t)(gr + j) * N + gc] = acc[mi][ni][j];
      }
    }
}

// ---------------- depthwise causal conv(4) + bias + SiLU (bf16 in/out) ----------------
__global__ __launch_bounds__(256) void conv_silu_k(
    const unsigned short* __restrict__ xzb, const float* __restrict__ cw,
    const float* __restrict__ cb, unsigned short* __restrict__ xsb)
{
  const int b = blockIdx.y;
  const int l0 = blockIdx.x * 64;
  const int d = threadIdx.x * 8;
  float w[4][8], bias[8];
#pragma unroll
  for (int i = 0; i < 8; ++i) {
    bias[i] = cb[d + i];
#pragma unroll
    for (int j = 0; j < 4; ++j) w[j][i] = cw[(d + i) * 4 + j];
  }
  const size_t rb = (size_t)b * 4096;
  float win[3][8];
#pragma unroll
  for (int j = 0; j < 3; ++j) {
    int l = l0 - 3 + j;
    if (l >= 0) {
      u16x8 v = *(const u16x8*)(xzb + (rb + l) * 4096 + d);
#pragma unroll
      for (int i = 0; i < 8; ++i) win[j][i] = bf2f(v[i]);
    } else {
#pragma unroll
      for (int i = 0; i < 8; ++i) win[j][i] = 0.f;
    }
  }
  for (int l = l0; l < l0 + 64; ++l) {
    u16x8 v = *(const u16x8*)(xzb + (rb + l) * 4096 + d);
    float cur[8]; u16x8 ob;
#pragma unroll
    for (int i = 0; i < 8; ++i) {
      cur[i] = bf2f(v[i]);
      float u = bias[i] + w[0][i] * win[0][i] + w[1][i] * win[1][i]
                        + w[2][i] * win[2][i] + w[3][i] * cur[i];
      float s = u / (1.f + __expf(-u));
      ob[i] = f2bf(s);
    }
    *(u16x8*)(xsb + (rb + l) * 2048 + d) = ob;
#pragma unroll
    for (int i = 0; i < 8; ++i) { win[0][i] = win[1][i]; win[1][i] = win[2][i]; win[2][i] = cur[i]; }
  }
}

// ---------------- chunk-parallel selective scan ----------------
// Phase 1: per (b, dgroup, chunk): local scan with h0=0 -> S (final local state),
//          P = prod dA = exp(adn * sum dlt). 16 channels x 16 states per block.
__global__ __launch_bounds__(256) void scan_p1(
    const unsigned short* __restrict__ xsb16, const float* __restrict__ dbc,
    const float* __restrict__ dtw, const float* __restrict__ dtb,
    const float* __restrict__ alog,
    float* __restrict__ Sg, float* __restrict__ Pg)
{
  const int chunk = blockIdx.x;
  const int d0 = blockIdx.y * 16;
  const int b = blockIdx.z;
  const int tid = threadIdx.x;
  const int c = tid >> 4, n = tid & 15;
  const int d = d0 + c;
  const size_t rowbase = (size_t)b * 4096 + chunk * TC;

  __shared__ float drS[TC];
  __shared__ float bS[TC][16];
  __shared__ float2 dxS[TC][16];

  if (tid < TC) drS[tid] = dbc[(rowbase + tid) * 128];
  for (int i = tid; i < TC * 16; i += 256) {
    int t = i >> 4, q = i & 15;
    bS[t][q] = dbc[(rowbase + t) * 128 + 1 + q];
  }
  __syncthreads();
  {
    const int cc = tid & 15;
    const float wdt = dtw[d0 + cc], bdt = dtb[d0 + cc];
#pragma unroll
    for (int j = 0; j < TC / 16; ++j) {
      int t = (tid >> 4) + 16 * j;
      float xv = bf2f(xsb16[(rowbase + t) * 2048 + d0 + cc]);
      float pre = fmaf(drS[t], wdt, bdt);
      float dlt = (pre > 20.f) ? pre : log1pf(__expf(pre));
      dxS[t][cc] = make_float2(dlt, dlt * xv);
    }
  }
  __syncthreads();

  const float adn = -__expf(alog[d * 16 + n]);
  float h = 0.f, cd = 0.f;
  for (int t = 0; t < TC; ++t) {
    float2 dd = dxS[t][c];
    float u = dd.y * bS[t][n];
    float dA = __expf(adn * dd.x);
    h = fmaf(dA, h, u);
    cd += dd.x;
  }
  size_t o = (size_t)(b * NC + chunk) * 32768 + d0 * 16 + tid;
  Sg[o] = h;
  Pg[o] = __expf(adn * cd);
}

// Phase 2: scan across chunks; Hg[c] = state entering chunk c.
__global__ __launch_bounds__(256) void scan_p2(
    const float* __restrict__ Pg, const float* __restrict__ Sg,
    float* __restrict__ Hg)
{
  int g = blockIdx.x * 256 + threadIdx.x;   // 65536 = B*D*N
  int b = g >> 15, dn = g & 32767;
  float h = 0.f;
  for (int c = 0; c < NC; ++c) {
    size_t o = (size_t)(b * NC + c) * 32768 + dn;
    float P = Pg[o], S = Sg[o];
    Hg[o] = h;
    h = fmaf(P, h, S);
  }
}

// Phase 3: re-run local scan from true entry state, emit y, fuse gating.
__global__ __launch_bounds__(256) void scan_p3(
    const unsigned short* __restrict__ xsb16, const float* __restrict__ dbc,
    const float* __restrict__ dtw, const float* __restrict__ dtb,
    const float* __restrict__ alog, const float* __restrict__ Dp,
    const unsigned short* __restrict__ xzb, const float* __restrict__ Hg,
    unsigned short* __restrict__ gb)
{
  const int chunk = blockIdx.x;
  const int d0 = blockIdx.y * 16;
  const int b = blockIdx.z;
  const int tid = threadIdx.x;
  const int c = tid >> 4, n = tid & 15;
  const int d = d0 + c;
  const size_t rowbase = (size_t)b * 4096 + chunk * TC;

  __shared__ float drS[TC];
  __shared__ float bcS[TC][32];
  __shared__ float2 dxS[TC][16];
  __shared__ float xvS[TC][16];
  __shared__ float ybS[TC][16];

  if (tid < TC) drS[tid] = dbc[(rowbase + tid) * 128];
  for (int i = tid; i < TC * 32; i += 256) {
    int t = i >> 5, q = i & 31;
    bcS[t][q] = dbc[(rowbase + t) * 128 + 1 + q];
  }
  __syncthreads();
  {
    const int cc = tid & 15;
    const float wdt = dtw[d0 + cc], bdt = dtb[d0 + cc];
#pragma unroll
    for (int j = 0; j < TC / 16; ++j) {
      int t = (tid >> 4) + 16 * j;
      float xv = bf2f(xsb16[(rowbase + t) * 2048 + d0 + cc]);
      float pre = fmaf(drS[t], wdt, bdt);
      float dlt = (pre > 20.f) ? pre : log1pf(__expf(pre));
      dxS[t][cc] = make_float2(dlt, dlt * xv);
      xvS[t][cc] = xv;
    }
  }
  __syncthreads();

  const float adn = -__expf(alog[d * 16 + n]);
  const float Dd = Dp[d];
  float h = Hg[(size_t)(b * NC + chunk) * 32768 + d0 * 16 + tid];
  for (int t = 0; t < TC; ++t) {
    float2 dd = dxS[t][c];
    float u = dd.y * bcS[t][n];
    float dA = __expf(adn * dd.x);
    h = fmaf(dA, h, u);
    float p = h * bcS[t][16 + n];
    p += __shfl_xor(p, 1, 16);
    p += __shfl_xor(p, 2, 16);
    p += __shfl_xor(p, 4, 16);
    p += __shfl_xor(p, 8, 16);
    if (n == 0) ybS[t][c] = fmaf(Dd, xvS[t][c], p);
  }
  __syncthreads();

  for (int i = tid; i < TC * 16; i += 256) {
    int t = i >> 4, cc = i & 15;
    size_t row = rowbase + t;
    float z = bf2f(xzb[row * 4096 + 2048 + d0 + cc]);
    float s = z / (1.f + __expf(-z));
    gb[row * 2048 + d0 + cc] = f2bf(ybS[t][cc] * s);
  }
}

extern "C" void kernel_launch(void* const* d_in, const int* in_sizes, int n_in,
                              void* d_out, int out_size, void* d_ws, size_t ws_size,
                              hipStream_t stream) {
  const float* x    = (const float*)d_in[0];
  const float* ipw  = (const float*)d_in[1];
  const float* cw   = (const float*)d_in[2];
  const float* cb   = (const float*)d_in[3];
  const float* xpw  = (const float*)d_in[4];
  const float* dtw  = (const float*)d_in[5];
  const float* dtb  = (const float*)d_in[6];
  const float* alog = (const float*)d_in[7];
  const float* Dp   = (const float*)d_in[8];
  const float* opw  = (const float*)d_in[9];
  float* out = (float*)d_out;

  char* p = (char*)d_ws;
  unsigned short* xb   = (unsigned short*)p; p += (size_t)8388608 * 2;   // x bf16 (16 MiB) — reused as Hg after in_proj
  unsigned short* wb1  = (unsigned short*)p; p += (size_t)4194304 * 2;   // in_proj_w bf16   (8 MiB)
  unsigned short* wb2  = (unsigned short*)p; p += (size_t)2097152 * 2;   // out_proj_w bf16  (4 MiB)
  unsigned short* xwp  = (unsigned short*)p; p += (size_t)262144 * 2;    // padded x_proj_w  (0.5 MiB)
  unsigned short* xzb  = (unsigned short*)p; p += (size_t)33554432 * 2;  // in_proj out bf16 (64 MiB)
  unsigned short* xsb16= (unsigned short*)p; p += (size_t)16777216 * 2;  // conv+silu bf16   (32 MiB)
  float*          dbc  = (float*)p;          p += (size_t)1048576 * 4;   // x_proj out fp32  (4 MiB)
  unsigned short* gb   = (unsigned short*)p; p += (size_t)16777216 * 2;  // y*silu(z) bf16   (32 MiB)
  float*          Sg   = (float*)p;          p += (size_t)2097152 * 4;   // chunk state      (8 MiB)
  float*          Pg   = (float*)p;          p += (size_t)2097152 * 4;   // chunk decay      (8 MiB)
  float*          Hg   = (float*)xb;                                     // chunk entry state (8 MiB, aliases xb)

  cast_bf16_k<<<1024, 256, 0, stream>>>((const float4*)x,   (ushort4*)xb,  8388608 / 4);
  cast_bf16_k<<<1024, 256, 0, stream>>>((const float4*)ipw, (ushort4*)wb1, 4194304 / 4);
  cast_bf16_k<<<512,  256, 0, stream>>>((const float4*)opw, (ushort4*)wb2, 2097152 / 4);
  pad_xw_k<<<1024, 256, 0, stream>>>(xpw, xwp);

  gemm_bf16_nt<true ><<<dim3(64, 32), 256, 0, stream>>>(xb, wb1, xzb, 8192, 4096, 1024);
  conv_silu_k<<<dim3(64, 2), 256, 0, stream>>>(xzb, cw, cb, xsb16);
  gemm_bf16_nt<false><<<dim3(64, 1), 256, 0, stream>>>(xsb16, xwp, dbc, 8192, 128, 2048);

  scan_p1<<<dim3(NC, 128, 2), 256, 0, stream>>>(xsb16, dbc, dtw, dtb, alog, Sg, Pg);
  scan_p2<<<256, 256, 0, stream>>>(Pg, Sg, Hg);
  scan_p3<<<dim3(NC, 128, 2), 256, 0, stream>>>(xsb16, dbc, dtw, dtb, alog, Dp, xzb, Hg, gb);

  gemm_bf16_nt<false><<<dim3(64, 8), 256, 0, stream>>>(gb, wb2, out, 8192, 1024, 2048);
}

// Round 4
// 453.474 us; speedup vs baseline: 5.1412x; 1.5974x over previous
//
#include <hip/hip_runtime.h>
#include <hip/hip_bf16.h>
#include <stdint.h>

typedef __bf16 bf16x8 __attribute__((ext_vector_type(8)));
typedef float  f32x4  __attribute__((ext_vector_type(4)));
typedef unsigned short u16x8 __attribute__((ext_vector_type(8)));

#define TC 64   // timesteps per chunk
#define NC 64   // chunks (TC*NC == 4096)

__device__ __forceinline__ unsigned short f2bf(float f) {
  unsigned u = __builtin_bit_cast(unsigned, f);
  unsigned r = (u + 0x7fffu + ((u >> 16) & 1u)) >> 16;
  return (unsigned short)r;
}
__device__ __forceinline__ float bf2f(unsigned short s) {
  unsigned u = ((unsigned)s) << 16;
  return __builtin_bit_cast(float, u);
}

__device__ __forceinline__ void gload_lds16(const void* g, void* l) {
  __builtin_amdgcn_global_load_lds(
      (const __attribute__((address_space(1))) unsigned int*)(g),
      (__attribute__((address_space(3))) unsigned int*)(l),
      16, 0, 0);
}

// ---------------- cast fp32 -> bf16 (vectorized) ----------------
__global__ __launch_bounds__(256) void cast_bf16_k(const float4* __restrict__ in,
                                                   ushort4* __restrict__ out, int n4) {
  int i = blockIdx.x * 256 + threadIdx.x;
  int stride = gridDim.x * 256;
  for (; i < n4; i += stride) {
    float4 v = in[i];
    ushort4 o;
    o.x = f2bf(v.x); o.y = f2bf(v.y); o.z = f2bf(v.z); o.w = f2bf(v.w);
    out[i] = o;
  }
}

// ---------------- pad+cast x_proj_w (33x2048) -> (128x2048) bf16 ----------------
__global__ __launch_bounds__(256) void pad_xw_k(const float* __restrict__ xw,
                                                unsigned short* __restrict__ xwp) {
  int i = blockIdx.x * 256 + threadIdx.x;   // grid covers 128*2048
  if (i >= 128 * 2048) return;
  int row = i >> 11, col = i & 2047;
  xwp[i] = (row < 33) ? f2bf(xw[row * 2048 + col]) : (unsigned short)0;
}

// ---------------- bf16 MFMA GEMM: C[M][N] = A[M][K] * B[N][K]^T ----------------
template <bool BF16OUT>
__global__ __launch_bounds__(256) void gemm_bf16_nt(
    const unsigned short* __restrict__ A, const unsigned short* __restrict__ B,
    void* __restrict__ Cv, int M, int N, int K)
{
  __shared__ __align__(16) unsigned short As[128 * 32];
  __shared__ __align__(16) unsigned short Bs[128 * 32];
  const int tid = threadIdx.x;
  const int m0 = blockIdx.x * 128;
  const int n0 = blockIdx.y * 128;
  const int w = tid >> 6, l = tid & 63;
  const int wr = w >> 1, wc = w & 1;
  const int lr = l & 15, kk = (l >> 4) * 8;

  f32x4 acc[4][4];
#pragma unroll
  for (int mi = 0; mi < 4; ++mi)
#pragma unroll
    for (int ni = 0; ni < 4; ++ni)
      acc[mi][ni] = (f32x4){0.f, 0.f, 0.f, 0.f};

  for (int k0 = 0; k0 < K; k0 += 32) {
#pragma unroll
    for (int i = 0; i < 2; ++i) {
      int q = tid + 256 * i;
      int row = q >> 2, sub = q & 3;
      gload_lds16(A + (size_t)(m0 + row) * K + k0 + sub * 8, &As[q * 8]);
      gload_lds16(B + (size_t)(n0 + row) * K + k0 + sub * 8, &Bs[q * 8]);
    }
    __syncthreads();
    bf16x8 af[4], bfr[4];
#pragma unroll
    for (int mi = 0; mi < 4; ++mi)
      af[mi] = *(const bf16x8*)&As[(wr * 64 + mi * 16 + lr) * 32 + kk];
#pragma unroll
    for (int ni = 0; ni < 4; ++ni)
      bfr[ni] = *(const bf16x8*)&Bs[(wc * 64 + ni * 16 + lr) * 32 + kk];
#pragma unroll
    for (int mi = 0; mi < 4; ++mi)
#pragma unroll
      for (int ni = 0; ni < 4; ++ni)
        acc[mi][ni] = __builtin_amdgcn_mfma_f32_16x16x32_bf16(af[mi], bfr[ni], acc[mi][ni], 0, 0, 0);
    __syncthreads();
  }

#pragma unroll
  for (int mi = 0; mi < 4; ++mi)
#pragma unroll
    for (int ni = 0; ni < 4; ++ni) {
      int gr = m0 + wr * 64 + mi * 16 + (l >> 4) * 4;
      int gc = n0 + wc * 64 + ni * 16 + (l & 15);
#pragma unroll
      for (int j = 0; j < 4; ++j) {
        if (BF16OUT)
          ((unsigned short*)Cv)[(size_t)(gr + j) * N + gc] = f2bf(acc[mi][ni][j]);
        else
          ((float*)Cv)[(size_t)(gr + j) * N + gc] = acc[mi][ni][j];
      }
    }
}

// ---------------- depthwise causal conv(4) + bias + SiLU (bf16 in/out) ----------------
#define CONV_L 16
__global__ __launch_bounds__(256) void conv_silu_k(
    const unsigned short* __restrict__ xzb, const float* __restrict__ cw,
    const float* __restrict__ cb, unsigned short* __restrict__ xsb)
{
  const int b = blockIdx.y;
  const int l0 = blockIdx.x * CONV_L;
  const int d = threadIdx.x * 8;
  float w[4][8], bias[8];
#pragma unroll
  for (int i = 0; i < 8; ++i) {
    bias[i] = cb[d + i];
#pragma unroll
    for (int j = 0; j < 4; ++j) w[j][i] = cw[(d + i) * 4 + j];
  }
  const size_t rb = (size_t)b * 4096;
  float win[3][8];
#pragma unroll
  for (int j = 0; j < 3; ++j) {
    int l = l0 - 3 + j;
    if (l >= 0) {
      u16x8 v = *(const u16x8*)(xzb + (rb + l) * 4096 + d);
#pragma unroll
      for (int i = 0; i < 8; ++i) win[j][i] = bf2f(v[i]);
    } else {
#pragma unroll
      for (int i = 0; i < 8; ++i) win[j][i] = 0.f;
    }
  }
  for (int l = l0; l < l0 + CONV_L; ++l) {
    u16x8 v = *(const u16x8*)(xzb + (rb + l) * 4096 + d);
    float cur[8]; u16x8 ob;
#pragma unroll
    for (int i = 0; i < 8; ++i) {
      cur[i] = bf2f(v[i]);
      float u = bias[i] + w[0][i] * win[0][i] + w[1][i] * win[1][i]
                        + w[2][i] * win[2][i] + w[3][i] * cur[i];
      float s = u / (1.f + __expf(-u));
      ob[i] = f2bf(s);
    }
    *(u16x8*)(xsb + (rb + l) * 2048 + d) = ob;
#pragma unroll
    for (int i = 0; i < 8; ++i) { win[0][i] = win[1][i]; win[1][i] = win[2][i]; win[2][i] = cur[i]; }
  }
}

// ---------------- chunk-parallel selective scan ----------------
// One THREAD per channel d; all 16 states in registers. No cross-lane ops.
// Phase 1: local scan h0=0 -> S[16] (final local state), cd = sum dlt.
__global__ __launch_bounds__(256) void scan_p1(
    const unsigned short* __restrict__ xsb16, const float* __restrict__ dbc,
    const float* __restrict__ dtw, const float* __restrict__ dtb,
    const float* __restrict__ alog,
    float* __restrict__ Sg, float* __restrict__ cdg)
{
  const int chunk = blockIdx.x;
  const int d0 = blockIdx.y * 256;
  const int b = blockIdx.z;
  const int tid = threadIdx.x;
  const size_t rowbase = (size_t)b * 4096 + chunk * TC;

  __shared__ __align__(16) unsigned short xsS[TC][256];
  __shared__ __align__(16) float bS[TC][16];
  __shared__ float drS[TC];

  if (tid < TC) drS[tid] = dbc[(rowbase + tid) * 128];
  for (int i = tid; i < TC * 16; i += 256) {
    int t = i >> 4, q = i & 15;
    bS[t][q] = dbc[(rowbase + t) * 128 + 1 + q];
  }
  for (int i = tid; i < TC * 32; i += 256) {
    int t = i >> 5, q = i & 31;
    *(u16x8*)&xsS[t][q * 8] = *(const u16x8*)(xsb16 + (rowbase + t) * 2048 + d0 + q * 8);
  }
  __syncthreads();

  const int d = d0 + tid;
  const float wdt = dtw[d], bdt = dtb[d];
  float adn[16];
#pragma unroll
  for (int k = 0; k < 4; ++k) {
    float4 a4 = *(const float4*)(alog + (size_t)d * 16 + k * 4);
    adn[4 * k + 0] = -__expf(a4.x); adn[4 * k + 1] = -__expf(a4.y);
    adn[4 * k + 2] = -__expf(a4.z); adn[4 * k + 3] = -__expf(a4.w);
  }
  float h[16];
#pragma unroll
  for (int n = 0; n < 16; ++n) h[n] = 0.f;
  float cd = 0.f;

  for (int t = 0; t < TC; ++t) {
    float pre = fmaf(drS[t], wdt, bdt);
    float dlt = (pre > 20.f) ? pre : log1pf(__expf(pre));
    float xv = bf2f(xsS[t][tid]);
    float dx = dlt * xv;
    cd += dlt;
    f32x4 Bv[4];
#pragma unroll
    for (int k = 0; k < 4; ++k) Bv[k] = ((const f32x4*)&bS[t][0])[k];
#pragma unroll
    for (int n = 0; n < 16; ++n) {
      float dA = __expf(adn[n] * dlt);
      h[n] = fmaf(dA, h[n], dx * Bv[n >> 2][n & 3]);
    }
  }
  cdg[(size_t)(b * NC + chunk) * 2048 + d] = cd;
  float* Sp = Sg + ((size_t)(b * NC + chunk) * 32768 + (size_t)d * 16);
#pragma unroll
  for (int k = 0; k < 4; ++k)
    ((float4*)Sp)[k] = make_float4(h[4 * k], h[4 * k + 1], h[4 * k + 2], h[4 * k + 3]);
}

// Phase 2: scan across chunks; Hg[c] = state entering chunk c. P recomputed from cd.
__global__ __launch_bounds__(256) void scan_p2(
    const float* __restrict__ Sg, const float* __restrict__ cdg,
    const float* __restrict__ alog, float* __restrict__ Hg)
{
  int g = blockIdx.x * 256 + threadIdx.x;   // 65536 = B*D*N
  int b = g >> 15, dn = g & 32767;
  int d = dn >> 4;
  float adn = -__expf(alog[dn]);
  float h = 0.f;
  for (int c = 0; c < NC; ++c) {
    size_t o = (size_t)(b * NC + c) * 32768 + dn;
    float P = __expf(adn * cdg[(size_t)(b * NC + c) * 2048 + d]);
    Hg[o] = h;
    h = fmaf(P, h, Sg[o]);
  }
}

// Phase 3: re-run local scan from true entry state, emit y (into xs tile), fuse gating.
__global__ __launch_bounds__(256) void scan_p3(
    const unsigned short* __restrict__ xsb16, const float* __restrict__ dbc,
    const float* __restrict__ dtw, const float* __restrict__ dtb,
    const float* __restrict__ alog, const float* __restrict__ Dp,
    const unsigned short* __restrict__ xzb, const float* __restrict__ Hg,
    unsigned short* __restrict__ gb)
{
  const int chunk = blockIdx.x;
  const int d0 = blockIdx.y * 256;
  const int b = blockIdx.z;
  const int tid = threadIdx.x;
  const size_t rowbase = (size_t)b * 4096 + chunk * TC;

  __shared__ __align__(16) unsigned short xsS[TC][256];
  __shared__ __align__(16) float bcS[TC][32];
  __shared__ float drS[TC];

  if (tid < TC) drS[tid] = dbc[(rowbase + tid) * 128];
  for (int i = tid; i < TC * 32; i += 256) {
    int t = i >> 5, q = i & 31;
    bcS[t][q] = dbc[(rowbase + t) * 128 + 1 + q];
  }
  for (int i = tid; i < TC * 32; i += 256) {
    int t = i >> 5, q = i & 31;
    *(u16x8*)&xsS[t][q * 8] = *(const u16x8*)(xsb16 + (rowbase + t) * 2048 + d0 + q * 8);
  }
  __syncthreads();

  const int d = d0 + tid;
  const float wdt = dtw[d], bdt = dtb[d], Dd = Dp[d];
  float adn[16];
#pragma unroll
  for (int k = 0; k < 4; ++k) {
    float4 a4 = *(const float4*)(alog + (size_t)d * 16 + k * 4);
    adn[4 * k + 0] = -__expf(a4.x); adn[4 * k + 1] = -__expf(a4.y);
    adn[4 * k + 2] = -__expf(a4.z); adn[4 * k + 3] = -__expf(a4.w);
  }
  float h[16];
  {
    const float* Hp = Hg + ((size_t)(b * NC + chunk) * 32768 + (size_t)d * 16);
#pragma unroll
    for (int k = 0; k < 4; ++k) {
      float4 h4 = ((const float4*)Hp)[k];
      h[4 * k + 0] = h4.x; h[4 * k + 1] = h4.y; h[4 * k + 2] = h4.z; h[4 * k + 3] = h4.w;
    }
  }

  for (int t = 0; t < TC; ++t) {
    float pre = fmaf(drS[t], wdt, bdt);
    float dlt = (pre > 20.f) ? pre : log1pf(__expf(pre));
    float xv = bf2f(xsS[t][tid]);
    float dx = dlt * xv;
    f32x4 Bv[4], Cv[4];
#pragma unroll
    for (int k = 0; k < 4; ++k) {
      Bv[k] = ((const f32x4*)&bcS[t][0])[k];
      Cv[k] = ((const f32x4*)&bcS[t][16])[k];
    }
    float yp[4];
    yp[0] = Dd * xv; yp[1] = 0.f; yp[2] = 0.f; yp[3] = 0.f;
#pragma unroll
    for (int n = 0; n < 16; ++n) {
      float dA = __expf(adn[n] * dlt);
      h[n] = fmaf(dA, h[n], dx * Bv[n >> 2][n & 3]);
      yp[n & 3] = fmaf(h[n], Cv[n >> 2][n & 3], yp[n & 3]);
    }
    float y = (yp[0] + yp[1]) + (yp[2] + yp[3]);
    xsS[t][tid] = f2bf(y);   // overwrite own column with y (no cross-lane hazard)
  }
  __syncthreads();

  for (int i = tid; i < TC * 32; i += 256) {
    int t = i >> 5, q = i & 31;
    u16x8 yv = *(const u16x8*)&xsS[t][q * 8];
    u16x8 zv = *(const u16x8*)(xzb + (rowbase + t) * 4096 + 2048 + d0 + q * 8);
    u16x8 ov;
#pragma unroll
    for (int j = 0; j < 8; ++j) {
      float z = bf2f(zv[j]);
      float s = z / (1.f + __expf(-z));
      ov[j] = f2bf(bf2f(yv[j]) * s);
    }
    *(u16x8*)(gb + (rowbase + t) * 2048 + d0 + q * 8) = ov;
  }
}

extern "C" void kernel_launch(void* const* d_in, const int* in_sizes, int n_in,
                              void* d_out, int out_size, void* d_ws, size_t ws_size,
                              hipStream_t stream) {
  const float* x    = (const float*)d_in[0];
  const float* ipw  = (const float*)d_in[1];
  const float* cw   = (const float*)d_in[2];
  const float* cb   = (const float*)d_in[3];
  const float* xpw  = (const float*)d_in[4];
  const float* dtw  = (const float*)d_in[5];
  const float* dtb  = (const float*)d_in[6];
  const float* alog = (const float*)d_in[7];
  const float* Dp   = (const float*)d_in[8];
  const float* opw  = (const float*)d_in[9];
  float* out = (float*)d_out;

  char* p = (char*)d_ws;
  unsigned short* xb   = (unsigned short*)p; p += (size_t)8388608 * 2;   // x bf16 (16 MiB) — reused as Hg
  unsigned short* wb1  = (unsigned short*)p; p += (size_t)4194304 * 2;   // in_proj_w bf16   (8 MiB)
  unsigned short* wb2  = (unsigned short*)p; p += (size_t)2097152 * 2;   // out_proj_w bf16  (4 MiB)
  unsigned short* xwp  = (unsigned short*)p; p += (size_t)262144 * 2;    // padded x_proj_w  (0.5 MiB)
  unsigned short* xzb  = (unsigned short*)p; p += (size_t)33554432 * 2;  // in_proj out bf16 (64 MiB)
  unsigned short* xsb16= (unsigned short*)p; p += (size_t)16777216 * 2;  // conv+silu bf16   (32 MiB)
  float*          dbc  = (float*)p;          p += (size_t)1048576 * 4;   // x_proj out fp32  (4 MiB)
  unsigned short* gb   = (unsigned short*)p; p += (size_t)16777216 * 2;  // y*silu(z) bf16   (32 MiB)
  float*          Sg   = (float*)p;          p += (size_t)4194304 * 4;   // chunk states     (16 MiB)
  float*          cdg  = (float*)p;          p += (size_t)262144 * 4;    // chunk decay sums (1 MiB)
  float*          Hg   = (float*)xb;                                     // chunk entry states (16 MiB, aliases xb)

  cast_bf16_k<<<1024, 256, 0, stream>>>((const float4*)x,   (ushort4*)xb,  8388608 / 4);
  cast_bf16_k<<<1024, 256, 0, stream>>>((const float4*)ipw, (ushort4*)wb1, 4194304 / 4);
  cast_bf16_k<<<512,  256, 0, stream>>>((const float4*)opw, (ushort4*)wb2, 2097152 / 4);
  pad_xw_k<<<1024, 256, 0, stream>>>(xpw, xwp);

  gemm_bf16_nt<true ><<<dim3(64, 32), 256, 0, stream>>>(xb, wb1, xzb, 8192, 4096, 1024);
  conv_silu_k<<<dim3(4096 / CONV_L, 2), 256, 0, stream>>>(xzb, cw, cb, xsb16);
  gemm_bf16_nt<false><<<dim3(64, 1), 256, 0, stream>>>(xsb16, xwp, dbc, 8192, 128, 2048);

  scan_p1<<<dim3(NC, 8, 2), 256, 0, stream>>>(xsb16, dbc, dtw, dtb, alog, Sg, cdg);
  scan_p2<<<256, 256, 0, stream>>>(Sg, cdg, alog, Hg);
  scan_p3<<<dim3(NC, 8, 2), 256, 0, stream>>>(xsb16, dbc, dtw, dtb, alog, Dp, xzb, Hg, gb);

  gemm_bf16_nt<false><<<dim3(64, 8), 256, 0, stream>>>(gb, wb2, out, 8192, 1024, 2048);
}

// Round 5
// 341.756 us; speedup vs baseline: 6.8219x; 1.3269x over previous
//
#include <hip/hip_runtime.h>
#include <hip/hip_bf16.h>
#include <stdint.h>

typedef __bf16 bf16x8 __attribute__((ext_vector_type(8)));
typedef float  f32x4  __attribute__((ext_vector_type(4)));
typedef unsigned short u16x8 __attribute__((ext_vector_type(8)));

#define TC 64   // timesteps per chunk
#define NC 64   // chunks (TC*NC == 4096)

__device__ __forceinline__ unsigned short f2bf(float f) {
  unsigned u = __builtin_bit_cast(unsigned, f);
  unsigned r = (u + 0x7fffu + ((u >> 16) & 1u)) >> 16;
  return (unsigned short)r;
}
__device__ __forceinline__ float bf2f(unsigned short s) {
  unsigned u = ((unsigned)s) << 16;
  return __builtin_bit_cast(float, u);
}

__device__ __forceinline__ void gload_lds16(const void* g, void* l) {
  __builtin_amdgcn_global_load_lds(
      (const __attribute__((address_space(1))) unsigned int*)(g),
      (__attribute__((address_space(3))) unsigned int*)(l),
      16, 0, 0);
}

// rp[k] = r^(k+1), k=0..15, via full-rate mul tree (depth <= 4)
__device__ __forceinline__ void rpowers(float r, float* rp) {
  float r2 = r * r, r4 = r2 * r2, r8 = r4 * r4;
  rp[0] = r;        rp[1] = r2;       rp[2] = r2 * r;   rp[3] = r4;
  rp[4] = r4 * r;   rp[5] = r4 * r2;  rp[6] = rp[5] * r; rp[7] = r8;
  rp[8] = r8 * r;   rp[9] = r8 * r2;  rp[10] = rp[9] * r; rp[11] = r8 * r4;
  rp[12] = rp[11] * r; rp[13] = rp[11] * r2; rp[14] = rp[13] * r; rp[15] = r8 * r8;
}

// ---------------- cast fp32 -> bf16 (vectorized) ----------------
__global__ __launch_bounds__(256) void cast_bf16_k(const float4* __restrict__ in,
                                                   ushort4* __restrict__ out, int n4) {
  int i = blockIdx.x * 256 + threadIdx.x;
  int stride = gridDim.x * 256;
  for (; i < n4; i += stride) {
    float4 v = in[i];
    ushort4 o;
    o.x = f2bf(v.x); o.y = f2bf(v.y); o.z = f2bf(v.z); o.w = f2bf(v.w);
    out[i] = o;
  }
}

// ---------------- pad+cast x_proj_w (33x2048) -> (128x2048) bf16 ----------------
__global__ __launch_bounds__(256) void pad_xw_k(const float* __restrict__ xw,
                                                unsigned short* __restrict__ xwp) {
  int i = blockIdx.x * 256 + threadIdx.x;   // grid covers 128*2048
  if (i >= 128 * 2048) return;
  int row = i >> 11, col = i & 2047;
  xwp[i] = (row < 33) ? f2bf(xw[row * 2048 + col]) : (unsigned short)0;
}

// ---------------- bf16 MFMA GEMM: C[M][N] = A[M][K] * B[N][K]^T ----------------
template <bool BF16OUT>
__global__ __launch_bounds__(256) void gemm_bf16_nt(
    const unsigned short* __restrict__ A, const unsigned short* __restrict__ B,
    void* __restrict__ Cv, int M, int N, int K)
{
  __shared__ __align__(16) unsigned short As[128 * 32];
  __shared__ __align__(16) unsigned short Bs[128 * 32];
  const int tid = threadIdx.x;
  const int m0 = blockIdx.x * 128;
  const int n0 = blockIdx.y * 128;
  const int w = tid >> 6, l = tid & 63;
  const int wr = w >> 1, wc = w & 1;
  const int lr = l & 15, kk = (l >> 4) * 8;

  f32x4 acc[4][4];
#pragma unroll
  for (int mi = 0; mi < 4; ++mi)
#pragma unroll
    for (int ni = 0; ni < 4; ++ni)
      acc[mi][ni] = (f32x4){0.f, 0.f, 0.f, 0.f};

  for (int k0 = 0; k0 < K; k0 += 32) {
#pragma unroll
    for (int i = 0; i < 2; ++i) {
      int q = tid + 256 * i;
      int row = q >> 2, sub = q & 3;
      gload_lds16(A + (size_t)(m0 + row) * K + k0 + sub * 8, &As[q * 8]);
      gload_lds16(B + (size_t)(n0 + row) * K + k0 + sub * 8, &Bs[q * 8]);
    }
    __syncthreads();
    bf16x8 af[4], bfr[4];
#pragma unroll
    for (int mi = 0; mi < 4; ++mi)
      af[mi] = *(const bf16x8*)&As[(wr * 64 + mi * 16 + lr) * 32 + kk];
#pragma unroll
    for (int ni = 0; ni < 4; ++ni)
      bfr[ni] = *(const bf16x8*)&Bs[(wc * 64 + ni * 16 + lr) * 32 + kk];
#pragma unroll
    for (int mi = 0; mi < 4; ++mi)
#pragma unroll
      for (int ni = 0; ni < 4; ++ni)
        acc[mi][ni] = __builtin_amdgcn_mfma_f32_16x16x32_bf16(af[mi], bfr[ni], acc[mi][ni], 0, 0, 0);
    __syncthreads();
  }

#pragma unroll
  for (int mi = 0; mi < 4; ++mi)
#pragma unroll
    for (int ni = 0; ni < 4; ++ni) {
      int gr = m0 + wr * 64 + mi * 16 + (l >> 4) * 4;
      int gc = n0 + wc * 64 + ni * 16 + (l & 15);
#pragma unroll
      for (int j = 0; j < 4; ++j) {
        if (BF16OUT)
          ((unsigned short*)Cv)[(size_t)(gr + j) * N + gc] = f2bf(acc[mi][ni][j]);
        else
          ((float*)Cv)[(size_t)(gr + j) * N + gc] = acc[mi][ni][j];
      }
    }
}

// ---------------- depthwise causal conv(4) + bias + SiLU (bf16 in/out) ----------------
#define CONV_L 16
__global__ __launch_bounds__(256) void conv_silu_k(
    const unsigned short* __restrict__ xzb, const float* __restrict__ cw,
    const float* __restrict__ cb, unsigned short* __restrict__ xsb)
{
  const int b = blockIdx.y;
  const int l0 = blockIdx.x * CONV_L;
  const int d = threadIdx.x * 8;
  float w[4][8], bias[8];
#pragma unroll
  for (int i = 0; i < 8; ++i) {
    bias[i] = cb[d + i];
#pragma unroll
    for (int j = 0; j < 4; ++j) w[j][i] = cw[(d + i) * 4 + j];
  }
  const size_t rb = (size_t)b * 4096;
  float win[3][8];
#pragma unroll
  for (int j = 0; j < 3; ++j) {
    int l = l0 - 3 + j;
    if (l >= 0) {
      u16x8 v = *(const u16x8*)(xzb + (rb + l) * 4096 + d);
#pragma unroll
      for (int i = 0; i < 8; ++i) win[j][i] = bf2f(v[i]);
    } else {
#pragma unroll
      for (int i = 0; i < 8; ++i) win[j][i] = 0.f;
    }
  }
  for (int l = l0; l < l0 + CONV_L; ++l) {
    u16x8 v = *(const u16x8*)(xzb + (rb + l) * 4096 + d);
    float cur[8]; u16x8 ob;
#pragma unroll
    for (int i = 0; i < 8; ++i) {
      cur[i] = bf2f(v[i]);
      float u = bias[i] + w[0][i] * win[0][i] + w[1][i] * win[1][i]
                        + w[2][i] * win[2][i] + w[3][i] * cur[i];
      float s = u / (1.f + __expf(-u));
      ob[i] = f2bf(s);
    }
    *(u16x8*)(xsb + (rb + l) * 2048 + d) = ob;
#pragma unroll
    for (int i = 0; i < 8; ++i) { win[0][i] = win[1][i]; win[1][i] = win[2][i]; win[2][i] = cur[i]; }
  }
}

// ---------------- chunk-parallel selective scan ----------------
// One THREAD per channel d; all 16 states in registers. No cross-lane ops.
// dA_n = exp(adn[n]*dlt); when adn[n] == -(n+1) (the tiled arange A_log),
// dA_n = r^(n+1), r = exp(-dlt): 1 transcendental + 17 muls per t.
__global__ __launch_bounds__(256) void scan_p1(
    const unsigned short* __restrict__ xsb16, const float* __restrict__ dbc,
    const float* __restrict__ dtw, const float* __restrict__ dtb,
    const float* __restrict__ alog,
    float* __restrict__ Sg, float* __restrict__ cdg)
{
  const int chunk = blockIdx.x;
  const int d0 = blockIdx.y * 256;
  const int b = blockIdx.z;
  const int tid = threadIdx.x;
  const size_t rowbase = (size_t)b * 4096 + chunk * TC;

  __shared__ __align__(16) unsigned short xsS[TC][256];  // 32 KiB
  __shared__ __align__(16) float bS[TC][16];             // 4 KiB
  __shared__ float drS[TC];                              // 256 B  -> 37.1 KiB, 4 blk/CU

  if (tid < TC) drS[tid] = dbc[(rowbase + tid) * 128];
  for (int i = tid; i < TC * 16; i += 256) {
    int t = i >> 4, q = i & 15;
    bS[t][q] = dbc[(rowbase + t) * 128 + 1 + q];
  }
  for (int i = tid; i < TC * 32; i += 256) {
    int t = i >> 5, q = i & 31;
    *(u16x8*)&xsS[t][q * 8] = *(const u16x8*)(xsb16 + (rowbase + t) * 2048 + d0 + q * 8);
  }
  __syncthreads();

  const int d = d0 + tid;
  const float wdt = dtw[d], bdt = dtb[d];
  float adn[16];
  bool ok = true;
#pragma unroll
  for (int k = 0; k < 4; ++k) {
    float4 a4 = *(const float4*)(alog + (size_t)d * 16 + k * 4);
    adn[4 * k + 0] = -__expf(a4.x); adn[4 * k + 1] = -__expf(a4.y);
    adn[4 * k + 2] = -__expf(a4.z); adn[4 * k + 3] = -__expf(a4.w);
  }
#pragma unroll
  for (int n = 0; n < 16; ++n)
    ok = ok && (fabsf(adn[n] + (float)(n + 1)) <= 1e-3f * (float)(n + 1));

  float h[16];
#pragma unroll
  for (int n = 0; n < 16; ++n) h[n] = 0.f;
  float cd = 0.f;

  if (ok) {
    for (int t = 0; t < TC; ++t) {
      float pre = fmaf(drS[t], wdt, bdt);
      float e = __expf(pre);
      float dlt = (pre > 20.f) ? pre : __logf(1.f + e);
      float xv = bf2f(xsS[t][tid]);
      float dx = dlt * xv;
      cd += dlt;
      float r = __expf(-dlt);
      float rp[16];
      rpowers(r, rp);
      f32x4 Bv[4];
#pragma unroll
      for (int k = 0; k < 4; ++k) Bv[k] = ((const f32x4*)&bS[t][0])[k];
#pragma unroll
      for (int n = 0; n < 16; ++n)
        h[n] = fmaf(rp[n], h[n], dx * Bv[n >> 2][n & 3]);
    }
  } else {
    for (int t = 0; t < TC; ++t) {
      float pre = fmaf(drS[t], wdt, bdt);
      float e = __expf(pre);
      float dlt = (pre > 20.f) ? pre : __logf(1.f + e);
      float xv = bf2f(xsS[t][tid]);
      float dx = dlt * xv;
      cd += dlt;
      f32x4 Bv[4];
#pragma unroll
      for (int k = 0; k < 4; ++k) Bv[k] = ((const f32x4*)&bS[t][0])[k];
#pragma unroll
      for (int n = 0; n < 16; ++n) {
        float dA = __expf(adn[n] * dlt);
        h[n] = fmaf(dA, h[n], dx * Bv[n >> 2][n & 3]);
      }
    }
  }
  cdg[(size_t)(b * NC + chunk) * 2048 + d] = cd;
  float* Sp = Sg + ((size_t)(b * NC + chunk) * 32768 + (size_t)d * 16);
#pragma unroll
  for (int k = 0; k < 4; ++k)
    ((float4*)Sp)[k] = make_float4(h[4 * k], h[4 * k + 1], h[4 * k + 2], h[4 * k + 3]);
}

// Phase 2: scan across chunks; Hg[c] = state entering chunk c. P recomputed from cd.
__global__ __launch_bounds__(256) void scan_p2(
    const float* __restrict__ Sg, const float* __restrict__ cdg,
    const float* __restrict__ alog, float* __restrict__ Hg)
{
  int g = blockIdx.x * 256 + threadIdx.x;   // 65536 = B*D*N
  int b = g >> 15, dn = g & 32767;
  int d = dn >> 4;
  float adn = -__expf(alog[dn]);
  float h = 0.f;
  for (int c = 0; c < NC; ++c) {
    size_t o = (size_t)(b * NC + c) * 32768 + dn;
    float P = __expf(adn * cdg[(size_t)(b * NC + c) * 2048 + d]);
    Hg[o] = h;
    h = fmaf(P, h, Sg[o]);
  }
}

// Phase 3: re-run local scan from true entry state, emit y, fuse gating.
// LDS exactly 40960 B -> 4 blocks/CU. delta_raw read per-t from global (L1-hot line).
__global__ __launch_bounds__(256) void scan_p3(
    const unsigned short* __restrict__ xsb16, const float* __restrict__ dbc,
    const float* __restrict__ dtw, const float* __restrict__ dtb,
    const float* __restrict__ alog, const float* __restrict__ Dp,
    const unsigned short* __restrict__ xzb, const float* __restrict__ Hg,
    unsigned short* __restrict__ gb)
{
  const int chunk = blockIdx.x;
  const int d0 = blockIdx.y * 256;
  const int b = blockIdx.z;
  const int tid = threadIdx.x;
  const size_t rowbase = (size_t)b * 4096 + chunk * TC;

  __shared__ __align__(16) unsigned short xsS[TC][256];  // 32 KiB
  __shared__ __align__(16) float bcS[TC][32];            // 8 KiB  -> 40960 B total

  for (int i = tid; i < TC * 32; i += 256) {
    int t = i >> 5, q = i & 31;
    bcS[t][q] = dbc[(rowbase + t) * 128 + 1 + q];
  }
  for (int i = tid; i < TC * 32; i += 256) {
    int t = i >> 5, q = i & 31;
    *(u16x8*)&xsS[t][q * 8] = *(const u16x8*)(xsb16 + (rowbase + t) * 2048 + d0 + q * 8);
  }
  __syncthreads();

  const int d = d0 + tid;
  const float wdt = dtw[d], bdt = dtb[d], Dd = Dp[d];
  const float* __restrict__ drp = dbc + rowbase * 128;
  float adn[16];
  bool ok = true;
#pragma unroll
  for (int k = 0; k < 4; ++k) {
    float4 a4 = *(const float4*)(alog + (size_t)d * 16 + k * 4);
    adn[4 * k + 0] = -__expf(a4.x); adn[4 * k + 1] = -__expf(a4.y);
    adn[4 * k + 2] = -__expf(a4.z); adn[4 * k + 3] = -__expf(a4.w);
  }
#pragma unroll
  for (int n = 0; n < 16; ++n)
    ok = ok && (fabsf(adn[n] + (float)(n + 1)) <= 1e-3f * (float)(n + 1));

  float h[16];
  {
    const float* Hp = Hg + ((size_t)(b * NC + chunk) * 32768 + (size_t)d * 16);
#pragma unroll
    for (int k = 0; k < 4; ++k) {
      float4 h4 = ((const float4*)Hp)[k];
      h[4 * k + 0] = h4.x; h[4 * k + 1] = h4.y; h[4 * k + 2] = h4.z; h[4 * k + 3] = h4.w;
    }
  }

  if (ok) {
    for (int t = 0; t < TC; ++t) {
      float pre = fmaf(drp[(size_t)t * 128], wdt, bdt);
      float e = __expf(pre);
      float dlt = (pre > 20.f) ? pre : __logf(1.f + e);
      float xv = bf2f(xsS[t][tid]);
      float dx = dlt * xv;
      float r = __expf(-dlt);
      float rp[16];
      rpowers(r, rp);
      f32x4 Bv[4], Cv[4];
#pragma unroll
      for (int k = 0; k < 4; ++k) {
        Bv[k] = ((const f32x4*)&bcS[t][0])[k];
        Cv[k] = ((const f32x4*)&bcS[t][16])[k];
      }
      float yp[4];
      yp[0] = Dd * xv; yp[1] = 0.f; yp[2] = 0.f; yp[3] = 0.f;
#pragma unroll
      for (int n = 0; n < 16; ++n) {
        h[n] = fmaf(rp[n], h[n], dx * Bv[n >> 2][n & 3]);
        yp[n & 3] = fmaf(h[n], Cv[n >> 2][n & 3], yp[n & 3]);
      }
      float y = (yp[0] + yp[1]) + (yp[2] + yp[3]);
      xsS[t][tid] = f2bf(y);
    }
  } else {
    for (int t = 0; t < TC; ++t) {
      float pre = fmaf(drp[(size_t)t * 128], wdt, bdt);
      float e = __expf(pre);
      float dlt = (pre > 20.f) ? pre : __logf(1.f + e);
      float xv = bf2f(xsS[t][tid]);
      float dx = dlt * xv;
      f32x4 Bv[4], Cv[4];
#pragma unroll
      for (int k = 0; k < 4; ++k) {
        Bv[k] = ((const f32x4*)&bcS[t][0])[k];
        Cv[k] = ((const f32x4*)&bcS[t][16])[k];
      }
      float yp[4];
      yp[0] = Dd * xv; yp[1] = 0.f; yp[2] = 0.f; yp[3] = 0.f;
#pragma unroll
      for (int n = 0; n < 16; ++n) {
        float dA = __expf(adn[n] * dlt);
        h[n] = fmaf(dA, h[n], dx * Bv[n >> 2][n & 3]);
        yp[n & 3] = fmaf(h[n], Cv[n >> 2][n & 3], yp[n & 3]);
      }
      float y = (yp[0] + yp[1]) + (yp[2] + yp[3]);
      xsS[t][tid] = f2bf(y);
    }
  }
  __syncthreads();

  for (int i = tid; i < TC * 32; i += 256) {
    int t = i >> 5, q = i & 31;
    u16x8 yv = *(const u16x8*)&xsS[t][q * 8];
    u16x8 zv = *(const u16x8*)(xzb + (rowbase + t) * 4096 + 2048 + d0 + q * 8);
    u16x8 ov;
#pragma unroll
    for (int j = 0; j < 8; ++j) {
      float z = bf2f(zv[j]);
      float s = z / (1.f + __expf(-z));
      ov[j] = f2bf(bf2f(yv[j]) * s);
    }
    *(u16x8*)(gb + (rowbase + t) * 2048 + d0 + q * 8) = ov;
  }
}

extern "C" void kernel_launch(void* const* d_in, const int* in_sizes, int n_in,
                              void* d_out, int out_size, void* d_ws, size_t ws_size,
                              hipStream_t stream) {
  const float* x    = (const float*)d_in[0];
  const float* ipw  = (const float*)d_in[1];
  const float* cw   = (const float*)d_in[2];
  const float* cb   = (const float*)d_in[3];
  const float* xpw  = (const float*)d_in[4];
  const float* dtw  = (const float*)d_in[5];
  const float* dtb  = (const float*)d_in[6];
  const float* alog = (const float*)d_in[7];
  const float* Dp   = (const float*)d_in[8];
  const float* opw  = (const float*)d_in[9];
  float* out = (float*)d_out;

  char* p = (char*)d_ws;
  unsigned short* xb   = (unsigned short*)p; p += (size_t)8388608 * 2;   // x bf16 (16 MiB) — reused as Hg
  unsigned short* wb1  = (unsigned short*)p; p += (size_t)4194304 * 2;   // in_proj_w bf16   (8 MiB)
  unsigned short* wb2  = (unsigned short*)p; p += (size_t)2097152 * 2;   // out_proj_w bf16  (4 MiB)
  unsigned short* xwp  = (unsigned short*)p; p += (size_t)262144 * 2;    // padded x_proj_w  (0.5 MiB)
  unsigned short* xzb  = (unsigned short*)p; p += (size_t)33554432 * 2;  // in_proj out bf16 (64 MiB)
  unsigned short* xsb16= (unsigned short*)p; p += (size_t)16777216 * 2;  // conv+silu bf16   (32 MiB)
  float*          dbc  = (float*)p;          p += (size_t)1048576 * 4;   // x_proj out fp32  (4 MiB)
  unsigned short* gb   = (unsigned short*)p; p += (size_t)16777216 * 2;  // y*silu(z) bf16   (32 MiB)
  float*          Sg   = (float*)p;          p += (size_t)4194304 * 4;   // chunk states     (16 MiB)
  float*          cdg  = (float*)p;          p += (size_t)262144 * 4;    // chunk decay sums (1 MiB)
  float*          Hg   = (float*)xb;                                     // chunk entry states (16 MiB, aliases xb)

  cast_bf16_k<<<1024, 256, 0, stream>>>((const float4*)x,   (ushort4*)xb,  8388608 / 4);
  cast_bf16_k<<<1024, 256, 0, stream>>>((const float4*)ipw, (ushort4*)wb1, 4194304 / 4);
  cast_bf16_k<<<512,  256, 0, stream>>>((const float4*)opw, (ushort4*)wb2, 2097152 / 4);
  pad_xw_k<<<1024, 256, 0, stream>>>(xpw, xwp);

  gemm_bf16_nt<true ><<<dim3(64, 32), 256, 0, stream>>>(xb, wb1, xzb, 8192, 4096, 1024);
  conv_silu_k<<<dim3(4096 / CONV_L, 2), 256, 0, stream>>>(xzb, cw, cb, xsb16);
  gemm_bf16_nt<false><<<dim3(64, 1), 256, 0, stream>>>(xsb16, xwp, dbc, 8192, 128, 2048);

  scan_p1<<<dim3(NC, 8, 2), 256, 0, stream>>>(xsb16, dbc, dtw, dtb, alog, Sg, cdg);
  scan_p2<<<256, 256, 0, stream>>>(Sg, cdg, alog, Hg);
  scan_p3<<<dim3(NC, 8, 2), 256, 0, stream>>>(xsb16, dbc, dtw, dtb, alog, Dp, xzb, Hg, gb);

  gemm_bf16_nt<false><<<dim3(64, 8), 256, 0, stream>>>(gb, wb2, out, 8192, 1024, 2048);
}

// Round 6
// 320.911 us; speedup vs baseline: 7.2650x; 1.0650x over previous
//
#include <hip/hip_runtime.h>
#include <hip/hip_bf16.h>
#include <stdint.h>

typedef __bf16 bf16x8 __attribute__((ext_vector_type(8)));
typedef float  f32x4  __attribute__((ext_vector_type(4)));
typedef unsigned short u16x8 __attribute__((ext_vector_type(8)));

#define TC 64   // timesteps per chunk
#define NC 64   // chunks (TC*NC == 4096)
#define TH 32   // staged half

__device__ __forceinline__ unsigned short f2bf(float f) {
  unsigned u = __builtin_bit_cast(unsigned, f);
  unsigned r = (u + 0x7fffu + ((u >> 16) & 1u)) >> 16;
  return (unsigned short)r;
}
__device__ __forceinline__ float bf2f(unsigned short s) {
  unsigned u = ((unsigned)s) << 16;
  return __builtin_bit_cast(float, u);
}

__device__ __forceinline__ void gload_lds16(const void* g, void* l) {
  __builtin_amdgcn_global_load_lds(
      (const __attribute__((address_space(1))) unsigned int*)(g),
      (__attribute__((address_space(3))) unsigned int*)(l),
      16, 0, 0);
}

// rp[k] = r^(k+1), k=0..15, via full-rate mul tree (depth <= 4)
__device__ __forceinline__ void rpowers(float r, float* rp) {
  float r2 = r * r, r4 = r2 * r2, r8 = r4 * r4;
  rp[0] = r;        rp[1] = r2;       rp[2] = r2 * r;   rp[3] = r4;
  rp[4] = r4 * r;   rp[5] = r4 * r2;  rp[6] = rp[5] * r; rp[7] = r8;
  rp[8] = r8 * r;   rp[9] = r8 * r2;  rp[10] = rp[9] * r; rp[11] = r8 * r4;
  rp[12] = rp[11] * r; rp[13] = rp[11] * r2; rp[14] = rp[13] * r; rp[15] = r8 * r8;
}

// ---------------- cast fp32 -> bf16 (vectorized) ----------------
__global__ __launch_bounds__(256) void cast_bf16_k(const float4* __restrict__ in,
                                                   ushort4* __restrict__ out, int n4) {
  int i = blockIdx.x * 256 + threadIdx.x;
  int stride = gridDim.x * 256;
  for (; i < n4; i += stride) {
    float4 v = in[i];
    ushort4 o;
    o.x = f2bf(v.x); o.y = f2bf(v.y); o.z = f2bf(v.z); o.w = f2bf(v.w);
    out[i] = o;
  }
}

// ---------------- pad+cast x_proj_w (33x2048) -> (128x2048) bf16 ----------------
__global__ __launch_bounds__(256) void pad_xw_k(const float* __restrict__ xw,
                                                unsigned short* __restrict__ xwp) {
  int i = blockIdx.x * 256 + threadIdx.x;   // grid covers 128*2048
  if (i >= 128 * 2048) return;
  int row = i >> 11, col = i & 2047;
  xwp[i] = (row < 33) ? f2bf(xw[row * 2048 + col]) : (unsigned short)0;
}

// ---------------- bf16 MFMA GEMM: C[M][N] = A[M][K] * B[N][K]^T ----------------
template <bool BF16OUT>
__global__ __launch_bounds__(256) void gemm_bf16_nt(
    const unsigned short* __restrict__ A, const unsigned short* __restrict__ B,
    void* __restrict__ Cv, int M, int N, int K)
{
  __shared__ __align__(16) unsigned short As[128 * 32];
  __shared__ __align__(16) unsigned short Bs[128 * 32];
  const int tid = threadIdx.x;
  const int m0 = blockIdx.x * 128;
  const int n0 = blockIdx.y * 128;
  const int w = tid >> 6, l = tid & 63;
  const int wr = w >> 1, wc = w & 1;
  const int lr = l & 15, kk = (l >> 4) * 8;

  f32x4 acc[4][4];
#pragma unroll
  for (int mi = 0; mi < 4; ++mi)
#pragma unroll
    for (int ni = 0; ni < 4; ++ni)
      acc[mi][ni] = (f32x4){0.f, 0.f, 0.f, 0.f};

  for (int k0 = 0; k0 < K; k0 += 32) {
#pragma unroll
    for (int i = 0; i < 2; ++i) {
      int q = tid + 256 * i;
      int row = q >> 2, sub = q & 3;
      gload_lds16(A + (size_t)(m0 + row) * K + k0 + sub * 8, &As[q * 8]);
      gload_lds16(B + (size_t)(n0 + row) * K + k0 + sub * 8, &Bs[q * 8]);
    }
    __syncthreads();
    bf16x8 af[4], bfr[4];
#pragma unroll
    for (int mi = 0; mi < 4; ++mi)
      af[mi] = *(const bf16x8*)&As[(wr * 64 + mi * 16 + lr) * 32 + kk];
#pragma unroll
    for (int ni = 0; ni < 4; ++ni)
      bfr[ni] = *(const bf16x8*)&Bs[(wc * 64 + ni * 16 + lr) * 32 + kk];
#pragma unroll
    for (int mi = 0; mi < 4; ++mi)
#pragma unroll
      for (int ni = 0; ni < 4; ++ni)
        acc[mi][ni] = __builtin_amdgcn_mfma_f32_16x16x32_bf16(af[mi], bfr[ni], acc[mi][ni], 0, 0, 0);
    __syncthreads();
  }

#pragma unroll
  for (int mi = 0; mi < 4; ++mi)
#pragma unroll
    for (int ni = 0; ni < 4; ++ni) {
      int gr = m0 + wr * 64 + mi * 16 + (l >> 4) * 4;
      int gc = n0 + wc * 64 + ni * 16 + (l & 15);
#pragma unroll
      for (int j = 0; j < 4; ++j) {
        if (BF16OUT)
          ((unsigned short*)Cv)[(size_t)(gr + j) * N + gc] = f2bf(acc[mi][ni][j]);
        else
          ((float*)Cv)[(size_t)(gr + j) * N + gc] = acc[mi][ni][j];
      }
    }
}

// ---------------- split-K GEMM for the skinny x_proj (N=128): partial buffers ----------------
#define KSPLIT 4
__global__ __launch_bounds__(256) void gemm_bf16_splitk(
    const unsigned short* __restrict__ A, const unsigned short* __restrict__ B,
    float* __restrict__ Cpart, int M, int N, int K)
{
  __shared__ __align__(16) unsigned short As[128 * 32];
  __shared__ __align__(16) unsigned short Bs[128 * 32];
  const int tid = threadIdx.x;
  const int m0 = blockIdx.x * 128;
  const int n0 = 0;
  const int z = blockIdx.z;
  const int kseg = K / KSPLIT;
  const int kbeg = z * kseg;
  const int w = tid >> 6, l = tid & 63;
  const int wr = w >> 1, wc = w & 1;
  const int lr = l & 15, kk = (l >> 4) * 8;
  float* C = Cpart + (size_t)z * M * N;

  f32x4 acc[4][4];
#pragma unroll
  for (int mi = 0; mi < 4; ++mi)
#pragma unroll
    for (int ni = 0; ni < 4; ++ni)
      acc[mi][ni] = (f32x4){0.f, 0.f, 0.f, 0.f};

  for (int k0 = kbeg; k0 < kbeg + kseg; k0 += 32) {
#pragma unroll
    for (int i = 0; i < 2; ++i) {
      int q = tid + 256 * i;
      int row = q >> 2, sub = q & 3;
      gload_lds16(A + (size_t)(m0 + row) * K + k0 + sub * 8, &As[q * 8]);
      gload_lds16(B + (size_t)(n0 + row) * K + k0 + sub * 8, &Bs[q * 8]);
    }
    __syncthreads();
    bf16x8 af[4], bfr[4];
#pragma unroll
    for (int mi = 0; mi < 4; ++mi)
      af[mi] = *(const bf16x8*)&As[(wr * 64 + mi * 16 + lr) * 32 + kk];
#pragma unroll
    for (int ni = 0; ni < 4; ++ni)
      bfr[ni] = *(const bf16x8*)&Bs[(wc * 64 + ni * 16 + lr) * 32 + kk];
#pragma unroll
    for (int mi = 0; mi < 4; ++mi)
#pragma unroll
      for (int ni = 0; ni < 4; ++ni)
        acc[mi][ni] = __builtin_amdgcn_mfma_f32_16x16x32_bf16(af[mi], bfr[ni], acc[mi][ni], 0, 0, 0);
    __syncthreads();
  }

#pragma unroll
  for (int mi = 0; mi < 4; ++mi)
#pragma unroll
    for (int ni = 0; ni < 4; ++ni) {
      int gr = m0 + wr * 64 + mi * 16 + (l >> 4) * 4;
      int gc = n0 + wc * 64 + ni * 16 + (l & 15);
#pragma unroll
      for (int j = 0; j < 4; ++j)
        C[(size_t)(gr + j) * N + gc] = acc[mi][ni][j];
    }
}

// reduce 4 partial C buffers -> dbc (1M floats, float4)
__global__ __launch_bounds__(256) void redux4_k(const float4* __restrict__ part,
                                                float4* __restrict__ out) {
  int i = blockIdx.x * 256 + threadIdx.x;   // 262144 float4
  const int STR = 262144;
  float4 a = part[i], b = part[i + STR], c = part[i + 2 * STR], d = part[i + 3 * STR];
  out[i] = make_float4(a.x + b.x + c.x + d.x, a.y + b.y + c.y + d.y,
                       a.z + b.z + c.z + d.z, a.w + b.w + c.w + d.w);
}

// ---------------- depthwise causal conv(4) + bias + SiLU (bf16 in/out) ----------------
#define CONV_L 16
__global__ __launch_bounds__(256) void conv_silu_k(
    const unsigned short* __restrict__ xzb, const float* __restrict__ cw,
    const float* __restrict__ cb, unsigned short* __restrict__ xsb)
{
  const int b = blockIdx.y;
  const int l0 = blockIdx.x * CONV_L;
  const int d = threadIdx.x * 8;
  float w[4][8], bias[8];
#pragma unroll
  for (int i = 0; i < 8; ++i) {
    bias[i] = cb[d + i];
#pragma unroll
    for (int j = 0; j < 4; ++j) w[j][i] = cw[(d + i) * 4 + j];
  }
  const size_t rb = (size_t)b * 4096;
  float win[3][8];
#pragma unroll
  for (int j = 0; j < 3; ++j) {
    int l = l0 - 3 + j;
    if (l >= 0) {
      u16x8 v = *(const u16x8*)(xzb + (rb + l) * 4096 + d);
#pragma unroll
      for (int i = 0; i < 8; ++i) win[j][i] = bf2f(v[i]);
    } else {
#pragma unroll
      for (int i = 0; i < 8; ++i) win[j][i] = 0.f;
    }
  }
  for (int l = l0; l < l0 + CONV_L; ++l) {
    u16x8 v = *(const u16x8*)(xzb + (rb + l) * 4096 + d);
    float cur[8]; u16x8 ob;
#pragma unroll
    for (int i = 0; i < 8; ++i) {
      cur[i] = bf2f(v[i]);
      float u = bias[i] + w[0][i] * win[0][i] + w[1][i] * win[1][i]
                        + w[2][i] * win[2][i] + w[3][i] * cur[i];
      float s = u / (1.f + __expf(-u));
      ob[i] = f2bf(s);
    }
    *(u16x8*)(xsb + (rb + l) * 2048 + d) = ob;
#pragma unroll
    for (int i = 0; i < 8; ++i) { win[0][i] = win[1][i]; win[1][i] = win[2][i]; win[2][i] = cur[i]; }
  }
}

// ---------------- chunk-parallel selective scan ----------------
// One THREAD per channel d; all 16 states in registers. xs staged in 32-row halves
// (ping-pong) to keep LDS small -> 4 blocks/CU resident.
__global__ __launch_bounds__(256) void scan_p1(
    const unsigned short* __restrict__ xsb16, const float* __restrict__ dbc,
    const float* __restrict__ dtw, const float* __restrict__ dtb,
    const float* __restrict__ alog,
    float* __restrict__ Sg, float* __restrict__ cdg)
{
  const int chunk = blockIdx.x;
  const int d0 = blockIdx.y * 256;
  const int b = blockIdx.z;
  const int tid = threadIdx.x;
  const size_t rowbase = (size_t)b * 4096 + chunk * TC;

  __shared__ __align__(16) unsigned short xsS[TH][256];  // 16 KiB
  __shared__ __align__(16) float bS[TC][16];             // 4 KiB
  __shared__ float drS[TC];                              // 256 B

  if (tid < TC) drS[tid] = dbc[(rowbase + tid) * 128];
  for (int i = tid; i < TC * 16; i += 256) {
    int t = i >> 4, q = i & 15;
    bS[t][q] = dbc[(rowbase + t) * 128 + 1 + q];
  }

  const int d = d0 + tid;
  const float wdt = dtw[d], bdt = dtb[d];
  float adn[16];
  bool ok = true;
#pragma unroll
  for (int k = 0; k < 4; ++k) {
    float4 a4 = *(const float4*)(alog + (size_t)d * 16 + k * 4);
    adn[4 * k + 0] = -__expf(a4.x); adn[4 * k + 1] = -__expf(a4.y);
    adn[4 * k + 2] = -__expf(a4.z); adn[4 * k + 3] = -__expf(a4.w);
  }
#pragma unroll
  for (int n = 0; n < 16; ++n)
    ok = ok && (fabsf(adn[n] + (float)(n + 1)) <= 1e-3f * (float)(n + 1));

  float h[16];
#pragma unroll
  for (int n = 0; n < 16; ++n) h[n] = 0.f;
  float cd = 0.f;

  for (int half = 0; half < 2; ++half) {
    if (half) __syncthreads();   // previous half's compute done before overwrite
    for (int i = tid; i < TH * 32; i += 256) {
      int tt = i >> 5, q = i & 31;
      *(u16x8*)&xsS[tt][q * 8] =
          *(const u16x8*)(xsb16 + (rowbase + half * TH + tt) * 2048 + d0 + q * 8);
    }
    __syncthreads();

    if (ok) {
      for (int tt = 0; tt < TH; ++tt) {
        int t = half * TH + tt;
        float pre = fmaf(drS[t], wdt, bdt);
        float e = __expf(pre);
        float dlt = (pre > 20.f) ? pre : __logf(1.f + e);
        float xv = bf2f(xsS[tt][tid]);
        float dx = dlt * xv;
        cd += dlt;
        float r = __expf(-dlt);
        float rp[16];
        rpowers(r, rp);
        f32x4 Bv[4];
#pragma unroll
        for (int k = 0; k < 4; ++k) Bv[k] = ((const f32x4*)&bS[t][0])[k];
#pragma unroll
        for (int n = 0; n < 16; ++n)
          h[n] = fmaf(rp[n], h[n], dx * Bv[n >> 2][n & 3]);
      }
    } else {
      for (int tt = 0; tt < TH; ++tt) {
        int t = half * TH + tt;
        float pre = fmaf(drS[t], wdt, bdt);
        float e = __expf(pre);
        float dlt = (pre > 20.f) ? pre : __logf(1.f + e);
        float xv = bf2f(xsS[tt][tid]);
        float dx = dlt * xv;
        cd += dlt;
        f32x4 Bv[4];
#pragma unroll
        for (int k = 0; k < 4; ++k) Bv[k] = ((const f32x4*)&bS[t][0])[k];
#pragma unroll
        for (int n = 0; n < 16; ++n) {
          float dA = __expf(adn[n] * dlt);
          h[n] = fmaf(dA, h[n], dx * Bv[n >> 2][n & 3]);
        }
      }
    }
  }
  cdg[(size_t)(b * NC + chunk) * 2048 + d] = cd;
  float* Sp = Sg + ((size_t)(b * NC + chunk) * 32768 + (size_t)d * 16);
#pragma unroll
  for (int k = 0; k < 4; ++k)
    ((float4*)Sp)[k] = make_float4(h[4 * k], h[4 * k + 1], h[4 * k + 2], h[4 * k + 3]);
}

// Phase 2: scan across chunks; Hg[c] = state entering chunk c. P recomputed from cd.
__global__ __launch_bounds__(256) void scan_p2(
    const float* __restrict__ Sg, const float* __restrict__ cdg,
    const float* __restrict__ alog, float* __restrict__ Hg)
{
  int g = blockIdx.x * 256 + threadIdx.x;   // 65536 = B*D*N
  int b = g >> 15, dn = g & 32767;
  int d = dn >> 4;
  float adn = -__expf(alog[dn]);
  float h = 0.f;
  for (int c = 0; c < NC; ++c) {
    size_t o = (size_t)(b * NC + c) * 32768 + dn;
    float P = __expf(adn * cdg[(size_t)(b * NC + c) * 2048 + d]);
    Hg[o] = h;
    h = fmaf(P, h, Sg[o]);
  }
}

// Phase 3: re-run local scan from true entry state, emit y, fuse gating.
// xs staged in halves; y written back into the staged tile then gated+stored per half.
__global__ __launch_bounds__(256) void scan_p3(
    const unsigned short* __restrict__ xsb16, const float* __restrict__ dbc,
    const float* __restrict__ dtw, const float* __restrict__ dtb,
    const float* __restrict__ alog, const float* __restrict__ Dp,
    const unsigned short* __restrict__ xzb, const float* __restrict__ Hg,
    unsigned short* __restrict__ gb)
{
  const int chunk = blockIdx.x;
  const int d0 = blockIdx.y * 256;
  const int b = blockIdx.z;
  const int tid = threadIdx.x;
  const size_t rowbase = (size_t)b * 4096 + chunk * TC;

  __shared__ __align__(16) unsigned short xsS[TH][256];  // 16 KiB
  __shared__ __align__(16) float bcS[TC][32];            // 8 KiB

  for (int i = tid; i < TC * 32; i += 256) {
    int t = i >> 5, q = i & 31;
    bcS[t][q] = dbc[(rowbase + t) * 128 + 1 + q];
  }

  const int d = d0 + tid;
  const float wdt = dtw[d], bdt = dtb[d], Dd = Dp[d];
  const float* __restrict__ drp = dbc + rowbase * 128;
  float adn[16];
  bool ok = true;
#pragma unroll
  for (int k = 0; k < 4; ++k) {
    float4 a4 = *(const float4*)(alog + (size_t)d * 16 + k * 4);
    adn[4 * k + 0] = -__expf(a4.x); adn[4 * k + 1] = -__expf(a4.y);
    adn[4 * k + 2] = -__expf(a4.z); adn[4 * k + 3] = -__expf(a4.w);
  }
#pragma unroll
  for (int n = 0; n < 16; ++n)
    ok = ok && (fabsf(adn[n] + (float)(n + 1)) <= 1e-3f * (float)(n + 1));

  float h[16];
  {
    const float* Hp = Hg + ((size_t)(b * NC + chunk) * 32768 + (size_t)d * 16);
#pragma unroll
    for (int k = 0; k < 4; ++k) {
      float4 h4 = ((const float4*)Hp)[k];
      h[4 * k + 0] = h4.x; h[4 * k + 1] = h4.y; h[4 * k + 2] = h4.z; h[4 * k + 3] = h4.w;
    }
  }

  for (int half = 0; half < 2; ++half) {
    if (half) __syncthreads();   // previous half's gate-store done before overwrite
    for (int i = tid; i < TH * 32; i += 256) {
      int tt = i >> 5, q = i & 31;
      *(u16x8*)&xsS[tt][q * 8] =
          *(const u16x8*)(xsb16 + (rowbase + half * TH + tt) * 2048 + d0 + q * 8);
    }
    __syncthreads();

    if (ok) {
      for (int tt = 0; tt < TH; ++tt) {
        int t = half * TH + tt;
        float pre = fmaf(drp[(size_t)t * 128], wdt, bdt);
        float e = __expf(pre);
        float dlt = (pre > 20.f) ? pre : __logf(1.f + e);
        float xv = bf2f(xsS[tt][tid]);
        float dx = dlt * xv;
        float r = __expf(-dlt);
        float rp[16];
        rpowers(r, rp);
        f32x4 Bv[4], Cv[4];
#pragma unroll
        for (int k = 0; k < 4; ++k) {
          Bv[k] = ((const f32x4*)&bcS[t][0])[k];
          Cv[k] = ((const f32x4*)&bcS[t][16])[k];
        }
        float yp[4];
        yp[0] = Dd * xv; yp[1] = 0.f; yp[2] = 0.f; yp[3] = 0.f;
#pragma unroll
        for (int n = 0; n < 16; ++n) {
          h[n] = fmaf(rp[n], h[n], dx * Bv[n >> 2][n & 3]);
          yp[n & 3] = fmaf(h[n], Cv[n >> 2][n & 3], yp[n & 3]);
        }
        float y = (yp[0] + yp[1]) + (yp[2] + yp[3]);
        xsS[tt][tid] = f2bf(y);
      }
    } else {
      for (int tt = 0; tt < TH; ++tt) {
        int t = half * TH + tt;
        float pre = fmaf(drp[(size_t)t * 128], wdt, bdt);
        float e = __expf(pre);
        float dlt = (pre > 20.f) ? pre : __logf(1.f + e);
        float xv = bf2f(xsS[tt][tid]);
        float dx = dlt * xv;
        f32x4 Bv[4], Cv[4];
#pragma unroll
        for (int k = 0; k < 4; ++k) {
          Bv[k] = ((const f32x4*)&bcS[t][0])[k];
          Cv[k] = ((const f32x4*)&bcS[t][16])[k];
        }
        float yp[4];
        yp[0] = Dd * xv; yp[1] = 0.f; yp[2] = 0.f; yp[3] = 0.f;
#pragma unroll
        for (int n = 0; n < 16; ++n) {
          float dA = __expf(adn[n] * dlt);
          h[n] = fmaf(dA, h[n], dx * Bv[n >> 2][n & 3]);
          yp[n & 3] = fmaf(h[n], Cv[n >> 2][n & 3], yp[n & 3]);
        }
        float y = (yp[0] + yp[1]) + (yp[2] + yp[3]);
        xsS[tt][tid] = f2bf(y);
      }
    }
    __syncthreads();

    for (int i = tid; i < TH * 32; i += 256) {
      int tt = i >> 5, q = i & 31;
      size_t row = rowbase + half * TH + tt;
      u16x8 yv = *(const u16x8*)&xsS[tt][q * 8];
      u16x8 zv = *(const u16x8*)(xzb + row * 4096 + 2048 + d0 + q * 8);
      u16x8 ov;
#pragma unroll
      for (int j = 0; j < 8; ++j) {
        float z = bf2f(zv[j]);
        float s = z / (1.f + __expf(-z));
        ov[j] = f2bf(bf2f(yv[j]) * s);
      }
      *(u16x8*)(gb + row * 2048 + d0 + q * 8) = ov;
    }
  }
}

extern "C" void kernel_launch(void* const* d_in, const int* in_sizes, int n_in,
                              void* d_out, int out_size, void* d_ws, size_t ws_size,
                              hipStream_t stream) {
  const float* x    = (const float*)d_in[0];
  const float* ipw  = (const float*)d_in[1];
  const float* cw   = (const float*)d_in[2];
  const float* cb   = (const float*)d_in[3];
  const float* xpw  = (const float*)d_in[4];
  const float* dtw  = (const float*)d_in[5];
  const float* dtb  = (const float*)d_in[6];
  const float* alog = (const float*)d_in[7];
  const float* Dp   = (const float*)d_in[8];
  const float* opw  = (const float*)d_in[9];
  float* out = (float*)d_out;

  char* p = (char*)d_ws;
  unsigned short* xb   = (unsigned short*)p; p += (size_t)8388608 * 2;   // x bf16 (16 MiB) — reused as Hg
  unsigned short* wb1  = (unsigned short*)p; p += (size_t)4194304 * 2;   // in_proj_w bf16   (8 MiB)
  unsigned short* wb2  = (unsigned short*)p; p += (size_t)2097152 * 2;   // out_proj_w bf16  (4 MiB)
  unsigned short* xwp  = (unsigned short*)p; p += (size_t)262144 * 2;    // padded x_proj_w  (0.5 MiB)
  unsigned short* xzb  = (unsigned short*)p; p += (size_t)33554432 * 2;  // in_proj out bf16 (64 MiB)
  unsigned short* xsb16= (unsigned short*)p; p += (size_t)16777216 * 2;  // conv+silu bf16   (32 MiB)
  float*          dbc  = (float*)p;          p += (size_t)1048576 * 4;   // x_proj out fp32  (4 MiB)
  unsigned short* gb   = (unsigned short*)p; p += (size_t)16777216 * 2;  // y*silu(z) bf16   (32 MiB)
  float*          Sg   = (float*)p;          p += (size_t)4194304 * 4;   // chunk states     (16 MiB)
  float*          cdg  = (float*)p;          p += (size_t)262144 * 4;    // chunk decay sums (1 MiB)
  float*          Hg   = (float*)xb;                                     // chunk entry states (aliases xb)
  float*          dbcp = Sg;                                             // 4 split-K partials (alias Sg, dead until scan_p1)

  cast_bf16_k<<<1024, 256, 0, stream>>>((const float4*)x,   (ushort4*)xb,  8388608 / 4);
  cast_bf16_k<<<1024, 256, 0, stream>>>((const float4*)ipw, (ushort4*)wb1, 4194304 / 4);
  cast_bf16_k<<<512,  256, 0, stream>>>((const float4*)opw, (ushort4*)wb2, 2097152 / 4);
  pad_xw_k<<<1024, 256, 0, stream>>>(xpw, xwp);

  gemm_bf16_nt<true ><<<dim3(64, 32), 256, 0, stream>>>(xb, wb1, xzb, 8192, 4096, 1024);
  conv_silu_k<<<dim3(4096 / CONV_L, 2), 256, 0, stream>>>(xzb, cw, cb, xsb16);

  gemm_bf16_splitk<<<dim3(64, 1, KSPLIT), 256, 0, stream>>>(xsb16, xwp, dbcp, 8192, 128, 2048);
  redux4_k<<<1024, 256, 0, stream>>>((const float4*)dbcp, (float4*)dbc);

  scan_p1<<<dim3(NC, 8, 2), 256, 0, stream>>>(xsb16, dbc, dtw, dtb, alog, Sg, cdg);
  scan_p2<<<256, 256, 0, stream>>>(Sg, cdg, alog, Hg);
  scan_p3<<<dim3(NC, 8, 2), 256, 0, stream>>>(xsb16, dbc, dtw, dtb, alog, Dp, xzb, Hg, gb);

  gemm_bf16_nt<false><<<dim3(64, 8), 256, 0, stream>>>(gb, wb2, out, 8192, 1024, 2048);
}

// Round 7
// 310.499 us; speedup vs baseline: 7.5086x; 1.0335x over previous
//
#include <hip/hip_runtime.h>
#include <hip/hip_bf16.h>
#include <stdint.h>

typedef __bf16 bf16x8 __attribute__((ext_vector_type(8)));
typedef float  f32x4  __attribute__((ext_vector_type(4)));
typedef unsigned short u16x8 __attribute__((ext_vector_type(8)));

#define TC 64   // timesteps per chunk
#define NC 64   // chunks (TC*NC == 4096)
#define TH 32   // staged half

__device__ __forceinline__ unsigned short f2bf(float f) {
  unsigned u = __builtin_bit_cast(unsigned, f);
  unsigned r = (u + 0x7fffu + ((u >> 16) & 1u)) >> 16;
  return (unsigned short)r;
}
__device__ __forceinline__ float bf2f(unsigned short s) {
  unsigned u = ((unsigned)s) << 16;
  return __builtin_bit_cast(float, u);
}

__device__ __forceinline__ void gload_lds16(const void* g, void* l) {
  __builtin_amdgcn_global_load_lds(
      (const __attribute__((address_space(1))) unsigned int*)(g),
      (__attribute__((address_space(3))) unsigned int*)(l),
      16, 0, 0);
}

// rp[k] = r^(k+1), k=0..15, via full-rate mul tree (depth <= 4)
__device__ __forceinline__ void rpowers(float r, float* rp) {
  float r2 = r * r, r4 = r2 * r2, r8 = r4 * r4;
  rp[0] = r;        rp[1] = r2;       rp[2] = r2 * r;   rp[3] = r4;
  rp[4] = r4 * r;   rp[5] = r4 * r2;  rp[6] = rp[5] * r; rp[7] = r8;
  rp[8] = r8 * r;   rp[9] = r8 * r2;  rp[10] = rp[9] * r; rp[11] = r8 * r4;
  rp[12] = rp[11] * r; rp[13] = rp[11] * r2; rp[14] = rp[13] * r; rp[15] = r8 * r8;
}

// ---------------- cast fp32 -> bf16 (vectorized) ----------------
__global__ __launch_bounds__(256) void cast_bf16_k(const float4* __restrict__ in,
                                                   ushort4* __restrict__ out, int n4) {
  int i = blockIdx.x * 256 + threadIdx.x;
  int stride = gridDim.x * 256;
  for (; i < n4; i += stride) {
    float4 v = in[i];
    ushort4 o;
    o.x = f2bf(v.x); o.y = f2bf(v.y); o.z = f2bf(v.z); o.w = f2bf(v.w);
    out[i] = o;
  }
}

// ---------------- pad+cast x_proj_w (33x2048) -> (128x2048) bf16 ----------------
__global__ __launch_bounds__(256) void pad_xw_k(const float* __restrict__ xw,
                                                unsigned short* __restrict__ xwp) {
  int i = blockIdx.x * 256 + threadIdx.x;   // grid covers 128*2048
  if (i >= 128 * 2048) return;
  int row = i >> 11, col = i & 2047;
  xwp[i] = (row < 33) ? f2bf(xw[row * 2048 + col]) : (unsigned short)0;
}

// ---------------- bf16 MFMA GEMM: C[M][N] = A[M][K] * B[N][K]^T ----------------
// 128x128 tile, BK=32, triple-buffered LDS pipeline (prefetch distance 2),
// counted vmcnt(4) + raw s_barrier (loads stay in flight across barriers).
// XCD-bijective swizzle + GROUP_M grouping for L2 panel reuse.
// gridDim.z>1 => split-K: z-slice writes fp32 partials at Cv + z*M*N.
template <bool BF16OUT, bool SWZ>
__global__ __launch_bounds__(256) void gemm2p(
    const unsigned short* __restrict__ A, const unsigned short* __restrict__ B,
    void* __restrict__ Cv, int M, int N, int K)
{
  __shared__ __align__(16) unsigned short AsB[3 * 128 * 32];
  __shared__ __align__(16) unsigned short BsB[3 * 128 * 32];
  const int tid = threadIdx.x;

  // ---- block -> (m0, n0) mapping ----
  const int grid_m = M >> 7, grid_n = N >> 7;
  const int nwg = grid_m * grid_n;
  int wid = blockIdx.x;
  if (SWZ) { int q = nwg >> 3; wid = (wid & 7) * q + (wid >> 3); }  // nwg % 8 == 0
  const int GM = 16;
  const int nig = GM * grid_n;
  const int gidg = wid / nig;
  const int rem = wid - gidg * nig;
  const int fm = gidg * GM;
  const int gsz = min(grid_m - fm, GM);
  const int pm = fm + rem % gsz;
  const int pn = rem / gsz;
  const int m0 = pm << 7, n0 = pn << 7;

  // ---- K range (split-K via z) ----
  const int kseg = K / gridDim.z;
  const int kbeg = blockIdx.z * kseg;
  const int NT = kseg >> 5;   // K-tiles of 32

  const int w = tid >> 6, l = tid & 63;
  const int wr = w >> 1, wc = w & 1;
  const int lr = l & 15, kk = (l >> 4) * 8;

  f32x4 acc[4][4];
#pragma unroll
  for (int mi = 0; mi < 4; ++mi)
#pragma unroll
    for (int ni = 0; ni < 4; ++ni)
      acc[mi][ni] = (f32x4){0.f, 0.f, 0.f, 0.f};

  // ---- prologue: stage tiles 0 and 1 ----
#pragma unroll
  for (int tt = 0; tt < 2; ++tt) {
    unsigned short* as = AsB + tt * 4096;
    unsigned short* bs = BsB + tt * 4096;
    int k0 = kbeg + tt * 32;
#pragma unroll
    for (int i = 0; i < 2; ++i) {
      int q = tid + 256 * i;
      int row = q >> 2, sub = q & 3;
      gload_lds16(A + (size_t)(m0 + row) * K + k0 + sub * 8, as + q * 8);
      gload_lds16(B + (size_t)(n0 + row) * K + k0 + sub * 8, bs + q * 8);
    }
  }
  asm volatile("s_waitcnt vmcnt(4)\n\ts_barrier" ::: "memory");  // tile0 ready

  // ---- main loop ----
  for (int t = 0; t < NT; ++t) {
    if (t + 2 < NT) {
      unsigned short* as = AsB + ((t + 2) % 3) * 4096;
      unsigned short* bs = BsB + ((t + 2) % 3) * 4096;
      int k0 = kbeg + (t + 2) * 32;
#pragma unroll
      for (int i = 0; i < 2; ++i) {
        int q = tid + 256 * i;
        int row = q >> 2, sub = q & 3;
        gload_lds16(A + (size_t)(m0 + row) * K + k0 + sub * 8, as + q * 8);
        gload_lds16(B + (size_t)(n0 + row) * K + k0 + sub * 8, bs + q * 8);
      }
    }
    const unsigned short* as = AsB + (t % 3) * 4096;
    const unsigned short* bs = BsB + (t % 3) * 4096;
    bf16x8 af[4], bfr[4];
#pragma unroll
    for (int mi = 0; mi < 4; ++mi)
      af[mi] = *(const bf16x8*)&as[(wr * 64 + mi * 16 + lr) * 32 + kk];
#pragma unroll
    for (int ni = 0; ni < 4; ++ni)
      bfr[ni] = *(const bf16x8*)&bs[(wc * 64 + ni * 16 + lr) * 32 + kk];
#pragma unroll
    for (int mi = 0; mi < 4; ++mi)
#pragma unroll
      for (int ni = 0; ni < 4; ++ni)
        acc[mi][ni] = __builtin_amdgcn_mfma_f32_16x16x32_bf16(af[mi], bfr[ni], acc[mi][ni], 0, 0, 0);
    if (t + 1 < NT) {
      if (t + 2 < NT) asm volatile("s_waitcnt vmcnt(4)\n\ts_barrier" ::: "memory");
      else            asm volatile("s_waitcnt vmcnt(0)\n\ts_barrier" ::: "memory");
    }
  }

  // ---- epilogue ----
#pragma unroll
  for (int mi = 0; mi < 4; ++mi)
#pragma unroll
    for (int ni = 0; ni < 4; ++ni) {
      int gr = m0 + wr * 64 + mi * 16 + (l >> 4) * 4;
      int gc = n0 + wc * 64 + ni * 16 + (l & 15);
#pragma unroll
      for (int j = 0; j < 4; ++j) {
        if (BF16OUT)
          ((unsigned short*)Cv)[(size_t)(gr + j) * N + gc] = f2bf(acc[mi][ni][j]);
        else
          ((float*)Cv + (size_t)blockIdx.z * M * N)[(size_t)(gr + j) * N + gc] = acc[mi][ni][j];
      }
    }
}

// reduce 4 partial C buffers -> dbc (1M floats, float4)
__global__ __launch_bounds__(256) void redux4_k(const float4* __restrict__ part,
                                                float4* __restrict__ out) {
  int i = blockIdx.x * 256 + threadIdx.x;   // 262144 float4
  const int STR = 262144;
  float4 a = part[i], b = part[i + STR], c = part[i + 2 * STR], d = part[i + 3 * STR];
  out[i] = make_float4(a.x + b.x + c.x + d.x, a.y + b.y + c.y + d.y,
                       a.z + b.z + c.z + d.z, a.w + b.w + c.w + d.w);
}

// ---------------- depthwise causal conv(4) + bias + SiLU (bf16 in/out) ----------------
#define CONV_L 16
__global__ __launch_bounds__(256) void conv_silu_k(
    const unsigned short* __restrict__ xzb, const float* __restrict__ cw,
    const float* __restrict__ cb, unsigned short* __restrict__ xsb)
{
  const int b = blockIdx.y;
  const int l0 = blockIdx.x * CONV_L;
  const int d = threadIdx.x * 8;
  float w[4][8], bias[8];
#pragma unroll
  for (int i = 0; i < 8; ++i) {
    bias[i] = cb[d + i];
#pragma unroll
    for (int j = 0; j < 4; ++j) w[j][i] = cw[(d + i) * 4 + j];
  }
  const size_t rb = (size_t)b * 4096;
  float win[3][8];
#pragma unroll
  for (int j = 0; j < 3; ++j) {
    int l = l0 - 3 + j;
    if (l >= 0) {
      u16x8 v = *(const u16x8*)(xzb + (rb + l) * 4096 + d);
#pragma unroll
      for (int i = 0; i < 8; ++i) win[j][i] = bf2f(v[i]);
    } else {
#pragma unroll
      for (int i = 0; i < 8; ++i) win[j][i] = 0.f;
    }
  }
  for (int l = l0; l < l0 + CONV_L; ++l) {
    u16x8 v = *(const u16x8*)(xzb + (rb + l) * 4096 + d);
    float cur[8]; u16x8 ob;
#pragma unroll
    for (int i = 0; i < 8; ++i) {
      cur[i] = bf2f(v[i]);
      float u = bias[i] + w[0][i] * win[0][i] + w[1][i] * win[1][i]
                        + w[2][i] * win[2][i] + w[3][i] * cur[i];
      float s = u / (1.f + __expf(-u));
      ob[i] = f2bf(s);
    }
    *(u16x8*)(xsb + (rb + l) * 2048 + d) = ob;
#pragma unroll
    for (int i = 0; i < 8; ++i) { win[0][i] = win[1][i]; win[1][i] = win[2][i]; win[2][i] = cur[i]; }
  }
}

// ---------------- chunk-parallel selective scan ----------------
// One THREAD per channel d; all 16 states in registers. xs staged in 32-row halves
// (ping-pong) to keep LDS small -> 4 blocks/CU resident.
__global__ __launch_bounds__(256) void scan_p1(
    const unsigned short* __restrict__ xsb16, const float* __restrict__ dbc,
    const float* __restrict__ dtw, const float* __restrict__ dtb,
    const float* __restrict__ alog,
    float* __restrict__ Sg, float* __restrict__ cdg)
{
  const int chunk = blockIdx.x;
  const int d0 = blockIdx.y * 256;
  const int b = blockIdx.z;
  const int tid = threadIdx.x;
  const size_t rowbase = (size_t)b * 4096 + chunk * TC;

  __shared__ __align__(16) unsigned short xsS[TH][256];  // 16 KiB
  __shared__ __align__(16) float bS[TC][16];             // 4 KiB
  __shared__ float drS[TC];                              // 256 B

  if (tid < TC) drS[tid] = dbc[(rowbase + tid) * 128];
  for (int i = tid; i < TC * 16; i += 256) {
    int t = i >> 4, q = i & 15;
    bS[t][q] = dbc[(rowbase + t) * 128 + 1 + q];
  }

  const int d = d0 + tid;
  const float wdt = dtw[d], bdt = dtb[d];
  float adn[16];
  bool ok = true;
#pragma unroll
  for (int k = 0; k < 4; ++k) {
    float4 a4 = *(const float4*)(alog + (size_t)d * 16 + k * 4);
    adn[4 * k + 0] = -__expf(a4.x); adn[4 * k + 1] = -__expf(a4.y);
    adn[4 * k + 2] = -__expf(a4.z); adn[4 * k + 3] = -__expf(a4.w);
  }
#pragma unroll
  for (int n = 0; n < 16; ++n)
    ok = ok && (fabsf(adn[n] + (float)(n + 1)) <= 1e-3f * (float)(n + 1));

  float h[16];
#pragma unroll
  for (int n = 0; n < 16; ++n) h[n] = 0.f;
  float cd = 0.f;

  for (int half = 0; half < 2; ++half) {
    if (half) __syncthreads();   // previous half's compute done before overwrite
    for (int i = tid; i < TH * 32; i += 256) {
      int tt = i >> 5, q = i & 31;
      *(u16x8*)&xsS[tt][q * 8] =
          *(const u16x8*)(xsb16 + (rowbase + half * TH + tt) * 2048 + d0 + q * 8);
    }
    __syncthreads();

    if (ok) {
      for (int tt = 0; tt < TH; ++tt) {
        int t = half * TH + tt;
        float pre = fmaf(drS[t], wdt, bdt);
        float e = __expf(pre);
        float dlt = (pre > 20.f) ? pre : __logf(1.f + e);
        float xv = bf2f(xsS[tt][tid]);
        float dx = dlt * xv;
        cd += dlt;
        float r = __expf(-dlt);
        float rp[16];
        rpowers(r, rp);
        f32x4 Bv[4];
#pragma unroll
        for (int k = 0; k < 4; ++k) Bv[k] = ((const f32x4*)&bS[t][0])[k];
#pragma unroll
        for (int n = 0; n < 16; ++n)
          h[n] = fmaf(rp[n], h[n], dx * Bv[n >> 2][n & 3]);
      }
    } else {
      for (int tt = 0; tt < TH; ++tt) {
        int t = half * TH + tt;
        float pre = fmaf(drS[t], wdt, bdt);
        float e = __expf(pre);
        float dlt = (pre > 20.f) ? pre : __logf(1.f + e);
        float xv = bf2f(xsS[tt][tid]);
        float dx = dlt * xv;
        cd += dlt;
        f32x4 Bv[4];
#pragma unroll
        for (int k = 0; k < 4; ++k) Bv[k] = ((const f32x4*)&bS[t][0])[k];
#pragma unroll
        for (int n = 0; n < 16; ++n) {
          float dA = __expf(adn[n] * dlt);
          h[n] = fmaf(dA, h[n], dx * Bv[n >> 2][n & 3]);
        }
      }
    }
  }
  cdg[(size_t)(b * NC + chunk) * 2048 + d] = cd;
  float* Sp = Sg + ((size_t)(b * NC + chunk) * 32768 + (size_t)d * 16);
#pragma unroll
  for (int k = 0; k < 4; ++k)
    ((float4*)Sp)[k] = make_float4(h[4 * k], h[4 * k + 1], h[4 * k + 2], h[4 * k + 3]);
}

// Phase 2: scan across chunks; Hg[c] = state entering chunk c. P recomputed from cd.
__global__ __launch_bounds__(256) void scan_p2(
    const float* __restrict__ Sg, const float* __restrict__ cdg,
    const float* __restrict__ alog, float* __restrict__ Hg)
{
  int g = blockIdx.x * 256 + threadIdx.x;   // 65536 = B*D*N
  int b = g >> 15, dn = g & 32767;
  int d = dn >> 4;
  float adn = -__expf(alog[dn]);
  float h = 0.f;
  for (int c = 0; c < NC; ++c) {
    size_t o = (size_t)(b * NC + c) * 32768 + dn;
    float P = __expf(adn * cdg[(size_t)(b * NC + c) * 2048 + d]);
    Hg[o] = h;
    h = fmaf(P, h, Sg[o]);
  }
}

// Phase 3: re-run local scan from true entry state, emit y, fuse gating.
// xs staged in halves; y written back into the staged tile then gated+stored per half.
__global__ __launch_bounds__(256) void scan_p3(
    const unsigned short* __restrict__ xsb16, const float* __restrict__ dbc,
    const float* __restrict__ dtw, const float* __restrict__ dtb,
    const float* __restrict__ alog, const float* __restrict__ Dp,
    const unsigned short* __restrict__ xzb, const float* __restrict__ Hg,
    unsigned short* __restrict__ gb)
{
  const int chunk = blockIdx.x;
  const int d0 = blockIdx.y * 256;
  const int b = blockIdx.z;
  const int tid = threadIdx.x;
  const size_t rowbase = (size_t)b * 4096 + chunk * TC;

  __shared__ __align__(16) unsigned short xsS[TH][256];  // 16 KiB
  __shared__ __align__(16) float bcS[TC][32];            // 8 KiB

  for (int i = tid; i < TC * 32; i += 256) {
    int t = i >> 5, q = i & 31;
    bcS[t][q] = dbc[(rowbase + t) * 128 + 1 + q];
  }

  const int d = d0 + tid;
  const float wdt = dtw[d], bdt = dtb[d], Dd = Dp[d];
  const float* __restrict__ drp = dbc + rowbase * 128;
  float adn[16];
  bool ok = true;
#pragma unroll
  for (int k = 0; k < 4; ++k) {
    float4 a4 = *(const float4*)(alog + (size_t)d * 16 + k * 4);
    adn[4 * k + 0] = -__expf(a4.x); adn[4 * k + 1] = -__expf(a4.y);
    adn[4 * k + 2] = -__expf(a4.z); adn[4 * k + 3] = -__expf(a4.w);
  }
#pragma unroll
  for (int n = 0; n < 16; ++n)
    ok = ok && (fabsf(adn[n] + (float)(n + 1)) <= 1e-3f * (float)(n + 1));

  float h[16];
  {
    const float* Hp = Hg + ((size_t)(b * NC + chunk) * 32768 + (size_t)d * 16);
#pragma unroll
    for (int k = 0; k < 4; ++k) {
      float4 h4 = ((const float4*)Hp)[k];
      h[4 * k + 0] = h4.x; h[4 * k + 1] = h4.y; h[4 * k + 2] = h4.z; h[4 * k + 3] = h4.w;
    }
  }

  for (int half = 0; half < 2; ++half) {
    if (half) __syncthreads();   // previous half's gate-store done before overwrite
    for (int i = tid; i < TH * 32; i += 256) {
      int tt = i >> 5, q = i & 31;
      *(u16x8*)&xsS[tt][q * 8] =
          *(const u16x8*)(xsb16 + (rowbase + half * TH + tt) * 2048 + d0 + q * 8);
    }
    __syncthreads();

    if (ok) {
      for (int tt = 0; tt < TH; ++tt) {
        int t = half * TH + tt;
        float pre = fmaf(drp[(size_t)t * 128], wdt, bdt);
        float e = __expf(pre);
        float dlt = (pre > 20.f) ? pre : __logf(1.f + e);
        float xv = bf2f(xsS[tt][tid]);
        float dx = dlt * xv;
        float r = __expf(-dlt);
        float rp[16];
        rpowers(r, rp);
        f32x4 Bv[4], Cv[4];
#pragma unroll
        for (int k = 0; k < 4; ++k) {
          Bv[k] = ((const f32x4*)&bcS[t][0])[k];
          Cv[k] = ((const f32x4*)&bcS[t][16])[k];
        }
        float yp[4];
        yp[0] = Dd * xv; yp[1] = 0.f; yp[2] = 0.f; yp[3] = 0.f;
#pragma unroll
        for (int n = 0; n < 16; ++n) {
          h[n] = fmaf(rp[n], h[n], dx * Bv[n >> 2][n & 3]);
          yp[n & 3] = fmaf(h[n], Cv[n >> 2][n & 3], yp[n & 3]);
        }
        float y = (yp[0] + yp[1]) + (yp[2] + yp[3]);
        xsS[tt][tid] = f2bf(y);
      }
    } else {
      for (int tt = 0; tt < TH; ++tt) {
        int t = half * TH + tt;
        float pre = fmaf(drp[(size_t)t * 128], wdt, bdt);
        float e = __expf(pre);
        float dlt = (pre > 20.f) ? pre : __logf(1.f + e);
        float xv = bf2f(xsS[tt][tid]);
        float dx = dlt * xv;
        f32x4 Bv[4], Cv[4];
#pragma unroll
        for (int k = 0; k < 4; ++k) {
          Bv[k] = ((const f32x4*)&bcS[t][0])[k];
          Cv[k] = ((const f32x4*)&bcS[t][16])[k];
        }
        float yp[4];
        yp[0] = Dd * xv; yp[1] = 0.f; yp[2] = 0.f; yp[3] = 0.f;
#pragma unroll
        for (int n = 0; n < 16; ++n) {
          float dA = __expf(adn[n] * dlt);
          h[n] = fmaf(dA, h[n], dx * Bv[n >> 2][n & 3]);
          yp[n & 3] = fmaf(h[n], Cv[n >> 2][n & 3], yp[n & 3]);
        }
        float y = (yp[0] + yp[1]) + (yp[2] + yp[3]);
        xsS[tt][tid] = f2bf(y);
      }
    }
    __syncthreads();

    for (int i = tid; i < TH * 32; i += 256) {
      int tt = i >> 5, q = i & 31;
      size_t row = rowbase + half * TH + tt;
      u16x8 yv = *(const u16x8*)&xsS[tt][q * 8];
      u16x8 zv = *(const u16x8*)(xzb + row * 4096 + 2048 + d0 + q * 8);
      u16x8 ov;
#pragma unroll
      for (int j = 0; j < 8; ++j) {
        float z = bf2f(zv[j]);
        float s = z / (1.f + __expf(-z));
        ov[j] = f2bf(bf2f(yv[j]) * s);
      }
      *(u16x8*)(gb + row * 2048 + d0 + q * 8) = ov;
    }
  }
}

extern "C" void kernel_launch(void* const* d_in, const int* in_sizes, int n_in,
                              void* d_out, int out_size, void* d_ws, size_t ws_size,
                              hipStream_t stream) {
  const float* x    = (const float*)d_in[0];
  const float* ipw  = (const float*)d_in[1];
  const float* cw   = (const float*)d_in[2];
  const float* cb   = (const float*)d_in[3];
  const float* xpw  = (const float*)d_in[4];
  const float* dtw  = (const float*)d_in[5];
  const float* dtb  = (const float*)d_in[6];
  const float* alog = (const float*)d_in[7];
  const float* Dp   = (const float*)d_in[8];
  const float* opw  = (const float*)d_in[9];
  float* out = (float*)d_out;

  char* p = (char*)d_ws;
  unsigned short* xb   = (unsigned short*)p; p += (size_t)8388608 * 2;   // x bf16 (16 MiB) — reused as Hg
  unsigned short* wb1  = (unsigned short*)p; p += (size_t)4194304 * 2;   // in_proj_w bf16   (8 MiB)
  unsigned short* wb2  = (unsigned short*)p; p += (size_t)2097152 * 2;   // out_proj_w bf16  (4 MiB)
  unsigned short* xwp  = (unsigned short*)p; p += (size_t)262144 * 2;    // padded x_proj_w  (0.5 MiB)
  unsigned short* xzb  = (unsigned short*)p; p += (size_t)33554432 * 2;  // in_proj out bf16 (64 MiB)
  unsigned short* xsb16= (unsigned short*)p; p += (size_t)16777216 * 2;  // conv+silu bf16   (32 MiB)
  float*          dbc  = (float*)p;          p += (size_t)1048576 * 4;   // x_proj out fp32  (4 MiB)
  unsigned short* gb   = (unsigned short*)p; p += (size_t)16777216 * 2;  // y*silu(z) bf16   (32 MiB)
  float*          Sg   = (float*)p;          p += (size_t)4194304 * 4;   // chunk states     (16 MiB)
  float*          cdg  = (float*)p;          p += (size_t)262144 * 4;    // chunk decay sums (1 MiB)
  float*          Hg   = (float*)xb;                                     // chunk entry states (aliases xb)
  float*          dbcp = Sg;                                             // 4 split-K partials (alias Sg, dead until scan_p1)

  cast_bf16_k<<<1024, 256, 0, stream>>>((const float4*)x,   (ushort4*)xb,  8388608 / 4);
  cast_bf16_k<<<1024, 256, 0, stream>>>((const float4*)ipw, (ushort4*)wb1, 4194304 / 4);
  cast_bf16_k<<<512,  256, 0, stream>>>((const float4*)opw, (ushort4*)wb2, 2097152 / 4);
  pad_xw_k<<<1024, 256, 0, stream>>>(xpw, xwp);

  gemm2p<true, true><<<2048, 256, 0, stream>>>(xb, wb1, xzb, 8192, 4096, 1024);
  conv_silu_k<<<dim3(4096 / CONV_L, 2), 256, 0, stream>>>(xzb, cw, cb, xsb16);

  gemm2p<false, false><<<dim3(64, 1, 4), 256, 0, stream>>>(xsb16, xwp, dbcp, 8192, 128, 2048);
  redux4_k<<<1024, 256, 0, stream>>>((const float4*)dbcp, (float4*)dbc);

  scan_p1<<<dim3(NC, 8, 2), 256, 0, stream>>>(xsb16, dbc, dtw, dtb, alog, Sg, cdg);
  scan_p2<<<256, 256, 0, stream>>>(Sg, cdg, alog, Hg);
  scan_p3<<<dim3(NC, 8, 2), 256, 0, stream>>>(xsb16, dbc, dtw, dtb, alog, Dp, xzb, Hg, gb);

  gemm2p<false, true><<<512, 256, 0, stream>>>(gb, wb2, out, 8192, 1024, 2048);
}

// Round 8
// 307.028 us; speedup vs baseline: 7.5935x; 1.0113x over previous
//
#include <hip/hip_runtime.h>
#include <hip/hip_bf16.h>
#include <stdint.h>

typedef __bf16 bf16x8 __attribute__((ext_vector_type(8)));
typedef float  f32x4  __attribute__((ext_vector_type(4)));
typedef unsigned short u16x8 __attribute__((ext_vector_type(8)));

#define TC 64   // timesteps per chunk
#define NC 64   // chunks (TC*NC == 4096)
#define TH 32   // staged half

__device__ __forceinline__ unsigned short f2bf(float f) {
  unsigned u = __builtin_bit_cast(unsigned, f);
  unsigned r = (u + 0x7fffu + ((u >> 16) & 1u)) >> 16;
  return (unsigned short)r;
}
__device__ __forceinline__ float bf2f(unsigned short s) {
  unsigned u = ((unsigned)s) << 16;
  return __builtin_bit_cast(float, u);
}

__device__ __forceinline__ void gload_lds16(const void* g, void* l) {
  __builtin_amdgcn_global_load_lds(
      (const __attribute__((address_space(1))) unsigned int*)(g),
      (__attribute__((address_space(3))) unsigned int*)(l),
      16, 0, 0);
}

// rp[k] = r^(k+1), k=0..15, via full-rate mul tree (depth <= 4)
__device__ __forceinline__ void rpowers(float r, float* rp) {
  float r2 = r * r, r4 = r2 * r2, r8 = r4 * r4;
  rp[0] = r;        rp[1] = r2;       rp[2] = r2 * r;   rp[3] = r4;
  rp[4] = r4 * r;   rp[5] = r4 * r2;  rp[6] = rp[5] * r; rp[7] = r8;
  rp[8] = r8 * r;   rp[9] = r8 * r2;  rp[10] = rp[9] * r; rp[11] = r8 * r4;
  rp[12] = rp[11] * r; rp[13] = rp[11] * r2; rp[14] = rp[13] * r; rp[15] = r8 * r8;
}

// ---------------- cast fp32 -> bf16 (vectorized) ----------------
__global__ __launch_bounds__(256) void cast_bf16_k(const float4* __restrict__ in,
                                                   ushort4* __restrict__ out, int n4) {
  int i = blockIdx.x * 256 + threadIdx.x;
  int stride = gridDim.x * 256;
  for (; i < n4; i += stride) {
    float4 v = in[i];
    ushort4 o;
    o.x = f2bf(v.x); o.y = f2bf(v.y); o.z = f2bf(v.z); o.w = f2bf(v.w);
    out[i] = o;
  }
}

// ---------------- pad+cast x_proj_w (33x2048) -> (128x2048) bf16 ----------------
__global__ __launch_bounds__(256) void pad_xw_k(const float* __restrict__ xw,
                                                unsigned short* __restrict__ xwp) {
  int i = blockIdx.x * 256 + threadIdx.x;   // grid covers 128*2048
  if (i >= 128 * 2048) return;
  int row = i >> 11, col = i & 2047;
  xwp[i] = (row < 33) ? f2bf(xw[row * 2048 + col]) : (unsigned short)0;
}

// ---------------- bf16 MFMA GEMM: C[M][N] = A[M][K] * B[N][K]^T ----------------
// 128x128 tile, BK=32, triple-buffered LDS pipeline (prefetch distance 2),
// counted vmcnt(4) + raw s_barrier (loads stay in flight across barriers).
// LDS bank-conflict-free via 2-bit XOR swizzle: slot' = slot ^ ((row>>1)&3),
// applied on BOTH sides (pre-swizzled global source + swizzled ds_read).
// XCD-bijective swizzle + GROUP_M grouping for L2 panel reuse.
// gridDim.z>1 => split-K: z-slice writes fp32 partials at Cv + z*M*N.
template <bool BF16OUT, bool SWZ>
__global__ __launch_bounds__(256) void gemm2p(
    const unsigned short* __restrict__ A, const unsigned short* __restrict__ B,
    void* __restrict__ Cv, int M, int N, int K)
{
  __shared__ __align__(16) unsigned short AsB[3 * 128 * 32];
  __shared__ __align__(16) unsigned short BsB[3 * 128 * 32];
  const int tid = threadIdx.x;

  // ---- block -> (m0, n0) mapping ----
  const int grid_m = M >> 7, grid_n = N >> 7;
  const int nwg = grid_m * grid_n;
  int wid = blockIdx.x;
  if (SWZ) { int q = nwg >> 3; wid = (wid & 7) * q + (wid >> 3); }  // nwg % 8 == 0
  const int GM = 16;
  const int nig = GM * grid_n;
  const int gidg = wid / nig;
  const int rem = wid - gidg * nig;
  const int fm = gidg * GM;
  const int gsz = min(grid_m - fm, GM);
  const int pm = fm + rem % gsz;
  const int pn = rem / gsz;
  const int m0 = pm << 7, n0 = pn << 7;

  // ---- K range (split-K via z) ----
  const int kseg = K / gridDim.z;
  const int kbeg = blockIdx.z * kseg;
  const int NT = kseg >> 5;   // K-tiles of 32

  const int w = tid >> 6, l = tid & 63;
  const int wr = w >> 1, wc = w & 1;
  const int lr = l & 15, kk = (l >> 4) * 8;

  // staging: thread q's linear LDS dest [16q,16q+16) holds source slot
  // sub = (q&3) ^ ((q>>3)&3)  (inverse of the read-side swizzle)
  f32x4 acc[4][4];
#pragma unroll
  for (int mi = 0; mi < 4; ++mi)
#pragma unroll
    for (int ni = 0; ni < 4; ++ni)
      acc[mi][ni] = (f32x4){0.f, 0.f, 0.f, 0.f};

  // ---- prologue: stage tiles 0 and 1 ----
#pragma unroll
  for (int tt = 0; tt < 2; ++tt) {
    unsigned short* as = AsB + tt * 4096;
    unsigned short* bs = BsB + tt * 4096;
    int k0 = kbeg + tt * 32;
#pragma unroll
    for (int i = 0; i < 2; ++i) {
      int q = tid + 256 * i;
      int row = q >> 2, sub = (q & 3) ^ ((q >> 3) & 3);
      gload_lds16(A + (size_t)(m0 + row) * K + k0 + sub * 8, as + q * 8);
      gload_lds16(B + (size_t)(n0 + row) * K + k0 + sub * 8, bs + q * 8);
    }
  }
  asm volatile("s_waitcnt vmcnt(4)\n\ts_barrier" ::: "memory");  // tile0 ready

  // ---- main loop ----
  for (int t = 0; t < NT; ++t) {
    if (t + 2 < NT) {
      unsigned short* as = AsB + ((t + 2) % 3) * 4096;
      unsigned short* bs = BsB + ((t + 2) % 3) * 4096;
      int k0 = kbeg + (t + 2) * 32;
#pragma unroll
      for (int i = 0; i < 2; ++i) {
        int q = tid + 256 * i;
        int row = q >> 2, sub = (q & 3) ^ ((q >> 3) & 3);
        gload_lds16(A + (size_t)(m0 + row) * K + k0 + sub * 8, as + q * 8);
        gload_lds16(B + (size_t)(n0 + row) * K + k0 + sub * 8, bs + q * 8);
      }
    }
    const unsigned short* as = AsB + (t % 3) * 4096;
    const unsigned short* bs = BsB + (t % 3) * 4096;
    bf16x8 af[4], bfr[4];
#pragma unroll
    for (int mi = 0; mi < 4; ++mi) {
      int row = wr * 64 + mi * 16 + lr;
      int col = kk ^ (((row >> 1) & 3) << 3);
      af[mi] = *(const bf16x8*)&as[row * 32 + col];
    }
#pragma unroll
    for (int ni = 0; ni < 4; ++ni) {
      int row = wc * 64 + ni * 16 + lr;
      int col = kk ^ (((row >> 1) & 3) << 3);
      bfr[ni] = *(const bf16x8*)&bs[row * 32 + col];
    }
    __builtin_amdgcn_s_setprio(1);
#pragma unroll
    for (int mi = 0; mi < 4; ++mi)
#pragma unroll
      for (int ni = 0; ni < 4; ++ni)
        acc[mi][ni] = __builtin_amdgcn_mfma_f32_16x16x32_bf16(af[mi], bfr[ni], acc[mi][ni], 0, 0, 0);
    __builtin_amdgcn_s_setprio(0);
    if (t + 1 < NT) {
      if (t + 2 < NT) asm volatile("s_waitcnt vmcnt(4)\n\ts_barrier" ::: "memory");
      else            asm volatile("s_waitcnt vmcnt(0)\n\ts_barrier" ::: "memory");
    }
  }

  // ---- epilogue ----
#pragma unroll
  for (int mi = 0; mi < 4; ++mi)
#pragma unroll
    for (int ni = 0; ni < 4; ++ni) {
      int gr = m0 + wr * 64 + mi * 16 + (l >> 4) * 4;
      int gc = n0 + wc * 64 + ni * 16 + (l & 15);
#pragma unroll
      for (int j = 0; j < 4; ++j) {
        if (BF16OUT)
          ((unsigned short*)Cv)[(size_t)(gr + j) * N + gc] = f2bf(acc[mi][ni][j]);
        else
          ((float*)Cv + (size_t)blockIdx.z * M * N)[(size_t)(gr + j) * N + gc] = acc[mi][ni][j];
      }
    }
}

// reduce 4 partial C buffers -> dbc (1M floats, float4)
__global__ __launch_bounds__(256) void redux4_k(const float4* __restrict__ part,
                                                float4* __restrict__ out) {
  int i = blockIdx.x * 256 + threadIdx.x;   // 262144 float4
  const int STR = 262144;
  float4 a = part[i], b = part[i + STR], c = part[i + 2 * STR], d = part[i + 3 * STR];
  out[i] = make_float4(a.x + b.x + c.x + d.x, a.y + b.y + c.y + d.y,
                       a.z + b.z + c.z + d.z, a.w + b.w + c.w + d.w);
}

// ---------------- depthwise causal conv(4) + bias + SiLU (bf16 in/out) ----------------
#define CONV_L 16
__global__ __launch_bounds__(256) void conv_silu_k(
    const unsigned short* __restrict__ xzb, const float* __restrict__ cw,
    const float* __restrict__ cb, unsigned short* __restrict__ xsb)
{
  const int b = blockIdx.y;
  const int l0 = blockIdx.x * CONV_L;
  const int d = threadIdx.x * 8;
  float w[4][8], bias[8];
#pragma unroll
  for (int i = 0; i < 8; ++i) {
    bias[i] = cb[d + i];
#pragma unroll
    for (int j = 0; j < 4; ++j) w[j][i] = cw[(d + i) * 4 + j];
  }
  const size_t rb = (size_t)b * 4096;
  float win[3][8];
#pragma unroll
  for (int j = 0; j < 3; ++j) {
    int l = l0 - 3 + j;
    if (l >= 0) {
      u16x8 v = *(const u16x8*)(xzb + (rb + l) * 4096 + d);
#pragma unroll
      for (int i = 0; i < 8; ++i) win[j][i] = bf2f(v[i]);
    } else {
#pragma unroll
      for (int i = 0; i < 8; ++i) win[j][i] = 0.f;
    }
  }
  for (int l = l0; l < l0 + CONV_L; ++l) {
    u16x8 v = *(const u16x8*)(xzb + (rb + l) * 4096 + d);
    float cur[8]; u16x8 ob;
#pragma unroll
    for (int i = 0; i < 8; ++i) {
      cur[i] = bf2f(v[i]);
      float u = bias[i] + w[0][i] * win[0][i] + w[1][i] * win[1][i]
                        + w[2][i] * win[2][i] + w[3][i] * cur[i];
      float s = u / (1.f + __expf(-u));
      ob[i] = f2bf(s);
    }
    *(u16x8*)(xsb + (rb + l) * 2048 + d) = ob;
#pragma unroll
    for (int i = 0; i < 8; ++i) { win[0][i] = win[1][i]; win[1][i] = win[2][i]; win[2][i] = cur[i]; }
  }
}

// ---------------- chunk-parallel selective scan ----------------
// One THREAD per channel d; all 16 states in registers. xs staged in 32-row halves
// (ping-pong) to keep LDS small -> 4 blocks/CU resident.
__global__ __launch_bounds__(256) void scan_p1(
    const unsigned short* __restrict__ xsb16, const float* __restrict__ dbc,
    const float* __restrict__ dtw, const float* __restrict__ dtb,
    const float* __restrict__ alog,
    float* __restrict__ Sg, float* __restrict__ cdg)
{
  const int chunk = blockIdx.x;
  const int d0 = blockIdx.y * 256;
  const int b = blockIdx.z;
  const int tid = threadIdx.x;
  const size_t rowbase = (size_t)b * 4096 + chunk * TC;

  __shared__ __align__(16) unsigned short xsS[TH][256];  // 16 KiB
  __shared__ __align__(16) float bS[TC][16];             // 4 KiB
  __shared__ float drS[TC];                              // 256 B

  if (tid < TC) drS[tid] = dbc[(rowbase + tid) * 128];
  for (int i = tid; i < TC * 16; i += 256) {
    int t = i >> 4, q = i & 15;
    bS[t][q] = dbc[(rowbase + t) * 128 + 1 + q];
  }

  const int d = d0 + tid;
  const float wdt = dtw[d], bdt = dtb[d];
  float adn[16];
  bool ok = true;
#pragma unroll
  for (int k = 0; k < 4; ++k) {
    float4 a4 = *(const float4*)(alog + (size_t)d * 16 + k * 4);
    adn[4 * k + 0] = -__expf(a4.x); adn[4 * k + 1] = -__expf(a4.y);
    adn[4 * k + 2] = -__expf(a4.z); adn[4 * k + 3] = -__expf(a4.w);
  }
#pragma unroll
  for (int n = 0; n < 16; ++n)
    ok = ok && (fabsf(adn[n] + (float)(n + 1)) <= 1e-3f * (float)(n + 1));

  float h[16];
#pragma unroll
  for (int n = 0; n < 16; ++n) h[n] = 0.f;
  float cd = 0.f;

  for (int half = 0; half < 2; ++half) {
    if (half) __syncthreads();   // previous half's compute done before overwrite
    for (int i = tid; i < TH * 32; i += 256) {
      int tt = i >> 5, q = i & 31;
      *(u16x8*)&xsS[tt][q * 8] =
          *(const u16x8*)(xsb16 + (rowbase + half * TH + tt) * 2048 + d0 + q * 8);
    }
    __syncthreads();

    if (ok) {
      for (int tt = 0; tt < TH; ++tt) {
        int t = half * TH + tt;
        float pre = fmaf(drS[t], wdt, bdt);
        float e = __expf(pre);
        float dlt = (pre > 20.f) ? pre : __logf(1.f + e);
        float xv = bf2f(xsS[tt][tid]);
        float dx = dlt * xv;
        cd += dlt;
        float r = __expf(-dlt);
        float rp[16];
        rpowers(r, rp);
        f32x4 Bv[4];
#pragma unroll
        for (int k = 0; k < 4; ++k) Bv[k] = ((const f32x4*)&bS[t][0])[k];
#pragma unroll
        for (int n = 0; n < 16; ++n)
          h[n] = fmaf(rp[n], h[n], dx * Bv[n >> 2][n & 3]);
      }
    } else {
      for (int tt = 0; tt < TH; ++tt) {
        int t = half * TH + tt;
        float pre = fmaf(drS[t], wdt, bdt);
        float e = __expf(pre);
        float dlt = (pre > 20.f) ? pre : __logf(1.f + e);
        float xv = bf2f(xsS[tt][tid]);
        float dx = dlt * xv;
        cd += dlt;
        f32x4 Bv[4];
#pragma unroll
        for (int k = 0; k < 4; ++k) Bv[k] = ((const f32x4*)&bS[t][0])[k];
#pragma unroll
        for (int n = 0; n < 16; ++n) {
          float dA = __expf(adn[n] * dlt);
          h[n] = fmaf(dA, h[n], dx * Bv[n >> 2][n & 3]);
        }
      }
    }
  }
  cdg[(size_t)(b * NC + chunk) * 2048 + d] = cd;
  float* Sp = Sg + ((size_t)(b * NC + chunk) * 32768 + (size_t)d * 16);
#pragma unroll
  for (int k = 0; k < 4; ++k)
    ((float4*)Sp)[k] = make_float4(h[4 * k], h[4 * k + 1], h[4 * k + 2], h[4 * k + 3]);
}

// Phase 2: scan across chunks; Hg[c] = state entering chunk c. P recomputed from cd.
__global__ __launch_bounds__(256) void scan_p2(
    const float* __restrict__ Sg, const float* __restrict__ cdg,
    const float* __restrict__ alog, float* __restrict__ Hg)
{
  int g = blockIdx.x * 256 + threadIdx.x;   // 65536 = B*D*N
  int b = g >> 15, dn = g & 32767;
  int d = dn >> 4;
  float adn = -__expf(alog[dn]);
  float h = 0.f;
  for (int c = 0; c < NC; ++c) {
    size_t o = (size_t)(b * NC + c) * 32768 + dn;
    float P = __expf(adn * cdg[(size_t)(b * NC + c) * 2048 + d]);
    Hg[o] = h;
    h = fmaf(P, h, Sg[o]);
  }
}

// Phase 3: re-run local scan from true entry state, emit y, fuse gating.
// xs staged in halves; y written back into the staged tile then gated+stored per half.
__global__ __launch_bounds__(256) void scan_p3(
    const unsigned short* __restrict__ xsb16, const float* __restrict__ dbc,
    const float* __restrict__ dtw, const float* __restrict__ dtb,
    const float* __restrict__ alog, const float* __restrict__ Dp,
    const unsigned short* __restrict__ xzb, const float* __restrict__ Hg,
    unsigned short* __restrict__ gb)
{
  const int chunk = blockIdx.x;
  const int d0 = blockIdx.y * 256;
  const int b = blockIdx.z;
  const int tid = threadIdx.x;
  const size_t rowbase = (size_t)b * 4096 + chunk * TC;

  __shared__ __align__(16) unsigned short xsS[TH][256];  // 16 KiB
  __shared__ __align__(16) float bcS[TC][32];            // 8 KiB

  for (int i = tid; i < TC * 32; i += 256) {
    int t = i >> 5, q = i & 31;
    bcS[t][q] = dbc[(rowbase + t) * 128 + 1 + q];
  }

  const int d = d0 + tid;
  const float wdt = dtw[d], bdt = dtb[d], Dd = Dp[d];
  const float* __restrict__ drp = dbc + rowbase * 128;
  float adn[16];
  bool ok = true;
#pragma unroll
  for (int k = 0; k < 4; ++k) {
    float4 a4 = *(const float4*)(alog + (size_t)d * 16 + k * 4);
    adn[4 * k + 0] = -__expf(a4.x); adn[4 * k + 1] = -__expf(a4.y);
    adn[4 * k + 2] = -__expf(a4.z); adn[4 * k + 3] = -__expf(a4.w);
  }
#pragma unroll
  for (int n = 0; n < 16; ++n)
    ok = ok && (fabsf(adn[n] + (float)(n + 1)) <= 1e-3f * (float)(n + 1));

  float h[16];
  {
    const float* Hp = Hg + ((size_t)(b * NC + chunk) * 32768 + (size_t)d * 16);
#pragma unroll
    for (int k = 0; k < 4; ++k) {
      float4 h4 = ((const float4*)Hp)[k];
      h[4 * k + 0] = h4.x; h[4 * k + 1] = h4.y; h[4 * k + 2] = h4.z; h[4 * k + 3] = h4.w;
    }
  }

  for (int half = 0; half < 2; ++half) {
    if (half) __syncthreads();   // previous half's gate-store done before overwrite
    for (int i = tid; i < TH * 32; i += 256) {
      int tt = i >> 5, q = i & 31;
      *(u16x8*)&xsS[tt][q * 8] =
          *(const u16x8*)(xsb16 + (rowbase + half * TH + tt) * 2048 + d0 + q * 8);
    }
    __syncthreads();

    if (ok) {
      for (int tt = 0; tt < TH; ++tt) {
        int t = half * TH + tt;
        float pre = fmaf(drp[(size_t)t * 128], wdt, bdt);
        float e = __expf(pre);
        float dlt = (pre > 20.f) ? pre : __logf(1.f + e);
        float xv = bf2f(xsS[tt][tid]);
        float dx = dlt * xv;
        float r = __expf(-dlt);
        float rp[16];
        rpowers(r, rp);
        f32x4 Bv[4], Cv[4];
#pragma unroll
        for (int k = 0; k < 4; ++k) {
          Bv[k] = ((const f32x4*)&bcS[t][0])[k];
          Cv[k] = ((const f32x4*)&bcS[t][16])[k];
        }
        float yp[4];
        yp[0] = Dd * xv; yp[1] = 0.f; yp[2] = 0.f; yp[3] = 0.f;
#pragma unroll
        for (int n = 0; n < 16; ++n) {
          h[n] = fmaf(rp[n], h[n], dx * Bv[n >> 2][n & 3]);
          yp[n & 3] = fmaf(h[n], Cv[n >> 2][n & 3], yp[n & 3]);
        }
        float y = (yp[0] + yp[1]) + (yp[2] + yp[3]);
        xsS[tt][tid] = f2bf(y);
      }
    } else {
      for (int tt = 0; tt < TH; ++tt) {
        int t = half * TH + tt;
        float pre = fmaf(drp[(size_t)t * 128], wdt, bdt);
        float e = __expf(pre);
        float dlt = (pre > 20.f) ? pre : __logf(1.f + e);
        float xv = bf2f(xsS[tt][tid]);
        float dx = dlt * xv;
        f32x4 Bv[4], Cv[4];
#pragma unroll
        for (int k = 0; k < 4; ++k) {
          Bv[k] = ((const f32x4*)&bcS[t][0])[k];
          Cv[k] = ((const f32x4*)&bcS[t][16])[k];
        }
        float yp[4];
        yp[0] = Dd * xv; yp[1] = 0.f; yp[2] = 0.f; yp[3] = 0.f;
#pragma unroll
        for (int n = 0; n < 16; ++n) {
          float dA = __expf(adn[n] * dlt);
          h[n] = fmaf(dA, h[n], dx * Bv[n >> 2][n & 3]);
          yp[n & 3] = fmaf(h[n], Cv[n >> 2][n & 3], yp[n & 3]);
        }
        float y = (yp[0] + yp[1]) + (yp[2] + yp[3]);
        xsS[tt][tid] = f2bf(y);
      }
    }
    __syncthreads();

    for (int i = tid; i < TH * 32; i += 256) {
      int tt = i >> 5, q = i & 31;
      size_t row = rowbase + half * TH + tt;
      u16x8 yv = *(const u16x8*)&xsS[tt][q * 8];
      u16x8 zv = *(const u16x8*)(xzb + row * 4096 + 2048 + d0 + q * 8);
      u16x8 ov;
#pragma unroll
      for (int j = 0; j < 8; ++j) {
        float z = bf2f(zv[j]);
        float s = z / (1.f + __expf(-z));
        ov[j] = f2bf(bf2f(yv[j]) * s);
      }
      *(u16x8*)(gb + row * 2048 + d0 + q * 8) = ov;
    }
  }
}

extern "C" void kernel_launch(void* const* d_in, const int* in_sizes, int n_in,
                              void* d_out, int out_size, void* d_ws, size_t ws_size,
                              hipStream_t stream) {
  const float* x    = (const float*)d_in[0];
  const float* ipw  = (const float*)d_in[1];
  const float* cw   = (const float*)d_in[2];
  const float* cb   = (const float*)d_in[3];
  const float* xpw  = (const float*)d_in[4];
  const float* dtw  = (const float*)d_in[5];
  const float* dtb  = (const float*)d_in[6];
  const float* alog = (const float*)d_in[7];
  const float* Dp   = (const float*)d_in[8];
  const float* opw  = (const float*)d_in[9];
  float* out = (float*)d_out;

  char* p = (char*)d_ws;
  unsigned short* xb   = (unsigned short*)p; p += (size_t)8388608 * 2;   // x bf16 (16 MiB) — reused as Hg
  unsigned short* wb1  = (unsigned short*)p; p += (size_t)4194304 * 2;   // in_proj_w bf16   (8 MiB)
  unsigned short* wb2  = (unsigned short*)p; p += (size_t)2097152 * 2;   // out_proj_w bf16  (4 MiB)
  unsigned short* xwp  = (unsigned short*)p; p += (size_t)262144 * 2;    // padded x_proj_w  (0.5 MiB)
  unsigned short* xzb  = (unsigned short*)p; p += (size_t)33554432 * 2;  // in_proj out bf16 (64 MiB)
  unsigned short* xsb16= (unsigned short*)p; p += (size_t)16777216 * 2;  // conv+silu bf16   (32 MiB)
  float*          dbc  = (float*)p;          p += (size_t)1048576 * 4;   // x_proj out fp32  (4 MiB)
  unsigned short* gb   = (unsigned short*)p; p += (size_t)16777216 * 2;  // y*silu(z) bf16   (32 MiB)
  float*          Sg   = (float*)p;          p += (size_t)4194304 * 4;   // chunk states     (16 MiB)
  float*          cdg  = (float*)p;          p += (size_t)262144 * 4;    // chunk decay sums (1 MiB)
  float*          Hg   = (float*)xb;                                     // chunk entry states (aliases xb)
  float*          dbcp = Sg;                                             // 4 split-K partials (alias Sg, dead until scan_p1)

  cast_bf16_k<<<1024, 256, 0, stream>>>((const float4*)x,   (ushort4*)xb,  8388608 / 4);
  cast_bf16_k<<<1024, 256, 0, stream>>>((const float4*)ipw, (ushort4*)wb1, 4194304 / 4);
  cast_bf16_k<<<512,  256, 0, stream>>>((const float4*)opw, (ushort4*)wb2, 2097152 / 4);
  pad_xw_k<<<1024, 256, 0, stream>>>(xpw, xwp);

  gemm2p<true, true><<<2048, 256, 0, stream>>>(xb, wb1, xzb, 8192, 4096, 1024);
  conv_silu_k<<<dim3(4096 / CONV_L, 2), 256, 0, stream>>>(xzb, cw, cb, xsb16);

  gemm2p<false, false><<<dim3(64, 1, 4), 256, 0, stream>>>(xsb16, xwp, dbcp, 8192, 128, 2048);
  redux4_k<<<1024, 256, 0, stream>>>((const float4*)dbcp, (float4*)dbc);

  scan_p1<<<dim3(NC, 8, 2), 256, 0, stream>>>(xsb16, dbc, dtw, dtb, alog, Sg, cdg);
  scan_p2<<<256, 256, 0, stream>>>(Sg, cdg, alog, Hg);
  scan_p3<<<dim3(NC, 8, 2), 256, 0, stream>>>(xsb16, dbc, dtw, dtb, alog, Dp, xzb, Hg, gb);

  gemm2p<false, true><<<512, 256, 0, stream>>>(gb, wb2, out, 8192, 1024, 2048);
}

// Round 9
// 295.168 us; speedup vs baseline: 7.8986x; 1.0402x over previous
//
#include <hip/hip_runtime.h>
#include <hip/hip_bf16.h>
#include <stdint.h>

typedef __bf16 bf16x8 __attribute__((ext_vector_type(8)));
typedef float  f32x4  __attribute__((ext_vector_type(4)));
typedef unsigned short u16x8 __attribute__((ext_vector_type(8)));

#define TC 64   // timesteps per chunk
#define NC 64   // chunks (TC*NC == 4096)
#define TH 32   // staged half

__device__ __forceinline__ unsigned short f2bf(float f) {
  unsigned u = __builtin_bit_cast(unsigned, f);
  unsigned r = (u + 0x7fffu + ((u >> 16) & 1u)) >> 16;
  return (unsigned short)r;
}
__device__ __forceinline__ float bf2f(unsigned short s) {
  unsigned u = ((unsigned)s) << 16;
  return __builtin_bit_cast(float, u);
}

__device__ __forceinline__ void gload_lds16(const void* g, void* l) {
  __builtin_amdgcn_global_load_lds(
      (const __attribute__((address_space(1))) unsigned int*)(g),
      (__attribute__((address_space(3))) unsigned int*)(l),
      16, 0, 0);
}

// rp[k] = r^(k+1), k=0..15, via full-rate mul tree (depth <= 4)
__device__ __forceinline__ void rpowers(float r, float* rp) {
  float r2 = r * r, r4 = r2 * r2, r8 = r4 * r4;
  rp[0] = r;        rp[1] = r2;       rp[2] = r2 * r;   rp[3] = r4;
  rp[4] = r4 * r;   rp[5] = r4 * r2;  rp[6] = rp[5] * r; rp[7] = r8;
  rp[8] = r8 * r;   rp[9] = r8 * r2;  rp[10] = rp[9] * r; rp[11] = r8 * r4;
  rp[12] = rp[11] * r; rp[13] = rp[11] * r2; rp[14] = rp[13] * r; rp[15] = r8 * r8;
}

// ---------------- cast fp32 -> bf16 (vectorized) ----------------
__global__ __launch_bounds__(256) void cast_bf16_k(const float4* __restrict__ in,
                                                   ushort4* __restrict__ out, int n4) {
  int i = blockIdx.x * 256 + threadIdx.x;
  int stride = gridDim.x * 256;
  for (; i < n4; i += stride) {
    float4 v = in[i];
    ushort4 o;
    o.x = f2bf(v.x); o.y = f2bf(v.y); o.z = f2bf(v.z); o.w = f2bf(v.w);
    out[i] = o;
  }
}

// ---------------- pad+cast x_proj_w (33x2048) -> (128x2048) bf16 ----------------
__global__ __launch_bounds__(256) void pad_xw_k(const float* __restrict__ xw,
                                                unsigned short* __restrict__ xwp) {
  int i = blockIdx.x * 256 + threadIdx.x;   // grid covers 128*2048
  if (i >= 128 * 2048) return;
  int row = i >> 11, col = i & 2047;
  xwp[i] = (row < 33) ? f2bf(xw[row * 2048 + col]) : (unsigned short)0;
}

// ================= 8-phase 256x256 BK=64 MFMA GEMM (T3+T4+T2+T5) =================
// C[M][N] = A[M][K] * B[N][K]^T. 512 threads = 8 waves (2x4). LDS 128 KiB:
// 2 dbuf x {A,B} x 2 halves x [128][64] bf16. Per K-tile: 4 phases = C-quadrants
// in Gray order (0,0)(0,1)(1,1)(1,0); each phase reads one A-half + one B-half,
// stages exactly one half-tile of a FUTURE tile into a provably-dead region:
//   p0: A1(t+1)  p1: B0(t+1)  p2: A0(t+2)  p3: B1(t+2)
// One counted vmcnt(4) per tile boundary (drain 0 only at tail).
// LDS swizzle: 16B-slot ^= (row&7), inverse-applied on the global source.
template <bool BF16OUT, bool SWZ>
__global__ __launch_bounds__(512) void gemm8p(
    const unsigned short* __restrict__ A, const unsigned short* __restrict__ B,
    void* __restrict__ Cv, int M, int N, int K)
{
  __shared__ __align__(16) unsigned short As[2][2][8192];
  __shared__ __align__(16) unsigned short Bs[2][2][8192];
  const int tid = threadIdx.x;

  const int grid_m = M >> 8, grid_n = N >> 8;
  const int nwg = grid_m * grid_n;
  int wid = blockIdx.x;
  if (SWZ) { int q = nwg >> 3; wid = (wid & 7) * q + (wid >> 3); }  // nwg % 8 == 0
  const int GM = 8;
  const int nig = GM * grid_n;
  const int gidg = wid / nig;
  const int rem = wid - gidg * nig;
  const int fm = gidg * GM;
  const int gsz = (grid_m - fm < GM) ? (grid_m - fm) : GM;
  const int pm = fm + rem % gsz;
  const int pn = rem / gsz;
  const int m0 = pm << 8, n0 = pn << 8;

  const int NT = K >> 6;

  const int wq = tid >> 6, l = tid & 63;
  const int wr2 = wq >> 2, wc2 = wq & 3;
  const int lr = l & 15, q16 = l >> 4;
  const int sw = lr & 7;

  const unsigned short* aH0 = A + (size_t)m0 * K;
  const unsigned short* aH1 = A + (size_t)(m0 + 128) * K;
  const unsigned short* bH0 = B + (size_t)n0 * K;
  const unsigned short* bH1 = B + (size_t)(n0 + 128) * K;

#define STAGE8(srcbase, dstp, kt)                                              \
  { _Pragma("unroll") for (int i = 0; i < 2; ++i) {                            \
      int q = tid + 512 * i; int rw = q >> 3; int ssl = (q & 7) ^ (rw & 7);    \
      gload_lds16((srcbase) + (size_t)rw * K + (size_t)(kt) * 64 + ssl * 8,    \
                  (dstp) + q * 8); } }

#define LDA8(dd, MH)                                                           \
  { _Pragma("unroll") for (int mi = 0; mi < 4; ++mi) {                         \
      int ar = (wr2 * 64 + mi * 16 + lr) * 64;                                 \
      _Pragma("unroll") for (int ks = 0; ks < 2; ++ks)                         \
        af[mi][ks] = *(const bf16x8*)&As[dd][MH][ar + (((ks * 4 + q16) ^ sw) << 3)]; } }

#define LDB8(dd, NH)                                                           \
  { _Pragma("unroll") for (int ni = 0; ni < 2; ++ni) {                         \
      int br = (wc2 * 32 + ni * 16 + lr) * 64;                                 \
      _Pragma("unroll") for (int ks = 0; ks < 2; ++ks)                         \
        bf[NH][ni][ks] = *(const bf16x8*)&Bs[dd][NH][br + (((ks * 4 + q16) ^ sw) << 3)]; } }

#define MMA8(MH, NH)                                                           \
  { __builtin_amdgcn_s_setprio(1);                                             \
    _Pragma("unroll") for (int mi = 0; mi < 4; ++mi)                           \
    _Pragma("unroll") for (int ni = 0; ni < 2; ++ni)                           \
    _Pragma("unroll") for (int ks = 0; ks < 2; ++ks)                           \
      acc[MH][NH][mi][ni] = __builtin_amdgcn_mfma_f32_16x16x32_bf16(           \
          af[mi][ks], bf[NH][ni][ks], acc[MH][NH][mi][ni], 0, 0, 0);           \
    __builtin_amdgcn_s_setprio(0); }

  f32x4 acc[2][2][4][2];
#pragma unroll
  for (int a = 0; a < 2; ++a)
#pragma unroll
    for (int b = 0; b < 2; ++b)
#pragma unroll
      for (int c = 0; c < 4; ++c)
#pragma unroll
        for (int d = 0; d < 2; ++d)
          acc[a][b][c][d] = (f32x4){0.f, 0.f, 0.f, 0.f};

  bf16x8 af[4][2];
  bf16x8 bf[2][2][2];

  // ---- prologue: stream order A0_0, B1_0, A1_0, B0_0, [A0_1, B1_1] ----
  STAGE8(aH0, As[0][0], 0);
  STAGE8(bH1, Bs[0][1], 0);
  STAGE8(aH1, As[0][1], 0);
  STAGE8(bH0, Bs[0][0], 0);
  if (NT > 1) {
    STAGE8(aH0, As[1][0], 1);
    STAGE8(bH1, Bs[1][1], 1);
    asm volatile("s_waitcnt vmcnt(4)" ::: "memory");
  } else {
    asm volatile("s_waitcnt vmcnt(0)" ::: "memory");
  }
  __builtin_amdgcn_s_barrier();

  for (int t = 0; t < NT; ++t) {
    const int d = t & 1;
    // ---- phase 0: quadrant (0,0) ----
    LDA8(d, 0); LDB8(d, 0);
    if (t + 1 < NT) STAGE8(aH1, As[(t + 1) & 1][1], t + 1);
    __builtin_amdgcn_s_barrier();
    MMA8(0, 0);
    __builtin_amdgcn_s_barrier();
    // ---- phase 1: quadrant (0,1) ----
    LDB8(d, 1);
    if (t + 1 < NT) STAGE8(bH0, Bs[(t + 1) & 1][0], t + 1);
    __builtin_amdgcn_s_barrier();
    MMA8(0, 1);
    __builtin_amdgcn_s_barrier();
    // ---- phase 2: quadrant (1,1) ----
    LDA8(d, 1);
    if (t + 2 < NT) STAGE8(aH0, As[d][0], t + 2);
    __builtin_amdgcn_s_barrier();
    MMA8(1, 1);
    __builtin_amdgcn_s_barrier();
    // ---- phase 3: quadrant (1,0) ----
    if (t + 2 < NT) STAGE8(bH1, Bs[d][1], t + 2);
    __builtin_amdgcn_s_barrier();
    MMA8(1, 0);
    __builtin_amdgcn_s_barrier();
    // ---- tile boundary: counted wait (never 0 in steady state) ----
    if (t + 2 < NT) asm volatile("s_waitcnt vmcnt(4)" ::: "memory");
    else            asm volatile("s_waitcnt vmcnt(0)" ::: "memory");
    __builtin_amdgcn_s_barrier();
  }

  // ---- epilogue ----
#pragma unroll
  for (int mh = 0; mh < 2; ++mh)
#pragma unroll
    for (int nh = 0; nh < 2; ++nh)
#pragma unroll
      for (int mi = 0; mi < 4; ++mi)
#pragma unroll
        for (int ni = 0; ni < 2; ++ni) {
          int gr = m0 + mh * 128 + wr2 * 64 + mi * 16 + q16 * 4;
          int gc = n0 + nh * 128 + wc2 * 32 + ni * 16 + lr;
#pragma unroll
          for (int j = 0; j < 4; ++j) {
            if (BF16OUT)
              ((unsigned short*)Cv)[(size_t)(gr + j) * N + gc] = f2bf(acc[mh][nh][mi][ni][j]);
            else
              ((float*)Cv)[(size_t)(gr + j) * N + gc] = acc[mh][nh][mi][ni][j];
          }
        }
#undef STAGE8
#undef LDA8
#undef LDB8
#undef MMA8
}

// ---------------- 2-phase 128x128 GEMM (kept for out_proj + split-K x_proj) ----------------
template <bool BF16OUT, bool SWZ>
__global__ __launch_bounds__(256) void gemm2p(
    const unsigned short* __restrict__ A, const unsigned short* __restrict__ B,
    void* __restrict__ Cv, int M, int N, int K)
{
  __shared__ __align__(16) unsigned short AsB[3 * 128 * 32];
  __shared__ __align__(16) unsigned short BsB[3 * 128 * 32];
  const int tid = threadIdx.x;

  const int grid_m = M >> 7, grid_n = N >> 7;
  const int nwg = grid_m * grid_n;
  int wid = blockIdx.x;
  if (SWZ) { int q = nwg >> 3; wid = (wid & 7) * q + (wid >> 3); }  // nwg % 8 == 0
  const int GM = 16;
  const int nig = GM * grid_n;
  const int gidg = wid / nig;
  const int rem = wid - gidg * nig;
  const int fm = gidg * GM;
  const int gsz = (grid_m - fm < GM) ? (grid_m - fm) : GM;
  const int pm = fm + rem % gsz;
  const int pn = rem / gsz;
  const int m0 = pm << 7, n0 = pn << 7;

  const int kseg = K / gridDim.z;
  const int kbeg = blockIdx.z * kseg;
  const int NT = kseg >> 5;

  const int w = tid >> 6, l = tid & 63;
  const int wr = w >> 1, wc = w & 1;
  const int lr = l & 15, kk = (l >> 4) * 8;

  f32x4 acc[4][4];
#pragma unroll
  for (int mi = 0; mi < 4; ++mi)
#pragma unroll
    for (int ni = 0; ni < 4; ++ni)
      acc[mi][ni] = (f32x4){0.f, 0.f, 0.f, 0.f};

#pragma unroll
  for (int tt = 0; tt < 2; ++tt) {
    unsigned short* as = AsB + tt * 4096;
    unsigned short* bs = BsB + tt * 4096;
    int k0 = kbeg + tt * 32;
#pragma unroll
    for (int i = 0; i < 2; ++i) {
      int q = tid + 256 * i;
      int row = q >> 2, sub = (q & 3) ^ ((q >> 3) & 3);
      gload_lds16(A + (size_t)(m0 + row) * K + k0 + sub * 8, as + q * 8);
      gload_lds16(B + (size_t)(n0 + row) * K + k0 + sub * 8, bs + q * 8);
    }
  }
  asm volatile("s_waitcnt vmcnt(4)\n\ts_barrier" ::: "memory");

  for (int t = 0; t < NT; ++t) {
    if (t + 2 < NT) {
      unsigned short* as = AsB + ((t + 2) % 3) * 4096;
      unsigned short* bs = BsB + ((t + 2) % 3) * 4096;
      int k0 = kbeg + (t + 2) * 32;
#pragma unroll
      for (int i = 0; i < 2; ++i) {
        int q = tid + 256 * i;
        int row = q >> 2, sub = (q & 3) ^ ((q >> 3) & 3);
        gload_lds16(A + (size_t)(m0 + row) * K + k0 + sub * 8, as + q * 8);
        gload_lds16(B + (size_t)(n0 + row) * K + k0 + sub * 8, bs + q * 8);
      }
    }
    const unsigned short* as = AsB + (t % 3) * 4096;
    const unsigned short* bs = BsB + (t % 3) * 4096;
    bf16x8 af[4], bfr[4];
#pragma unroll
    for (int mi = 0; mi < 4; ++mi) {
      int row = wr * 64 + mi * 16 + lr;
      int col = kk ^ (((row >> 1) & 3) << 3);
      af[mi] = *(const bf16x8*)&as[row * 32 + col];
    }
#pragma unroll
    for (int ni = 0; ni < 4; ++ni) {
      int row = wc * 64 + ni * 16 + lr;
      int col = kk ^ (((row >> 1) & 3) << 3);
      bfr[ni] = *(const bf16x8*)&bs[row * 32 + col];
    }
    __builtin_amdgcn_s_setprio(1);
#pragma unroll
    for (int mi = 0; mi < 4; ++mi)
#pragma unroll
      for (int ni = 0; ni < 4; ++ni)
        acc[mi][ni] = __builtin_amdgcn_mfma_f32_16x16x32_bf16(af[mi], bfr[ni], acc[mi][ni], 0, 0, 0);
    __builtin_amdgcn_s_setprio(0);
    if (t + 1 < NT) {
      if (t + 2 < NT) asm volatile("s_waitcnt vmcnt(4)\n\ts_barrier" ::: "memory");
      else            asm volatile("s_waitcnt vmcnt(0)\n\ts_barrier" ::: "memory");
    }
  }

#pragma unroll
  for (int mi = 0; mi < 4; ++mi)
#pragma unroll
    for (int ni = 0; ni < 4; ++ni) {
      int gr = m0 + wr * 64 + mi * 16 + (l >> 4) * 4;
      int gc = n0 + wc * 64 + ni * 16 + (l & 15);
#pragma unroll
      for (int j = 0; j < 4; ++j) {
        if (BF16OUT)
          ((unsigned short*)Cv)[(size_t)(gr + j) * N + gc] = f2bf(acc[mi][ni][j]);
        else
          ((float*)Cv + (size_t)blockIdx.z * M * N)[(size_t)(gr + j) * N + gc] = acc[mi][ni][j];
      }
    }
}

// reduce 4 partial C buffers -> dbc (1M floats, float4)
__global__ __launch_bounds__(256) void redux4_k(const float4* __restrict__ part,
                                                float4* __restrict__ out) {
  int i = blockIdx.x * 256 + threadIdx.x;   // 262144 float4
  const int STR = 262144;
  float4 a = part[i], b = part[i + STR], c = part[i + 2 * STR], d = part[i + 3 * STR];
  out[i] = make_float4(a.x + b.x + c.x + d.x, a.y + b.y + c.y + d.y,
                       a.z + b.z + c.z + d.z, a.w + b.w + c.w + d.w);
}

// ---------------- depthwise causal conv(4) + bias + SiLU (bf16 in/out) ----------------
#define CONV_L 16
__global__ __launch_bounds__(256) void conv_silu_k(
    const unsigned short* __restrict__ xzb, const float* __restrict__ cw,
    const float* __restrict__ cb, unsigned short* __restrict__ xsb)
{
  const int b = blockIdx.y;
  const int l0 = blockIdx.x * CONV_L;
  const int d = threadIdx.x * 8;
  float w[4][8], bias[8];
#pragma unroll
  for (int i = 0; i < 8; ++i) {
    bias[i] = cb[d + i];
#pragma unroll
    for (int j = 0; j < 4; ++j) w[j][i] = cw[(d + i) * 4 + j];
  }
  const size_t rb = (size_t)b * 4096;
  float win[3][8];
#pragma unroll
  for (int j = 0; j < 3; ++j) {
    int l = l0 - 3 + j;
    if (l >= 0) {
      u16x8 v = *(const u16x8*)(xzb + (rb + l) * 4096 + d);
#pragma unroll
      for (int i = 0; i < 8; ++i) win[j][i] = bf2f(v[i]);
    } else {
#pragma unroll
      for (int i = 0; i < 8; ++i) win[j][i] = 0.f;
    }
  }
  for (int l = l0; l < l0 + CONV_L; ++l) {
    u16x8 v = *(const u16x8*)(xzb + (rb + l) * 4096 + d);
    float cur[8]; u16x8 ob;
#pragma unroll
    for (int i = 0; i < 8; ++i) {
      cur[i] = bf2f(v[i]);
      float u = bias[i] + w[0][i] * win[0][i] + w[1][i] * win[1][i]
                        + w[2][i] * win[2][i] + w[3][i] * cur[i];
      float s = u / (1.f + __expf(-u));
      ob[i] = f2bf(s);
    }
    *(u16x8*)(xsb + (rb + l) * 2048 + d) = ob;
#pragma unroll
    for (int i = 0; i < 8; ++i) { win[0][i] = win[1][i]; win[1][i] = win[2][i]; win[2][i] = cur[i]; }
  }
}

// ---------------- chunk-parallel selective scan ----------------
__global__ __launch_bounds__(256) void scan_p1(
    const unsigned short* __restrict__ xsb16, const float* __restrict__ dbc,
    const float* __restrict__ dtw, const float* __restrict__ dtb,
    const float* __restrict__ alog,
    float* __restrict__ Sg, float* __restrict__ cdg)
{
  const int chunk = blockIdx.x;
  const int d0 = blockIdx.y * 256;
  const int b = blockIdx.z;
  const int tid = threadIdx.x;
  const size_t rowbase = (size_t)b * 4096 + chunk * TC;

  __shared__ __align__(16) unsigned short xsS[TH][256];
  __shared__ __align__(16) float bS[TC][16];
  __shared__ float drS[TC];

  if (tid < TC) drS[tid] = dbc[(rowbase + tid) * 128];
  for (int i = tid; i < TC * 16; i += 256) {
    int t = i >> 4, q = i & 15;
    bS[t][q] = dbc[(rowbase + t) * 128 + 1 + q];
  }

  const int d = d0 + tid;
  const float wdt = dtw[d], bdt = dtb[d];
  float adn[16];
  bool ok = true;
#pragma unroll
  for (int k = 0; k < 4; ++k) {
    float4 a4 = *(const float4*)(alog + (size_t)d * 16 + k * 4);
    adn[4 * k + 0] = -__expf(a4.x); adn[4 * k + 1] = -__expf(a4.y);
    adn[4 * k + 2] = -__expf(a4.z); adn[4 * k + 3] = -__expf(a4.w);
  }
#pragma unroll
  for (int n = 0; n < 16; ++n)
    ok = ok && (fabsf(adn[n] + (float)(n + 1)) <= 1e-3f * (float)(n + 1));

  float h[16];
#pragma unroll
  for (int n = 0; n < 16; ++n) h[n] = 0.f;
  float cd = 0.f;

  for (int half = 0; half < 2; ++half) {
    if (half) __syncthreads();
    for (int i = tid; i < TH * 32; i += 256) {
      int tt = i >> 5, q = i & 31;
      *(u16x8*)&xsS[tt][q * 8] =
          *(const u16x8*)(xsb16 + (rowbase + half * TH + tt) * 2048 + d0 + q * 8);
    }
    __syncthreads();

    if (ok) {
      for (int tt = 0; tt < TH; ++tt) {
        int t = half * TH + tt;
        float pre = fmaf(drS[t], wdt, bdt);
        float e = __expf(pre);
        float dlt = (pre > 20.f) ? pre : __logf(1.f + e);
        float xv = bf2f(xsS[tt][tid]);
        float dx = dlt * xv;
        cd += dlt;
        float r = __expf(-dlt);
        float rp[16];
        rpowers(r, rp);
        f32x4 Bv[4];
#pragma unroll
        for (int k = 0; k < 4; ++k) Bv[k] = ((const f32x4*)&bS[t][0])[k];
#pragma unroll
        for (int n = 0; n < 16; ++n)
          h[n] = fmaf(rp[n], h[n], dx * Bv[n >> 2][n & 3]);
      }
    } else {
      for (int tt = 0; tt < TH; ++tt) {
        int t = half * TH + tt;
        float pre = fmaf(drS[t], wdt, bdt);
        float e = __expf(pre);
        float dlt = (pre > 20.f) ? pre : __logf(1.f + e);
        float xv = bf2f(xsS[tt][tid]);
        float dx = dlt * xv;
        cd += dlt;
        f32x4 Bv[4];
#pragma unroll
        for (int k = 0; k < 4; ++k) Bv[k] = ((const f32x4*)&bS[t][0])[k];
#pragma unroll
        for (int n = 0; n < 16; ++n) {
          float dA = __expf(adn[n] * dlt);
          h[n] = fmaf(dA, h[n], dx * Bv[n >> 2][n & 3]);
        }
      }
    }
  }
  cdg[(size_t)(b * NC + chunk) * 2048 + d] = cd;
  float* Sp = Sg + ((size_t)(b * NC + chunk) * 32768 + (size_t)d * 16);
#pragma unroll
  for (int k = 0; k < 4; ++k)
    ((float4*)Sp)[k] = make_float4(h[4 * k], h[4 * k + 1], h[4 * k + 2], h[4 * k + 3]);
}

__global__ __launch_bounds__(256) void scan_p2(
    const float* __restrict__ Sg, const float* __restrict__ cdg,
    const float* __restrict__ alog, float* __restrict__ Hg)
{
  int g = blockIdx.x * 256 + threadIdx.x;   // 65536 = B*D*N
  int b = g >> 15, dn = g & 32767;
  int d = dn >> 4;
  float adn = -__expf(alog[dn]);
  float h = 0.f;
  for (int c = 0; c < NC; ++c) {
    size_t o = (size_t)(b * NC + c) * 32768 + dn;
    float P = __expf(adn * cdg[(size_t)(b * NC + c) * 2048 + d]);
    Hg[o] = h;
    h = fmaf(P, h, Sg[o]);
  }
}

__global__ __launch_bounds__(256) void scan_p3(
    const unsigned short* __restrict__ xsb16, const float* __restrict__ dbc,
    const float* __restrict__ dtw, const float* __restrict__ dtb,
    const float* __restrict__ alog, const float* __restrict__ Dp,
    const unsigned short* __restrict__ xzb, const float* __restrict__ Hg,
    unsigned short* __restrict__ gb)
{
  const int chunk = blockIdx.x;
  const int d0 = blockIdx.y * 256;
  const int b = blockIdx.z;
  const int tid = threadIdx.x;
  const size_t rowbase = (size_t)b * 4096 + chunk * TC;

  __shared__ __align__(16) unsigned short xsS[TH][256];
  __shared__ __align__(16) float bcS[TC][32];

  for (int i = tid; i < TC * 32; i += 256) {
    int t = i >> 5, q = i & 31;
    bcS[t][q] = dbc[(rowbase + t) * 128 + 1 + q];
  }

  const int d = d0 + tid;
  const float wdt = dtw[d], bdt = dtb[d], Dd = Dp[d];
  const float* __restrict__ drp = dbc + rowbase * 128;
  float adn[16];
  bool ok = true;
#pragma unroll
  for (int k = 0; k < 4; ++k) {
    float4 a4 = *(const float4*)(alog + (size_t)d * 16 + k * 4);
    adn[4 * k + 0] = -__expf(a4.x); adn[4 * k + 1] = -__expf(a4.y);
    adn[4 * k + 2] = -__expf(a4.z); adn[4 * k + 3] = -__expf(a4.w);
  }
#pragma unroll
  for (int n = 0; n < 16; ++n)
    ok = ok && (fabsf(adn[n] + (float)(n + 1)) <= 1e-3f * (float)(n + 1));

  float h[16];
  {
    const float* Hp = Hg + ((size_t)(b * NC + chunk) * 32768 + (size_t)d * 16);
#pragma unroll
    for (int k = 0; k < 4; ++k) {
      float4 h4 = ((const float4*)Hp)[k];
      h[4 * k + 0] = h4.x; h[4 * k + 1] = h4.y; h[4 * k + 2] = h4.z; h[4 * k + 3] = h4.w;
    }
  }

  for (int half = 0; half < 2; ++half) {
    if (half) __syncthreads();
    for (int i = tid; i < TH * 32; i += 256) {
      int tt = i >> 5, q = i & 31;
      *(u16x8*)&xsS[tt][q * 8] =
          *(const u16x8*)(xsb16 + (rowbase + half * TH + tt) * 2048 + d0 + q * 8);
    }
    __syncthreads();

    if (ok) {
      for (int tt = 0; tt < TH; ++tt) {
        int t = half * TH + tt;
        float pre = fmaf(drp[(size_t)t * 128], wdt, bdt);
        float e = __expf(pre);
        float dlt = (pre > 20.f) ? pre : __logf(1.f + e);
        float xv = bf2f(xsS[tt][tid]);
        float dx = dlt * xv;
        float r = __expf(-dlt);
        float rp[16];
        rpowers(r, rp);
        f32x4 Bv[4], Cv[4];
#pragma unroll
        for (int k = 0; k < 4; ++k) {
          Bv[k] = ((const f32x4*)&bcS[t][0])[k];
          Cv[k] = ((const f32x4*)&bcS[t][16])[k];
        }
        float yp[4];
        yp[0] = Dd * xv; yp[1] = 0.f; yp[2] = 0.f; yp[3] = 0.f;
#pragma unroll
        for (int n = 0; n < 16; ++n) {
          h[n] = fmaf(rp[n], h[n], dx * Bv[n >> 2][n & 3]);
          yp[n & 3] = fmaf(h[n], Cv[n >> 2][n & 3], yp[n & 3]);
        }
        float y = (yp[0] + yp[1]) + (yp[2] + yp[3]);
        xsS[tt][tid] = f2bf(y);
      }
    } else {
      for (int tt = 0; tt < TH; ++tt) {
        int t = half * TH + tt;
        float pre = fmaf(drp[(size_t)t * 128], wdt, bdt);
        float e = __expf(pre);
        float dlt = (pre > 20.f) ? pre : __logf(1.f + e);
        float xv = bf2f(xsS[tt][tid]);
        float dx = dlt * xv;
        f32x4 Bv[4], Cv[4];
#pragma unroll
        for (int k = 0; k < 4; ++k) {
          Bv[k] = ((const f32x4*)&bcS[t][0])[k];
          Cv[k] = ((const f32x4*)&bcS[t][16])[k];
        }
        float yp[4];
        yp[0] = Dd * xv; yp[1] = 0.f; yp[2] = 0.f; yp[3] = 0.f;
#pragma unroll
        for (int n = 0; n < 16; ++n) {
          float dA = __expf(adn[n] * dlt);
          h[n] = fmaf(dA, h[n], dx * Bv[n >> 2][n & 3]);
          yp[n & 3] = fmaf(h[n], Cv[n >> 2][n & 3], yp[n & 3]);
        }
        float y = (yp[0] + yp[1]) + (yp[2] + yp[3]);
        xsS[tt][tid] = f2bf(y);
      }
    }
    __syncthreads();

    for (int i = tid; i < TH * 32; i += 256) {
      int tt = i >> 5, q = i & 31;
      size_t row = rowbase + half * TH + tt;
      u16x8 yv = *(const u16x8*)&xsS[tt][q * 8];
      u16x8 zv = *(const u16x8*)(xzb + row * 4096 + 2048 + d0 + q * 8);
      u16x8 ov;
#pragma unroll
      for (int j = 0; j < 8; ++j) {
        float z = bf2f(zv[j]);
        float s = z / (1.f + __expf(-z));
        ov[j] = f2bf(bf2f(yv[j]) * s);
      }
      *(u16x8*)(gb + row * 2048 + d0 + q * 8) = ov;
    }
  }
}

extern "C" void kernel_launch(void* const* d_in, const int* in_sizes, int n_in,
                              void* d_out, int out_size, void* d_ws, size_t ws_size,
                              hipStream_t stream) {
  const float* x    = (const float*)d_in[0];
  const float* ipw  = (const float*)d_in[1];
  const float* cw   = (const float*)d_in[2];
  const float* cb   = (const float*)d_in[3];
  const float* xpw  = (const float*)d_in[4];
  const float* dtw  = (const float*)d_in[5];
  const float* dtb  = (const float*)d_in[6];
  const float* alog = (const float*)d_in[7];
  const float* Dp   = (const float*)d_in[8];
  const float* opw  = (const float*)d_in[9];
  float* out = (float*)d_out;

  char* p = (char*)d_ws;
  unsigned short* xb   = (unsigned short*)p; p += (size_t)8388608 * 2;   // x bf16 (16 MiB) — reused as Hg
  unsigned short* wb1  = (unsigned short*)p; p += (size_t)4194304 * 2;   // in_proj_w bf16   (8 MiB)
  unsigned short* wb2  = (unsigned short*)p; p += (size_t)2097152 * 2;   // out_proj_w bf16  (4 MiB)
  unsigned short* xwp  = (unsigned short*)p; p += (size_t)262144 * 2;    // padded x_proj_w  (0.5 MiB)
  unsigned short* xzb  = (unsigned short*)p; p += (size_t)33554432 * 2;  // in_proj out bf16 (64 MiB)
  unsigned short* xsb16= (unsigned short*)p; p += (size_t)16777216 * 2;  // conv+silu bf16   (32 MiB)
  float*          dbc  = (float*)p;          p += (size_t)1048576 * 4;   // x_proj out fp32  (4 MiB)
  unsigned short* gb   = (unsigned short*)p; p += (size_t)16777216 * 2;  // y*silu(z) bf16   (32 MiB)
  float*          Sg   = (float*)p;          p += (size_t)4194304 * 4;   // chunk states     (16 MiB)
  float*          cdg  = (float*)p;          p += (size_t)262144 * 4;    // chunk decay sums (1 MiB)
  float*          Hg   = (float*)xb;                                     // chunk entry states (aliases xb)
  float*          dbcp = Sg;                                             // 4 split-K partials (alias Sg)

  cast_bf16_k<<<1024, 256, 0, stream>>>((const float4*)x,   (ushort4*)xb,  8388608 / 4);
  cast_bf16_k<<<1024, 256, 0, stream>>>((const float4*)ipw, (ushort4*)wb1, 4194304 / 4);
  cast_bf16_k<<<512,  256, 0, stream>>>((const float4*)opw, (ushort4*)wb2, 2097152 / 4);
  pad_xw_k<<<1024, 256, 0, stream>>>(xpw, xwp);

  gemm8p<true, true><<<512, 512, 0, stream>>>(xb, wb1, xzb, 8192, 4096, 1024);
  conv_silu_k<<<dim3(4096 / CONV_L, 2), 256, 0, stream>>>(xzb, cw, cb, xsb16);

  gemm2p<false, false><<<dim3(64, 1, 4), 256, 0, stream>>>(xsb16, xwp, dbcp, 8192, 128, 2048);
  redux4_k<<<1024, 256, 0, stream>>>((const float4*)dbcp, (float4*)dbc);

  scan_p1<<<dim3(NC, 8, 2), 256, 0, stream>>>(xsb16, dbc, dtw, dtb, alog, Sg, cdg);
  scan_p2<<<256, 256, 0, stream>>>(Sg, cdg, alog, Hg);
  scan_p3<<<dim3(NC, 8, 2), 256, 0, stream>>>(xsb16, dbc, dtw, dtb, alog, Dp, xzb, Hg, gb);

  gemm2p<false, true><<<dim3(512, 1, 1), 256, 0, stream>>>(gb, wb2, out, 8192, 1024, 2048);
}

// Round 10
// 294.359 us; speedup vs baseline: 7.9203x; 1.0027x over previous
//
#include <hip/hip_runtime.h>
#include <hip/hip_bf16.h>
#include <stdint.h>

typedef __bf16 bf16x8 __attribute__((ext_vector_type(8)));
typedef float  f32x4  __attribute__((ext_vector_type(4)));
typedef unsigned short u16x8 __attribute__((ext_vector_type(8)));

#define TC 64   // timesteps per chunk
#define NC 64   // chunks (TC*NC == 4096)
#define TH 32   // staged half

__device__ __forceinline__ unsigned short f2bf(float f) {
  unsigned u = __builtin_bit_cast(unsigned, f);
  unsigned r = (u + 0x7fffu + ((u >> 16) & 1u)) >> 16;
  return (unsigned short)r;
}
__device__ __forceinline__ float bf2f(unsigned short s) {
  unsigned u = ((unsigned)s) << 16;
  return __builtin_bit_cast(float, u);
}

__device__ __forceinline__ void gload_lds16(const void* g, void* l) {
  __builtin_amdgcn_global_load_lds(
      (const __attribute__((address_space(1))) unsigned int*)(g),
      (__attribute__((address_space(3))) unsigned int*)(l),
      16, 0, 0);
}

// rp[k] = r^(k+1), k=0..15, via full-rate mul tree (depth <= 4)
__device__ __forceinline__ void rpowers(float r, float* rp) {
  float r2 = r * r, r4 = r2 * r2, r8 = r4 * r4;
  rp[0] = r;        rp[1] = r2;       rp[2] = r2 * r;   rp[3] = r4;
  rp[4] = r4 * r;   rp[5] = r4 * r2;  rp[6] = rp[5] * r; rp[7] = r8;
  rp[8] = r8 * r;   rp[9] = r8 * r2;  rp[10] = rp[9] * r; rp[11] = r8 * r4;
  rp[12] = rp[11] * r; rp[13] = rp[11] * r2; rp[14] = rp[13] * r; rp[15] = r8 * r8;
}

// ---------------- fused prep: casts + pad (one launch) ----------------
__global__ __launch_bounds__(256) void prep_k(
    const float4* __restrict__ x, const float4* __restrict__ ipw,
    const float4* __restrict__ opw, const float* __restrict__ xpw,
    ushort4* __restrict__ xb, ushort4* __restrict__ wb1,
    ushort4* __restrict__ wb2, unsigned short* __restrict__ xwp)
{
  const int r = blockIdx.y;
  int i = blockIdx.x * 256 + threadIdx.x;
  const int stride = gridDim.x * 256;
  if (r == 0) {
    for (; i < 2097152; i += stride) {
      float4 v = x[i]; ushort4 o;
      o.x = f2bf(v.x); o.y = f2bf(v.y); o.z = f2bf(v.z); o.w = f2bf(v.w);
      xb[i] = o;
    }
  } else if (r == 1) {
    for (; i < 1048576; i += stride) {
      float4 v = ipw[i]; ushort4 o;
      o.x = f2bf(v.x); o.y = f2bf(v.y); o.z = f2bf(v.z); o.w = f2bf(v.w);
      wb1[i] = o;
    }
  } else if (r == 2) {
    for (; i < 524288; i += stride) {
      float4 v = opw[i]; ushort4 o;
      o.x = f2bf(v.x); o.y = f2bf(v.y); o.z = f2bf(v.z); o.w = f2bf(v.w);
      wb2[i] = o;
    }
  } else {
    for (; i < 262144; i += stride) {
      int row = i >> 11, col = i & 2047;
      xwp[i] = (row < 33) ? f2bf(xpw[row * 2048 + col]) : (unsigned short)0;
    }
  }
}

// ================= 8-phase 256x256 BK=64 MFMA GEMM (T2+T3+T4+T5) =================
// Single barrier per phase: wave skew < 1 phase; every STAGE target is provably
// untouched by any concurrent reader (ledger in session notes). Boundary
// vmcnt(4)+barrier covers async gload_lds arrival: each boundary drains exactly
// through tile t+1's stages, leaving tile t+2's two stages in flight.
template <bool BF16OUT, bool SWZ>
__global__ __launch_bounds__(512) void gemm8p(
    const unsigned short* __restrict__ A, const unsigned short* __restrict__ B,
    void* __restrict__ Cv, int M, int N, int K)
{
  __shared__ __align__(16) unsigned short As[2][2][8192];
  __shared__ __align__(16) unsigned short Bs[2][2][8192];
  const int tid = threadIdx.x;

  const int grid_m = M >> 8, grid_n = N >> 8;
  const int nwg = grid_m * grid_n;
  int wid = blockIdx.x;
  if (SWZ) { int q = nwg >> 3; wid = (wid & 7) * q + (wid >> 3); }  // nwg % 8 == 0
  const int GM = 8;
  const int nig = GM * grid_n;
  const int gidg = wid / nig;
  const int rem = wid - gidg * nig;
  const int fm = gidg * GM;
  const int gsz = (grid_m - fm < GM) ? (grid_m - fm) : GM;
  const int pm = fm + rem % gsz;
  const int pn = rem / gsz;
  const int m0 = pm << 8, n0 = pn << 8;

  const int NT = K >> 6;

  const int wq = tid >> 6, l = tid & 63;
  const int wr2 = wq >> 2, wc2 = wq & 3;
  const int lr = l & 15, q16 = l >> 4;
  const int sw = lr & 7;

  const unsigned short* aH0 = A + (size_t)m0 * K;
  const unsigned short* aH1 = A + (size_t)(m0 + 128) * K;
  const unsigned short* bH0 = B + (size_t)n0 * K;
  const unsigned short* bH1 = B + (size_t)(n0 + 128) * K;

#define STAGE8(srcbase, dstp, kt)                                              \
  { _Pragma("unroll") for (int i = 0; i < 2; ++i) {                            \
      int q = tid + 512 * i; int rw = q >> 3; int ssl = (q & 7) ^ (rw & 7);    \
      gload_lds16((srcbase) + (size_t)rw * K + (size_t)(kt) * 64 + ssl * 8,    \
                  (dstp) + q * 8); } }

#define LDA8(dd, MH)                                                           \
  { _Pragma("unroll") for (int mi = 0; mi < 4; ++mi) {                         \
      int ar = (wr2 * 64 + mi * 16 + lr) * 64;                                 \
      _Pragma("unroll") for (int ks = 0; ks < 2; ++ks)                         \
        af[mi][ks] = *(const bf16x8*)&As[dd][MH][ar + (((ks * 4 + q16) ^ sw) << 3)]; } }

#define LDB8(dd, NH)                                                           \
  { _Pragma("unroll") for (int ni = 0; ni < 2; ++ni) {                         \
      int br = (wc2 * 32 + ni * 16 + lr) * 64;                                 \
      _Pragma("unroll") for (int ks = 0; ks < 2; ++ks)                         \
        bf[NH][ni][ks] = *(const bf16x8*)&Bs[dd][NH][br + (((ks * 4 + q16) ^ sw) << 3)]; } }

#define MMA8(MH, NH)                                                           \
  { __builtin_amdgcn_s_setprio(1);                                             \
    _Pragma("unroll") for (int mi = 0; mi < 4; ++mi)                           \
    _Pragma("unroll") for (int ni = 0; ni < 2; ++ni)                           \
    _Pragma("unroll") for (int ks = 0; ks < 2; ++ks)                           \
      acc[MH][NH][mi][ni] = __builtin_amdgcn_mfma_f32_16x16x32_bf16(           \
          af[mi][ks], bf[NH][ni][ks], acc[MH][NH][mi][ni], 0, 0, 0);           \
    __builtin_amdgcn_s_setprio(0); }

  f32x4 acc[2][2][4][2];
#pragma unroll
  for (int a = 0; a < 2; ++a)
#pragma unroll
    for (int b = 0; b < 2; ++b)
#pragma unroll
      for (int c = 0; c < 4; ++c)
#pragma unroll
        for (int d = 0; d < 2; ++d)
          acc[a][b][c][d] = (f32x4){0.f, 0.f, 0.f, 0.f};

  bf16x8 af[4][2];
  bf16x8 bf[2][2][2];

  // ---- prologue: stream order A0_0, B1_0, A1_0, B0_0, [A0_1, B1_1] ----
  STAGE8(aH0, As[0][0], 0);
  STAGE8(bH1, Bs[0][1], 0);
  STAGE8(aH1, As[0][1], 0);
  STAGE8(bH0, Bs[0][0], 0);
  if (NT > 1) {
    STAGE8(aH0, As[1][0], 1);
    STAGE8(bH1, Bs[1][1], 1);
    asm volatile("s_waitcnt vmcnt(4)" ::: "memory");
  } else {
    asm volatile("s_waitcnt vmcnt(0)" ::: "memory");
  }
  __builtin_amdgcn_s_barrier();

  for (int t = 0; t < NT; ++t) {
    const int d = t & 1;
    // ---- phase 0: quadrant (0,0) ----
    LDA8(d, 0); LDB8(d, 0);
    if (t + 1 < NT) STAGE8(aH1, As[(t + 1) & 1][1], t + 1);
    MMA8(0, 0);
    __builtin_amdgcn_s_barrier();
    // ---- phase 1: quadrant (0,1) ----
    LDB8(d, 1);
    if (t + 1 < NT) STAGE8(bH0, Bs[(t + 1) & 1][0], t + 1);
    MMA8(0, 1);
    __builtin_amdgcn_s_barrier();
    // ---- phase 2: quadrant (1,1) ----
    LDA8(d, 1);
    if (t + 2 < NT) STAGE8(aH0, As[d][0], t + 2);
    MMA8(1, 1);
    __builtin_amdgcn_s_barrier();
    // ---- phase 3: quadrant (1,0) — no LDS reads (reuses af, bf[0]) ----
    if (t + 2 < NT) STAGE8(bH1, Bs[d][1], t + 2);
    MMA8(1, 0);
    if (t + 2 < NT) asm volatile("s_waitcnt vmcnt(4)" ::: "memory");
    else            asm volatile("s_waitcnt vmcnt(0)" ::: "memory");
    __builtin_amdgcn_s_barrier();
  }

  // ---- epilogue ----
#pragma unroll
  for (int mh = 0; mh < 2; ++mh)
#pragma unroll
    for (int nh = 0; nh < 2; ++nh)
#pragma unroll
      for (int mi = 0; mi < 4; ++mi)
#pragma unroll
        for (int ni = 0; ni < 2; ++ni) {
          int gr = m0 + mh * 128 + wr2 * 64 + mi * 16 + q16 * 4;
          int gc = n0 + nh * 128 + wc2 * 32 + ni * 16 + lr;
#pragma unroll
          for (int j = 0; j < 4; ++j) {
            if (BF16OUT)
              ((unsigned short*)Cv)[(size_t)(gr + j) * N + gc] = f2bf(acc[mh][nh][mi][ni][j]);
            else
              ((float*)Cv)[(size_t)(gr + j) * N + gc] = acc[mh][nh][mi][ni][j];
          }
        }
#undef STAGE8
#undef LDA8
#undef LDB8
#undef MMA8
}

// ---------------- 2-phase 128x128 GEMM (out_proj + split-K x_proj) ----------------
template <bool BF16OUT, bool SWZ>
__global__ __launch_bounds__(256) void gemm2p(
    const unsigned short* __restrict__ A, const unsigned short* __restrict__ B,
    void* __restrict__ Cv, int M, int N, int K)
{
  __shared__ __align__(16) unsigned short AsB[3 * 128 * 32];
  __shared__ __align__(16) unsigned short BsB[3 * 128 * 32];
  const int tid = threadIdx.x;

  const int grid_m = M >> 7, grid_n = N >> 7;
  const int nwg = grid_m * grid_n;
  int wid = blockIdx.x;
  if (SWZ) { int q = nwg >> 3; wid = (wid & 7) * q + (wid >> 3); }  // nwg % 8 == 0
  const int GM = 16;
  const int nig = GM * grid_n;
  const int gidg = wid / nig;
  const int rem = wid - gidg * nig;
  const int fm = gidg * GM;
  const int gsz = (grid_m - fm < GM) ? (grid_m - fm) : GM;
  const int pm = fm + rem % gsz;
  const int pn = rem / gsz;
  const int m0 = pm << 7, n0 = pn << 7;

  const int kseg = K / gridDim.z;
  const int kbeg = blockIdx.z * kseg;
  const int NT = kseg >> 5;

  const int w = tid >> 6, l = tid & 63;
  const int wr = w >> 1, wc = w & 1;
  const int lr = l & 15, kk = (l >> 4) * 8;

  f32x4 acc[4][4];
#pragma unroll
  for (int mi = 0; mi < 4; ++mi)
#pragma unroll
    for (int ni = 0; ni < 4; ++ni)
      acc[mi][ni] = (f32x4){0.f, 0.f, 0.f, 0.f};

#pragma unroll
  for (int tt = 0; tt < 2; ++tt) {
    unsigned short* as = AsB + tt * 4096;
    unsigned short* bs = BsB + tt * 4096;
    int k0 = kbeg + tt * 32;
#pragma unroll
    for (int i = 0; i < 2; ++i) {
      int q = tid + 256 * i;
      int row = q >> 2, sub = (q & 3) ^ ((q >> 3) & 3);
      gload_lds16(A + (size_t)(m0 + row) * K + k0 + sub * 8, as + q * 8);
      gload_lds16(B + (size_t)(n0 + row) * K + k0 + sub * 8, bs + q * 8);
    }
  }
  asm volatile("s_waitcnt vmcnt(4)\n\ts_barrier" ::: "memory");

  for (int t = 0; t < NT; ++t) {
    if (t + 2 < NT) {
      unsigned short* as = AsB + ((t + 2) % 3) * 4096;
      unsigned short* bs = BsB + ((t + 2) % 3) * 4096;
      int k0 = kbeg + (t + 2) * 32;
#pragma unroll
      for (int i = 0; i < 2; ++i) {
        int q = tid + 256 * i;
        int row = q >> 2, sub = (q & 3) ^ ((q >> 3) & 3);
        gload_lds16(A + (size_t)(m0 + row) * K + k0 + sub * 8, as + q * 8);
        gload_lds16(B + (size_t)(n0 + row) * K + k0 + sub * 8, bs + q * 8);
      }
    }
    const unsigned short* as = AsB + (t % 3) * 4096;
    const unsigned short* bs = BsB + (t % 3) * 4096;
    bf16x8 af[4], bfr[4];
#pragma unroll
    for (int mi = 0; mi < 4; ++mi) {
      int row = wr * 64 + mi * 16 + lr;
      int col = kk ^ (((row >> 1) & 3) << 3);
      af[mi] = *(const bf16x8*)&as[row * 32 + col];
    }
#pragma unroll
    for (int ni = 0; ni < 4; ++ni) {
      int row = wc * 64 + ni * 16 + lr;
      int col = kk ^ (((row >> 1) & 3) << 3);
      bfr[ni] = *(const bf16x8*)&bs[row * 32 + col];
    }
    __builtin_amdgcn_s_setprio(1);
#pragma unroll
    for (int mi = 0; mi < 4; ++mi)
#pragma unroll
      for (int ni = 0; ni < 4; ++ni)
        acc[mi][ni] = __builtin_amdgcn_mfma_f32_16x16x32_bf16(af[mi], bfr[ni], acc[mi][ni], 0, 0, 0);
    __builtin_amdgcn_s_setprio(0);
    if (t + 1 < NT) {
      if (t + 2 < NT) asm volatile("s_waitcnt vmcnt(4)\n\ts_barrier" ::: "memory");
      else            asm volatile("s_waitcnt vmcnt(0)\n\ts_barrier" ::: "memory");
    }
  }

#pragma unroll
  for (int mi = 0; mi < 4; ++mi)
#pragma unroll
    for (int ni = 0; ni < 4; ++ni) {
      int gr = m0 + wr * 64 + mi * 16 + (l >> 4) * 4;
      int gc = n0 + wc * 64 + ni * 16 + (l & 15);
#pragma unroll
      for (int j = 0; j < 4; ++j) {
        if (BF16OUT)
          ((unsigned short*)Cv)[(size_t)(gr + j) * N + gc] = f2bf(acc[mi][ni][j]);
        else
          ((float*)Cv + (size_t)blockIdx.z * M * N)[(size_t)(gr + j) * N + gc] = acc[mi][ni][j];
      }
    }
}

// reduce 4 partial C buffers -> dbc (1M floats, float4)
__global__ __launch_bounds__(256) void redux4_k(const float4* __restrict__ part,
                                                float4* __restrict__ out) {
  int i = blockIdx.x * 256 + threadIdx.x;   // 262144 float4
  const int STR = 262144;
  float4 a = part[i], b = part[i + STR], c = part[i + 2 * STR], d = part[i + 3 * STR];
  out[i] = make_float4(a.x + b.x + c.x + d.x, a.y + b.y + c.y + d.y,
                       a.z + b.z + c.z + d.z, a.w + b.w + c.w + d.w);
}

// ---------------- depthwise causal conv(4) + bias + SiLU (bf16 in/out) ----------------
#define CONV_L 16
__global__ __launch_bounds__(256) void conv_silu_k(
    const unsigned short* __restrict__ xzb, const float* __restrict__ cw,
    const float* __restrict__ cb, unsigned short* __restrict__ xsb)
{
  const int b = blockIdx.y;
  const int l0 = blockIdx.x * CONV_L;
  const int d = threadIdx.x * 8;
  float w[4][8], bias[8];
#pragma unroll
  for (int i = 0; i < 8; ++i) {
    bias[i] = cb[d + i];
#pragma unroll
    for (int j = 0; j < 4; ++j) w[j][i] = cw[(d + i) * 4 + j];
  }
  const size_t rb = (size_t)b * 4096;
  float win[3][8];
#pragma unroll
  for (int j = 0; j < 3; ++j) {
    int l = l0 - 3 + j;
    if (l >= 0) {
      u16x8 v = *(const u16x8*)(xzb + (rb + l) * 4096 + d);
#pragma unroll
      for (int i = 0; i < 8; ++i) win[j][i] = bf2f(v[i]);
    } else {
#pragma unroll
      for (int i = 0; i < 8; ++i) win[j][i] = 0.f;
    }
  }
  for (int l = l0; l < l0 + CONV_L; ++l) {
    u16x8 v = *(const u16x8*)(xzb + (rb + l) * 4096 + d);
    float cur[8]; u16x8 ob;
#pragma unroll
    for (int i = 0; i < 8; ++i) {
      cur[i] = bf2f(v[i]);
      float u = bias[i] + w[0][i] * win[0][i] + w[1][i] * win[1][i]
                        + w[2][i] * win[2][i] + w[3][i] * cur[i];
      float s = u / (1.f + __expf(-u));
      ob[i] = f2bf(s);
    }
    *(u16x8*)(xsb + (rb + l) * 2048 + d) = ob;
#pragma unroll
    for (int i = 0; i < 8; ++i) { win[0][i] = win[1][i]; win[1][i] = win[2][i]; win[2][i] = cur[i]; }
  }
}

// ---------------- chunk-parallel selective scan ----------------
__global__ __launch_bounds__(256) void scan_p1(
    const unsigned short* __restrict__ xsb16, const float* __restrict__ dbc,
    const float* __restrict__ dtw, const float* __restrict__ dtb,
    const float* __restrict__ alog,
    float* __restrict__ Sg, float* __restrict__ cdg)
{
  const int chunk = blockIdx.x;
  const int d0 = blockIdx.y * 256;
  const int b = blockIdx.z;
  const int tid = threadIdx.x;
  const size_t rowbase = (size_t)b * 4096 + chunk * TC;

  __shared__ __align__(16) unsigned short xsS[TH][256];
  __shared__ __align__(16) float bS[TC][16];
  __shared__ float drS[TC];

  if (tid < TC) drS[tid] = dbc[(rowbase + tid) * 128];
  for (int i = tid; i < TC * 16; i += 256) {
    int t = i >> 4, q = i & 15;
    bS[t][q] = dbc[(rowbase + t) * 128 + 1 + q];
  }

  const int d = d0 + tid;
  const float wdt = dtw[d], bdt = dtb[d];
  float adn[16];
  bool ok = true;
#pragma unroll
  for (int k = 0; k < 4; ++k) {
    float4 a4 = *(const float4*)(alog + (size_t)d * 16 + k * 4);
    adn[4 * k + 0] = -__expf(a4.x); adn[4 * k + 1] = -__expf(a4.y);
    adn[4 * k + 2] = -__expf(a4.z); adn[4 * k + 3] = -__expf(a4.w);
  }
#pragma unroll
  for (int n = 0; n < 16; ++n)
    ok = ok && (fabsf(adn[n] + (float)(n + 1)) <= 1e-3f * (float)(n + 1));

  float h[16];
#pragma unroll
  for (int n = 0; n < 16; ++n) h[n] = 0.f;
  float cd = 0.f;

  for (int half = 0; half < 2; ++half) {
    if (half) __syncthreads();
    for (int i = tid; i < TH * 32; i += 256) {
      int tt = i >> 5, q = i & 31;
      *(u16x8*)&xsS[tt][q * 8] =
          *(const u16x8*)(xsb16 + (rowbase + half * TH + tt) * 2048 + d0 + q * 8);
    }
    __syncthreads();

    if (ok) {
      for (int tt = 0; tt < TH; ++tt) {
        int t = half * TH + tt;
        float pre = fmaf(drS[t], wdt, bdt);
        float e = __expf(pre);
        float dlt = (pre > 20.f) ? pre : __logf(1.f + e);
        float xv = bf2f(xsS[tt][tid]);
        float dx = dlt * xv;
        cd += dlt;
        float r = __expf(-dlt);
        float rp[16];
        rpowers(r, rp);
        f32x4 Bv[4];
#pragma unroll
        for (int k = 0; k < 4; ++k) Bv[k] = ((const f32x4*)&bS[t][0])[k];
#pragma unroll
        for (int n = 0; n < 16; ++n)
          h[n] = fmaf(rp[n], h[n], dx * Bv[n >> 2][n & 3]);
      }
    } else {
      for (int tt = 0; tt < TH; ++tt) {
        int t = half * TH + tt;
        float pre = fmaf(drS[t], wdt, bdt);
        float e = __expf(pre);
        float dlt = (pre > 20.f) ? pre : __logf(1.f + e);
        float xv = bf2f(xsS[tt][tid]);
        float dx = dlt * xv;
        cd += dlt;
        f32x4 Bv[4];
#pragma unroll
        for (int k = 0; k < 4; ++k) Bv[k] = ((const f32x4*)&bS[t][0])[k];
#pragma unroll
        for (int n = 0; n < 16; ++n) {
          float dA = __expf(adn[n] * dlt);
          h[n] = fmaf(dA, h[n], dx * Bv[n >> 2][n & 3]);
        }
      }
    }
  }
  cdg[(size_t)(b * NC + chunk) * 2048 + d] = cd;
  float* Sp = Sg + ((size_t)(b * NC + chunk) * 32768 + (size_t)d * 16);
#pragma unroll
  for (int k = 0; k < 4; ++k)
    ((float4*)Sp)[k] = make_float4(h[4 * k], h[4 * k + 1], h[4 * k + 2], h[4 * k + 3]);
}

__global__ __launch_bounds__(256) void scan_p2(
    const float* __restrict__ Sg, const float* __restrict__ cdg,
    const float* __restrict__ alog, float* __restrict__ Hg)
{
  int g = blockIdx.x * 256 + threadIdx.x;   // 65536 = B*D*N
  int b = g >> 15, dn = g & 32767;
  int d = dn >> 4;
  float adn = -__expf(alog[dn]);
  float h = 0.f;
  for (int c = 0; c < NC; ++c) {
    size_t o = (size_t)(b * NC + c) * 32768 + dn;
    float P = __expf(adn * cdg[(size_t)(b * NC + c) * 2048 + d]);
    Hg[o] = h;
    h = fmaf(P, h, Sg[o]);
  }
}

__global__ __launch_bounds__(256) void scan_p3(
    const unsigned short* __restrict__ xsb16, const float* __restrict__ dbc,
    const float* __restrict__ dtw, const float* __restrict__ dtb,
    const float* __restrict__ alog, const float* __restrict__ Dp,
    const unsigned short* __restrict__ xzb, const float* __restrict__ Hg,
    unsigned short* __restrict__ gb)
{
  const int chunk = blockIdx.x;
  const int d0 = blockIdx.y * 256;
  const int b = blockIdx.z;
  const int tid = threadIdx.x;
  const size_t rowbase = (size_t)b * 4096 + chunk * TC;

  __shared__ __align__(16) unsigned short xsS[TH][256];
  __shared__ __align__(16) float bcS[TC][32];

  for (int i = tid; i < TC * 32; i += 256) {
    int t = i >> 5, q = i & 31;
    bcS[t][q] = dbc[(rowbase + t) * 128 + 1 + q];
  }

  const int d = d0 + tid;
  const float wdt = dtw[d], bdt = dtb[d], Dd = Dp[d];
  const float* __restrict__ drp = dbc + rowbase * 128;
  float adn[16];
  bool ok = true;
#pragma unroll
  for (int k = 0; k < 4; ++k) {
    float4 a4 = *(const float4*)(alog + (size_t)d * 16 + k * 4);
    adn[4 * k + 0] = -__expf(a4.x); adn[4 * k + 1] = -__expf(a4.y);
    adn[4 * k + 2] = -__expf(a4.z); adn[4 * k + 3] = -__expf(a4.w);
  }
#pragma unroll
  for (int n = 0; n < 16; ++n)
    ok = ok && (fabsf(adn[n] + (float)(n + 1)) <= 1e-3f * (float)(n + 1));

  float h[16];
  {
    const float* Hp = Hg + ((size_t)(b * NC + chunk) * 32768 + (size_t)d * 16);
#pragma unroll
    for (int k = 0; k < 4; ++k) {
      float4 h4 = ((const float4*)Hp)[k];
      h[4 * k + 0] = h4.x; h[4 * k + 1] = h4.y; h[4 * k + 2] = h4.z; h[4 * k + 3] = h4.w;
    }
  }

  for (int half = 0; half < 2; ++half) {
    if (half) __syncthreads();
    for (int i = tid; i < TH * 32; i += 256) {
      int tt = i >> 5, q = i & 31;
      *(u16x8*)&xsS[tt][q * 8] =
          *(const u16x8*)(xsb16 + (rowbase + half * TH + tt) * 2048 + d0 + q * 8);
    }
    __syncthreads();

    if (ok) {
      for (int tt = 0; tt < TH; ++tt) {
        int t = half * TH + tt;
        float pre = fmaf(drp[(size_t)t * 128], wdt, bdt);
        float e = __expf(pre);
        float dlt = (pre > 20.f) ? pre : __logf(1.f + e);
        float xv = bf2f(xsS[tt][tid]);
        float dx = dlt * xv;
        float r = __expf(-dlt);
        float rp[16];
        rpowers(r, rp);
        f32x4 Bv[4], Cv[4];
#pragma unroll
        for (int k = 0; k < 4; ++k) {
          Bv[k] = ((const f32x4*)&bcS[t][0])[k];
          Cv[k] = ((const f32x4*)&bcS[t][16])[k];
        }
        float yp[4];
        yp[0] = Dd * xv; yp[1] = 0.f; yp[2] = 0.f; yp[3] = 0.f;
#pragma unroll
        for (int n = 0; n < 16; ++n) {
          h[n] = fmaf(rp[n], h[n], dx * Bv[n >> 2][n & 3]);
          yp[n & 3] = fmaf(h[n], Cv[n >> 2][n & 3], yp[n & 3]);
        }
        float y = (yp[0] + yp[1]) + (yp[2] + yp[3]);
        xsS[tt][tid] = f2bf(y);
      }
    } else {
      for (int tt = 0; tt < TH; ++tt) {
        int t = half * TH + tt;
        float pre = fmaf(drp[(size_t)t * 128], wdt, bdt);
        float e = __expf(pre);
        float dlt = (pre > 20.f) ? pre : __logf(1.f + e);
        float xv = bf2f(xsS[tt][tid]);
        float dx = dlt * xv;
        f32x4 Bv[4], Cv[4];
#pragma unroll
        for (int k = 0; k < 4; ++k) {
          Bv[k] = ((const f32x4*)&bcS[t][0])[k];
          Cv[k] = ((const f32x4*)&bcS[t][16])[k];
        }
        float yp[4];
        yp[0] = Dd * xv; yp[1] = 0.f; yp[2] = 0.f; yp[3] = 0.f;
#pragma unroll
        for (int n = 0; n < 16; ++n) {
          float dA = __expf(adn[n] * dlt);
          h[n] = fmaf(dA, h[n], dx * Bv[n >> 2][n & 3]);
          yp[n & 3] = fmaf(h[n], Cv[n >> 2][n & 3], yp[n & 3]);
        }
        float y = (yp[0] + yp[1]) + (yp[2] + yp[3]);
        xsS[tt][tid] = f2bf(y);
      }
    }
    __syncthreads();

    for (int i = tid; i < TH * 32; i += 256) {
      int tt = i >> 5, q = i & 31;
      size_t row = rowbase + half * TH + tt;
      u16x8 yv = *(const u16x8*)&xsS[tt][q * 8];
      u16x8 zv = *(const u16x8*)(xzb + row * 4096 + 2048 + d0 + q * 8);
      u16x8 ov;
#pragma unroll
      for (int j = 0; j < 8; ++j) {
        float z = bf2f(zv[j]);
        float s = z / (1.f + __expf(-z));
        ov[j] = f2bf(bf2f(yv[j]) * s);
      }
      *(u16x8*)(gb + row * 2048 + d0 + q * 8) = ov;
    }
  }
}

extern "C" void kernel_launch(void* const* d_in, const int* in_sizes, int n_in,
                              void* d_out, int out_size, void* d_ws, size_t ws_size,
                              hipStream_t stream) {
  const float* x    = (const float*)d_in[0];
  const float* ipw  = (const float*)d_in[1];
  const float* cw   = (const float*)d_in[2];
  const float* cb   = (const float*)d_in[3];
  const float* xpw  = (const float*)d_in[4];
  const float* dtw  = (const float*)d_in[5];
  const float* dtb  = (const float*)d_in[6];
  const float* alog = (const float*)d_in[7];
  const float* Dp   = (const float*)d_in[8];
  const float* opw  = (const float*)d_in[9];
  float* out = (float*)d_out;

  char* p = (char*)d_ws;
  unsigned short* xb   = (unsigned short*)p; p += (size_t)8388608 * 2;   // x bf16 (16 MiB) — reused as Hg
  unsigned short* wb1  = (unsigned short*)p; p += (size_t)4194304 * 2;   // in_proj_w bf16   (8 MiB)
  unsigned short* wb2  = (unsigned short*)p; p += (size_t)2097152 * 2;   // out_proj_w bf16  (4 MiB)
  unsigned short* xwp  = (unsigned short*)p; p += (size_t)262144 * 2;    // padded x_proj_w  (0.5 MiB)
  unsigned short* xzb  = (unsigned short*)p; p += (size_t)33554432 * 2;  // in_proj out bf16 (64 MiB)
  unsigned short* xsb16= (unsigned short*)p; p += (size_t)16777216 * 2;  // conv+silu bf16   (32 MiB)
  float*          dbc  = (float*)p;          p += (size_t)1048576 * 4;   // x_proj out fp32  (4 MiB)
  unsigned short* gb   = (unsigned short*)p; p += (size_t)16777216 * 2;  // y*silu(z) bf16   (32 MiB)
  float*          Sg   = (float*)p;          p += (size_t)4194304 * 4;   // chunk states     (16 MiB)
  float*          cdg  = (float*)p;          p += (size_t)262144 * 4;    // chunk decay sums (1 MiB)
  float*          Hg   = (float*)xb;                                     // chunk entry states (aliases xb)
  float*          dbcp = Sg;                                             // 4 split-K partials (alias Sg)

  prep_k<<<dim3(512, 4), 256, 0, stream>>>(
      (const float4*)x, (const float4*)ipw, (const float4*)opw, xpw,
      (ushort4*)xb, (ushort4*)wb1, (ushort4*)wb2, xwp);

  gemm8p<true, true><<<512, 512, 0, stream>>>(xb, wb1, xzb, 8192, 4096, 1024);
  conv_silu_k<<<dim3(4096 / CONV_L, 2), 256, 0, stream>>>(xzb, cw, cb, xsb16);

  gemm2p<false, false><<<dim3(64, 1, 4), 256, 0, stream>>>(xsb16, xwp, dbcp, 8192, 128, 2048);
  redux4_k<<<1024, 256, 0, stream>>>((const float4*)dbcp, (float4*)dbc);

  scan_p1<<<dim3(NC, 8, 2), 256, 0, stream>>>(xsb16, dbc, dtw, dtb, alog, Sg, cdg);
  scan_p2<<<256, 256, 0, stream>>>(Sg, cdg, alog, Hg);
  scan_p3<<<dim3(NC, 8, 2), 256, 0, stream>>>(xsb16, dbc, dtw, dtb, alog, Dp, xzb, Hg, gb);

  gemm2p<false, true><<<dim3(512, 1, 1), 256, 0, stream>>>(gb, wb2, out, 8192, 1024, 2048);
}